// Round 13
// baseline (820.360 us; speedup 1.0000x reference)
//
#include <hip/hip_runtime.h>

#define LTOK 4096
#define DHID 2048
#define HKN  16
#define HVN  32
#define DKK  128
#define NTOT 12288

typedef unsigned short u16;
typedef __attribute__((ext_vector_type(8))) short short8;
typedef __attribute__((ext_vector_type(8))) unsigned short u16x8;
typedef __attribute__((ext_vector_type(4))) unsigned short u16x4;
typedef __attribute__((ext_vector_type(4))) float f32x4;

__device__ __forceinline__ float b2f(u16 u) {
  unsigned int x = ((unsigned int)u) << 16;
  return __builtin_bit_cast(float, x);
}
__device__ __forceinline__ u16 f2bf(float f) {
  unsigned int u = __builtin_bit_cast(unsigned int, f);
  u += 0x7FFFu + ((u >> 16) & 1u);
  return (u16)(u >> 16);
}

template<int C> __device__ __forceinline__ float dppmv(float x) {
  int i = __builtin_amdgcn_update_dpp(0, __builtin_bit_cast(int, x), C, 0xF, 0xF, true);
  return __builtin_bit_cast(float, i);
}
__device__ __forceinline__ float red16(float x) {
  x += dppmv<0xB1>(x);
  x += dppmv<0x4E>(x);
  x += dppmv<0x124>(x);
  x += dppmv<0x128>(x);
  return x;
}

__device__ __forceinline__ void gld16(const void* g, void* l) {
  __builtin_amdgcn_global_load_lds((const __attribute__((address_space(1))) void*)g,
                                   (__attribute__((address_space(3))) void*)l, 16, 0, 0);
}

// pinned-order LDS vector read (addr VGPR + compile-time byte offset)
template<int OFF> __device__ __forceinline__ short8 dsr(unsigned a) {
  short8 r;
  asm volatile("ds_read_b128 %0, %1 offset:%2" : "=v"(r) : "v"(a), "n"(OFF));
  return r;
}
// pinned-order global vector load to VGPR (B fragments; counted in vmcnt manually)
__device__ __forceinline__ short8 gldx4(const u16* p) {
  short8 r;
  asm volatile("global_load_dwordx4 %0, %1, off" : "=v"(r) : "v"(p));
  return r;
}
// keep a register value live (rule #17) - blocks allocator reuse until this point
#define KEEPV(x) asm volatile("" :: "v"(x))

// swizzled LDS element offsets (XOR row-bits into 16B-slot bits); byte^=((r&7)<<4)
__device__ __forceinline__ int sw16(int r, int c, int rowc) { return (r * rowc + c) ^ ((r & 7) << 3); }

__device__ __forceinline__ void cstore(u16* C, size_t i, float v) { C[i] = f2bf(v); }
__device__ __forceinline__ void cstore(float* C, size_t i, float v) { C[i] = v; }

// ---------------- fp32 -> bf16 convert ----------------
__global__ __launch_bounds__(256)
void k_cvt(const float* __restrict__ s, u16* __restrict__ d, int n) {
  const int i = (blockIdx.x * 256 + threadIdx.x) * 4;
  const float4 v = *(const float4*)(s + i);
  ushort4 o;
  o.x = f2bf(v.x); o.y = f2bf(v.y); o.z = f2bf(v.z); o.w = f2bf(v.w);
  *(ushort4*)(d + i) = o;
}

// ---------------- fp32 W[K][N] -> bf16 B-fragment-major layout ----------------
__global__ __launch_bounds__(256)
void k_trf(const float* __restrict__ W, u16* __restrict__ Bf, int Ncols, int nkt, int j16base) {
  const int wv = threadIdx.x >> 6, lane = threadIdx.x & 63;
  const int frag = blockIdx.x * 4 + wv;
  const int j16 = frag / nkt, kt = frag % nkt;
  const int r0 = kt * 32 + (lane >> 4) * 8;
  const int c = j16 * 16 + (lane & 15);
  u16x8 o;
#pragma unroll
  for (int e = 0; e < 8; ++e) o[e] = f2bf(W[(size_t)(r0 + e) * Ncols + c]);
  *(u16x8*)(Bf + ((size_t)(j16base + j16) * nkt + kt) * 512 + lane * 8) = o;
}

#define MFMA16(a, b, c) __builtin_amdgcn_mfma_f32_16x16x32_bf16(a, b, c, 0, 0, 0)

// ---------------- 256xBN bf16 MFMA GEMM, B-from-global, 1 barrier / 2 K-tiles ----------------
// A: LDS-staged gld16 (4 bufs, depth-3, T2 source-swizzle) + 1-tile-ahead reg frag prefetch.
// B: fragment-major global, 1-tile-ahead reg loads. ITERA/ITERB pair shares ONE barrier:
//   ITERA(kt): LOADB(kt+1); vmcnt(NWN) [retires B(kt)+A(kt+2) pre-barrier]; BARRIER;
//              STAGE(kt+3) [post-barrier: ordered vs all waves' RD(kt-1)]; RD(kt+1); MFMA(kt).
//   ITERB:     LOADB(kt+2); vmcnt(NWN+2) [retires B(kt+1)]; STAGE(kt+4); RD(kt+2); MFMA(kt+1).
// Safety: barrier guarantees all waves completed ITERB(kt-1) (lgkm-drained reads of tiles
// kt-1,kt) before the post-barrier STAGEs overwrite those buffers; pre-barrier vmcnt covers
// A(kt+1)/A(kt+2) for every wave so both post-barrier RDs are landed chip-wide.
template<typename OutT, int NWN>
__global__ __launch_bounds__(512, 2)
void k_g256(const u16* __restrict__ A, const u16* __restrict__ Bf, OutT* __restrict__ C,
            int M, int N, int K, int NT) {
  constexpr int BN = NWN * 64;
  __shared__ u16 Lds[4 * 8192];              // A only: 4 bufs x 16KB
  const int tid = threadIdx.x;
  const int lane = tid & 63, w = tid >> 6;
  const int fr = lane & 15, fq = lane >> 4;
  const int wm = (w >> 2) * 128, wn = (w & 3) * (NWN * 16);
  const int nkt = K >> 5;
  const size_t sK = (size_t)K;

  // supertile + XCD-aware ordering (bijective; MT%8==0)
  const int MT = gridDim.x / NT;
  const int nts = (NT < 16) ? NT : 16;
  const int per_super = MT * nts;
  const int super = blockIdx.x / per_super;
  const int within = blockIdx.x % per_super;
  const int mtg = MT >> 3;
  const int q = within >> 3;
  const int mt = (within & 7) * mtg + (q % mtg);
  const int nt = super * nts + q / mtg;

  // A staging: thread covers row tid/4 (+128 for 2nd load); k-slot pre-swizzled (T2 #21)
  const int kslot = ((tid & 3) ^ ((tid >> 3) & 3)) * 8;
  const u16* aS = A + (size_t)(mt * 256 + (tid >> 2)) * sK + kslot;

  // B fragment base pointers (compile-time-indexed -> registers, rule #20)
  const int jw = nt * (BN / 16) + (w & 3) * NWN;
  const u16* bp[NWN];
#pragma unroll
  for (int j = 0; j < NWN; ++j) bp[j] = Bf + ((size_t)(jw + j) * nkt) * 512 + lane * 8;

  f32x4 acc[8][NWN] = {};

  auto STAGE = [&](int kt_) {
    const int sk = (kt_ < nkt) ? kt_ : nkt - 1;
    u16* base = &Lds[(kt_ & 3) * 8192];
    gld16(aS + (size_t)sk * 32, base + w * 512);
    gld16(aS + 128 * sK + (size_t)sk * 32, base + w * 512 + 4096);
  };

#define LOADB(bset, kt_) {                                                    \
    const int sk2 = ((kt_) < nkt) ? (kt_) : (nkt - 1);                        \
    _Pragma("unroll")                                                         \
    for (int j = 0; j < NWN; ++j) bset[j] = gldx4(bp[j] + (size_t)sk2 * 512); }

  const int akey = (fr >> 1) & 3;            // read-side swizzle key
  const unsigned ldsBase = (unsigned)(size_t)(__attribute__((address_space(3))) void*)&Lds[0];
  const unsigned aA0 = ldsBase + 2u * (unsigned)((wm + fr) * 32 + ((fq ^ akey) << 3));

  short8 afA[8], afB[8], bs0[NWN], bs1[NWN];

#define RD(afX, kt_) {                                                        \
    const unsigned aAr = aA0 + (unsigned)(((kt_) & 3) * 16384);               \
    afX[0] = dsr<0>(aAr);    afX[1] = dsr<1024>(aAr);                         \
    afX[2] = dsr<2048>(aAr); afX[3] = dsr<3072>(aAr);                         \
    afX[4] = dsr<4096>(aAr); afX[5] = dsr<5120>(aAr);                         \
    afX[6] = dsr<6144>(aAr); afX[7] = dsr<7168>(aAr); }

#define MFMABLK(afC, bC) {                                                    \
    __builtin_amdgcn_s_setprio(1);                                            \
    _Pragma("unroll")                                                         \
    for (int i = 0; i < 8; ++i)                                               \
      _Pragma("unroll")                                                       \
      for (int j = 0; j < NWN; ++j)                                           \
        acc[i][j] = MFMA16(afC[i], bC[j], acc[i][j]);                         \
    __builtin_amdgcn_s_setprio(0);                                            \
    asm volatile("s_waitcnt lgkmcnt(0)" ::: "memory");                        \
    __builtin_amdgcn_sched_barrier(0); }

  // prologue: A0..A2 staged, B0 loaded, full drain, read A0 fragments
  STAGE(0); STAGE(1); STAGE(2);
  LOADB(bs0, 0)
  asm volatile("s_waitcnt vmcnt(0)" ::: "memory");
  __builtin_amdgcn_s_barrier();
  RD(afA, 0)
  asm volatile("s_waitcnt lgkmcnt(0)" ::: "memory");
  __builtin_amdgcn_sched_barrier(0);

  for (int kt = 0; kt < nkt; kt += 2) {
    // ---- ITERA(kt): even tile, carries the barrier ----
    LOADB(bs1, kt + 1)
    asm volatile("s_waitcnt vmcnt(%0)" :: "n"(NWN) : "memory");
    __builtin_amdgcn_s_barrier();
    __builtin_amdgcn_sched_barrier(0);
    STAGE(kt + 3);
    RD(afB, kt + 1)
    __builtin_amdgcn_sched_barrier(0);
    MFMABLK(afA, bs0)
    // ---- ITERB(kt+1): odd tile, no barrier ----
    LOADB(bs0, kt + 2)
    asm volatile("s_waitcnt vmcnt(%0)" :: "n"(NWN + 2) : "memory");
    __builtin_amdgcn_sched_barrier(0);
    STAGE(kt + 4);
    RD(afA, kt + 2)
    __builtin_amdgcn_sched_barrier(0);
    MFMABLK(afB, bs1)
  }
#undef MFMABLK
#undef RD
#undef LOADB

  // drain ALL in-flight vmem; keep unconsumed asm-load destinations alive past the
  // drain so the allocator cannot hand their registers to epilogue values while
  // loads are still landing (R11 fault).
  asm volatile("s_waitcnt vmcnt(0) lgkmcnt(0)" ::: "memory");
  __builtin_amdgcn_sched_barrier(0);
  KEEPV(bs0[0]); KEEPV(bs0[1]);
  if constexpr (NWN == 4) { KEEPV(bs0[2]); KEEPV(bs0[3]); }
  KEEPV(bs1[0]); KEEPV(bs1[1]);
  if constexpr (NWN == 4) { KEEPV(bs1[2]); KEEPV(bs1[3]); }
  KEEPV(afA[0]); KEEPV(afA[1]); KEEPV(afA[2]); KEEPV(afA[3]);
  KEEPV(afA[4]); KEEPV(afA[5]); KEEPV(afA[6]); KEEPV(afA[7]);
  KEEPV(afB[0]); KEEPV(afB[1]); KEEPV(afB[2]); KEEPV(afB[3]);
  KEEPV(afB[4]); KEEPV(afB[5]); KEEPV(afB[6]); KEEPV(afB[7]);

  const int r0 = mt * 256 + wm + fq * 4;
  const int c0 = nt * BN + wn + fr;
#pragma unroll
  for (int i = 0; i < 8; ++i)
#pragma unroll
    for (int j = 0; j < NWN; ++j)
#pragma unroll
      for (int e = 0; e < 4; ++e)
        cstore(C, (size_t)(r0 + i * 16 + e) * N + c0 + j * 16, acc[i][j][e]);
}

// ---------------- beta / g (log-decay): [L,2048]@[2048,32] x2 + activations ----------------
__global__ __launch_bounds__(256)
void k_ba(const float* __restrict__ h, const float* __restrict__ Wb, const float* __restrict__ Wa,
          const float* __restrict__ A_log, const float* __restrict__ dtb,
          float* __restrict__ beta, float* __restrict__ g_out) {
  const int w = threadIdx.x >> 6, lane = threadIdx.x & 63;
  const int t = blockIdx.x * 4 + w;
  const int j = lane & 31;
  const bool isB = lane < 32;
  const float* __restrict__ hr = h + (size_t)t * DHID;
  const float* Wc = isB ? Wb : Wa;
  float acc = 0.f;
  for (int kk = 0; kk < DHID; ++kk) acc = fmaf(hr[kk], Wc[(size_t)kk * HVN + j], acc);
  if (isB) {
    beta[(size_t)t * HVN + j] = 1.f / (1.f + expf(-acc));
  } else {
    float xx = acc + dtb[j];
    float sp = (xx > 20.f) ? xx : log1pf(expf(xx));
    g_out[(size_t)t * HVN + j] = -expf(A_log[j]) * sp;   // g = log(decay) <= 0
  }
}

// ---------------- in-place l2norm of q (scaled) and k heads ----------------
__global__ __launch_bounds__(256)
void k_l2n(u16* __restrict__ qkvz) {
  const int w = threadIdx.x >> 6, lane = threadIdx.x & 63;
  const int r = blockIdx.x * 4 + w;
  const int isK = r >> 16;
  const int rr = r & 65535;
  const int t = rr >> 4, hd = rr & 15;
  u16* p = qkvz + (size_t)t * NTOT + isK * 2048 + hd * DKK + lane * 2;
  float a = b2f(p[0]), b = b2f(p[1]);
  float ss = a * a + b * b;
  ss = red16(ss);
  ss += __shfl_xor(ss, 16);
  ss += __shfl_xor(ss, 32);
  const float sc = rsqrtf(ss + 1e-6f) * (isK ? 1.f : 0.08838834764831845f);
  p[0] = f2bf(a * sc); p[1] = f2bf(b * sc);
}

// ---------------- chunk solve (parallel): per (hv, chunk n) ----------------
__global__ __launch_bounds__(256)
void k_r1(const u16* __restrict__ qkvz, const float* __restrict__ beta_g,
          const float* __restrict__ g_g, u16* __restrict__ UM_g, float* __restrict__ cumL_g) {
  const int pair = blockIdx.x;          // hv*64 + n
  const int hv = pair >> 6, n = pair & 63;
  const int hk = hv >> 1;
  const int t0 = n * 64;
  const int tid = threadIdx.x, lane = tid & 63, wv = tid >> 6;
  const int fr = lane & 15, fq = lane >> 4;

  __shared__ __align__(16) u16 Xb[256 * 64];
  __shared__ __align__(16) u16 Dbuf0[64 * 64 * 2];
  __shared__ __align__(16) u16 Dbuf1[64 * 64 * 2];
  __shared__ float Lc[64];
  __shared__ float Bc[64];
  u16* Kl = Dbuf0;

  const int j = tid & 63, h = tid >> 6;
  const u16* kg = qkvz + (size_t)(t0 + j) * NTOT + 2048 + hk * DKK + h * 32;
  const u16* vg = qkvz + (size_t)(t0 + j) * NTOT + 4096 + hv * DKK + h * 32;
  u16x8 kv[4], vv[4];
#pragma unroll
  for (int i = 0; i < 4; ++i) { kv[i] = *(const u16x8*)(kg + i * 8); vv[i] = *(const u16x8*)(vg + i * 8); }
  if (tid < 64) {
    Lc[tid] = g_g[(size_t)(t0 + tid) * HVN + hv];
    Bc[tid] = beta_g[(size_t)(t0 + tid) * HVN + hv];
  }
#pragma unroll
  for (int i = 0; i < 4; ++i) *(u16x8*)&Kl[sw16(j, h * 32 + i * 8, 128)] = kv[i];
  __syncthreads();
  if (tid == 0) { float a = 0.f; for (int t = 0; t < 64; ++t) { a += Lc[t]; Lc[t] = a; } }
  __syncthreads();
  if (tid < 64) cumL_g[(size_t)pair * 64 + tid] = Lc[tid];

  {
    const float bj = Bc[j];
    const float mj = bj * __expf(Lc[j]);
#pragma unroll
    for (int i = 0; i < 4; ++i)
#pragma unroll
      for (int e = 0; e < 8; ++e) {
        int c = h * 32 + i * 8 + e;
        Xb[sw16(c, j, 64)] = f2bf(bj * b2f(vv[i][e]));
        Xb[sw16(128 + c, j, 64)] = f2bf(mj * b2f(kv[i][e]));
      }
  }
  f32x4 kk[4] = {};
#pragma unroll
  for (int ks = 0; ks < 4; ++ks) {
    short8 afr = *(const short8*)&Kl[sw16(wv * 16 + fr, ks * 32 + fq * 8, 128)];
#pragma unroll
    for (int ct = 0; ct < 4; ++ct) {
      short8 bfr = *(const short8*)&Kl[sw16(ct * 16 + fr, ks * 32 + fq * 8, 128)];
      kk[ct] = MFMA16(afr, bfr, kk[ct]);
    }
  }
  __syncthreads();

  f32x4 acc[16];
#pragma unroll
  for (int ct = 0; ct < 16; ++ct) {
    u16x4 xi = *(const u16x4*)&Xb[sw16(ct * 16 + fr, wv * 16 + fq * 4, 64)];
    acc[ct][0] = b2f(xi[0]); acc[ct][1] = b2f(xi[1]); acc[ct][2] = b2f(xi[2]); acc[ct][3] = b2f(xi[3]);
  }
#pragma unroll
  for (int ct = 0; ct < 4; ++ct) {
    const int s = ct * 16 + fr;
    u16x4 pk;
#pragma unroll
    for (int e = 0; e < 4; ++e) {
      const int t = wv * 16 + fq * 4 + e;
      float v = (s < t) ? -Bc[t] * __expf(Lc[t] - Lc[s]) * kk[ct][e] : 0.f;
      pk[e] = f2bf(v);
      Dbuf0[sw16(t, s, 64)] = pk[e];
    }
    *(u16x4*)&Dbuf0[4096 + sw16(s, wv * 16 + fq * 4, 64)] = pk;
  }
  __syncthreads();

  u16* DA = Dbuf0;
  u16* DB = Dbuf1;
  for (int stg = 0; stg < 6; ++stg) {
    u16* Dr = DA;
    u16* Dc = DA + 4096;
    short8 da0 = *(const short8*)&Dr[sw16(wv * 16 + fr, 0 + fq * 8, 64)];
    short8 da1 = *(const short8*)&Dr[sw16(wv * 16 + fr, 32 + fq * 8, 64)];
#pragma unroll
    for (int ct = 0; ct < 16; ++ct) {
      short8 b0 = *(const short8*)&Xb[sw16(ct * 16 + fr, 0 + fq * 8, 64)];
      short8 b1 = *(const short8*)&Xb[sw16(ct * 16 + fr, 32 + fq * 8, 64)];
      acc[ct] = MFMA16(da0, b0, acc[ct]);
      acc[ct] = MFMA16(da1, b1, acc[ct]);
    }
    f32x4 sq[4] = {};
    if (stg < 5) {
#pragma unroll
      for (int ct = 0; ct < 4; ++ct) {
        short8 sb0 = *(const short8*)&Dc[sw16(ct * 16 + fr, 0 + fq * 8, 64)];
        short8 sb1 = *(const short8*)&Dc[sw16(ct * 16 + fr, 32 + fq * 8, 64)];
        sq[ct] = MFMA16(da0, sb0, sq[ct]);
        sq[ct] = MFMA16(da1, sb1, sq[ct]);
      }
    }
    __syncthreads();
#pragma unroll
    for (int ct = 0; ct < 16; ++ct) {
      u16x4 pk;
      pk[0] = f2bf(acc[ct][0]); pk[1] = f2bf(acc[ct][1]); pk[2] = f2bf(acc[ct][2]); pk[3] = f2bf(acc[ct][3]);
      *(u16x4*)&Xb[sw16(ct * 16 + fr, wv * 16 + fq * 4, 64)] = pk;
    }
    if (stg < 5) {
#pragma unroll
      for (int ct = 0; ct < 4; ++ct) {
        u16x4 pk;
        pk[0] = f2bf(sq[ct][0]); pk[1] = f2bf(sq[ct][1]); pk[2] = f2bf(sq[ct][2]); pk[3] = f2bf(sq[ct][3]);
        *(u16x4*)&(DB + 4096)[sw16(ct * 16 + fr, wv * 16 + fq * 4, 64)] = pk;
#pragma unroll
        for (int e = 0; e < 4; ++e) DB[sw16(wv * 16 + fq * 4 + e, ct * 16 + fr, 64)] = pk[e];
      }
    }
    __syncthreads();
    u16* tmp = DA; DA = DB; DB = tmp;
  }

#pragma unroll
  for (int ct = 0; ct < 16; ++ct) {
    const int c = ct * 16 + fr;
#pragma unroll
    for (int e = 0; e < 4; ++e) {
      const int t = wv * 16 + fq * 4 + e;
      float v = acc[ct][e];
      if (ct >= 8) v = -v;
      UM_g[((size_t)pair * 64 + t) * 256 + c] = f2bf(v);
    }
  }
}

// ---------------- sequential chunk scan: 128 blocks = (hv, dv-quarter cs) ----------------
__global__ __launch_bounds__(512)
void k_r2(u16* __restrict__ qkvz, const u16* __restrict__ UM_g,
          const float* __restrict__ cumL_g, u16* __restrict__ o1_g) {
  const int hv = blockIdx.x >> 2, cs = blockIdx.x & 3;
  const int hk = hv >> 1;
  const int tid = threadIdx.x, lane = tid & 63, w = tid >> 6;   // 8 waves
  const int fr = lane & 15, fq = lane >> 4;
  const int j = tid & 63, h = tid >> 6;                          // staging coords
  const int tw = w & 3, dwv = w >> 2;                            // ph1 tile coords

  __shared__ __align__(16) u16 Ml2[2][8192];   // -M rows [t][dk] swz
  __shared__ __align__(16) u16 Ql2[2][8192];   // q rows
  __shared__ __align__(16) u16 Kt2[2][8192];   // Kbar^T [dk][t] swz
  __shared__ __align__(16) u16 dT[2048];       // delta^T [32 ldv][64 t] swz
  __shared__ __align__(16) u16 SbT[4096];      // S^T [32 ldv][128 dk] swz
  __shared__ __align__(16) u16 o1b[2048];      // o1 [32 ldv][64 t] swz
  __shared__ float Lc2[2][64];

  f32x4 sacc[2];
#pragma unroll
  for (int d = 0; d < 2; ++d) sacc[d] = (f32x4){0.f, 0.f, 0.f, 0.f};
  for (int i = tid; i < 4096; i += 512) SbT[i] = 0;

  u16x8 pQ0, pQ1, pK0, pK1, pM0, pM1;
  u16 pUn0, pUn1, pUn2, pUn3, pUc0, pUc1, pUc2, pUc3;
  float pL, pL63;

#define PREF(nn) {                                                            \
    const int nc = ((nn) < 64) ? (nn) : 63;                                   \
    const int pr = hv * 64 + nc; const int tt0 = nc * 64;                     \
    const u16* qg = qkvz + (size_t)(tt0 + j) * NTOT + hk * DKK + h * 16;      \
    pQ0 = *(const u16x8*)qg;          pQ1 = *(const u16x8*)(qg + 8);          \
    pK0 = *(const u16x8*)(qg + 2048); pK1 = *(const u16x8*)(qg + 2056);       \
    const u16* mg = UM_g + ((size_t)pr * 64 + j) * 256;                       \
    pM0 = *(const u16x8*)(mg + 128 + h * 16);                                 \
    pM1 = *(const u16x8*)(mg + 136 + h * 16);                                 \
    const u16* ug = UM_g + ((size_t)pr * 64 + tw * 16 + fq * 4) * 256         \
                    + cs * 32 + dwv * 16 + fr;                                \
    pUn0 = ug[0]; pUn1 = ug[256]; pUn2 = ug[512]; pUn3 = ug[768];             \
    pL = cumL_g[(size_t)pr * 64 + j]; pL63 = cumL_g[(size_t)pr * 64 + 63]; }

#define STW(b) {                                                              \
    *(u16x8*)&Ql2[b][sw16(j, h * 16, 128)] = pQ0;                             \
    *(u16x8*)&Ql2[b][sw16(j, h * 16 + 8, 128)] = pQ1;                         \
    *(u16x8*)&Ml2[b][sw16(j, h * 16, 128)] = pM0;                             \
    *(u16x8*)&Ml2[b][sw16(j, h * 16 + 8, 128)] = pM1;                         \
    const float scK = __expf(pL63 - pL);                                      \
    _Pragma("unroll")                                                         \
    for (int e = 0; e < 8; ++e) {                                             \
      Kt2[b][sw16(h * 16 + e, j, 64)] = f2bf(scK * b2f(pK0[e]));              \
      Kt2[b][sw16(h * 16 + 8 + e, j, 64)] = f2bf(scK * b2f(pK1[e]));          \
    }                                                                         \
    if (h == 0) Lc2[b][j] = pL; }

  PREF(0)
  STW(0)
  __syncthreads();

  for (int n = 0; n < 64; ++n) {
    const int cur = n & 1;
    const int pair = hv * 64 + n, t0 = n * 64;
    pUc0 = pUn0; pUc1 = pUn1; pUc2 = pUn2; pUc3 = pUn3;
    const float curL63 = pL63;
    PREF(n + 1)

    // ---- ph1: delta = U + (-M)@S ; o1 = e^{Lt}(Q@S) ----
    short8 amf[4], aqf[4];
#pragma unroll
    for (int ks = 0; ks < 4; ++ks) {
      amf[ks] = *(const short8*)&Ml2[cur][sw16(tw * 16 + fr, ks * 32 + fq * 8, 128)];
      aqf[ks] = *(const short8*)&Ql2[cur][sw16(tw * 16 + fr, ks * 32 + fq * 8, 128)];
    }
    float el[4];
#pragma unroll
    for (int e = 0; e < 4; ++e) el[e] = __expf(Lc2[cur][tw * 16 + fq * 4 + e]);
    {
      f32x4 dc;
      dc[0] = b2f(pUc0); dc[1] = b2f(pUc1); dc[2] = b2f(pUc2); dc[3] = b2f(pUc3);
      f32x4 oc = {};
#pragma unroll
      for (int ks = 0; ks < 4; ++ks) {
        short8 bs = *(const short8*)&SbT[sw16(dwv * 16 + fr, ks * 32 + fq * 8, 128)];
        dc = MFMA16(amf[ks], bs, dc);
        oc = MFMA16(aqf[ks], bs, oc);
      }
      u16x4 pkd;
      pkd[0] = f2bf(dc[0]); pkd[1] = f2bf(dc[1]); pkd[2] = f2bf(dc[2]); pkd[3] = f2bf(dc[3]);
      *(u16x4*)&dT[sw16(dwv * 16 + fr, tw * 16 + fq * 4, 64)] = pkd;
      u16x4 pko;
#pragma unroll
      for (int e = 0; e < 4; ++e) pko[e] = f2bf(oc[e] * el[e]);
      *(u16x4*)&o1b[sw16(dwv * 16 + fr, tw * 16 + fq * 4, 64)] = pko;
    }
    __syncthreads();

    // ---- ph2: flush delta/o1 to global; stage next; S-update ----
    {
      const int i = tid * 4;
      u16x4 vd = *(const u16x4*)&dT[i];
      const int f = cs * 2048 + i;
      *(u16x4*)(qkvz + (size_t)(t0 + (f >> 7)) * NTOT + 4096 + hv * DKK + (f & 127)) = vd;
      u16x4 vo = *(const u16x4*)&o1b[i];
      *(u16x4*)(o1_g + (size_t)pair * 8192 + cs * 2048 + i) = vo;
    }
    STW(cur ^ 1)
    {
      const float eC = __expf(curL63);
      short8 ak0 = *(const short8*)&Kt2[cur][sw16(w * 16 + fr, fq * 8, 64)];
      short8 ak1 = *(const short8*)&Kt2[cur][sw16(w * 16 + fr, 32 + fq * 8, 64)];
#pragma unroll
      for (int d = 0; d < 2; ++d) {
        short8 bd0 = *(const short8*)&dT[sw16(d * 16 + fr, fq * 8, 64)];
        short8 bd1 = *(const short8*)&dT[sw16(d * 16 + fr, 32 + fq * 8, 64)];
        f32x4 sa = sacc[d];
#pragma unroll
        for (int e = 0; e < 4; ++e) sa[e] *= eC;
        sa = MFMA16(ak0, bd0, sa);
        sa = MFMA16(ak1, bd1, sa);
        sacc[d] = sa;
        u16x4 pk;
        pk[0] = f2bf(sa[0]); pk[1] = f2bf(sa[1]); pk[2] = f2bf(sa[2]); pk[3] = f2bf(sa[3]);
        *(u16x4*)&SbT[sw16(d * 16 + fr, w * 16 + fq * 4, 128)] = pk;
      }
    }
    __syncthreads();
  }
#undef PREF
#undef STW
}

// ---------------- parallel epilogue: o = o1 + G@delta, fused gated RMSNorm ----------------
__global__ __launch_bounds__(512)
void k_r3(const u16* __restrict__ qkvz, const u16* __restrict__ o1_g,
          const float* __restrict__ cumL_g, const float* __restrict__ nw,
          u16* __restrict__ x) {
  const int pair = blockIdx.x, hv = pair >> 6, n = pair & 63, hk = hv >> 1, t0 = n * 64;
  const int tid = threadIdx.x, lane = tid & 63, w = tid >> 6;
  const int fr = lane & 15, fq = lane >> 4;
  const int j = tid & 63, h = tid >> 6;   // h 0..7

  __shared__ __align__(16) u16 Ql[8192];
  __shared__ __align__(16) u16 Kl[8192];
  __shared__ __align__(16) u16 Gl[4096];
  __shared__ __align__(16) u16 dTl[8192];
  __shared__ __align__(16) u16 o1l[8192];      // o1 [dv][t] swz (raw block from k_r2)
  __shared__ __align__(16) float of[64 * 132];
  __shared__ float Lc[64];
  __shared__ float Lw[128];

  {
    const u16* qg = qkvz + (size_t)(t0 + j) * NTOT + hk * DKK + h * 16;
    u16x8 q0 = *(const u16x8*)qg, q1 = *(const u16x8*)(qg + 8);
    u16x8 k0 = *(const u16x8*)(qg + 2048), k1 = *(const u16x8*)(qg + 2056);
    *(u16x8*)&Ql[sw16(j, h * 16, 128)] = q0;
    *(u16x8*)&Ql[sw16(j, h * 16 + 8, 128)] = q1;
    *(u16x8*)&Kl[sw16(j, h * 16, 128)] = k0;
    *(u16x8*)&Kl[sw16(j, h * 16 + 8, 128)] = k1;
  }
#pragma unroll
  for (int it = 0; it < 2; ++it) {
    const int f = ((w * 2 + it) * 64 + lane) * 8;
    gld16(qkvz + (size_t)(t0 + (f >> 7)) * NTOT + 4096 + hv * DKK + (f & 127),
          (char*)dTl + (w * 2 + it) * 1024);
    gld16(o1_g + (size_t)pair * 8192 + f, (char*)o1l + (w * 2 + it) * 1024);
  }
  if (tid < 64) Lc[tid] = cumL_g[(size_t)pair * 64 + tid];
  if (tid < 128) Lw[tid] = nw[tid];
  __syncthreads();

  // ---- G = tril(e^{Lt-Ls} * QK^T) ----
  const int tw = w & 3, sp = (w >> 2) * 2;
  {
    f32x4 kk0 = {}, kk1 = {};
#pragma unroll
    for (int ks = 0; ks < 4; ++ks) {
      short8 aq = *(const short8*)&Ql[sw16(tw * 16 + fr, ks * 32 + fq * 8, 128)];
      short8 b0 = *(const short8*)&Kl[sw16(sp * 16 + fr, ks * 32 + fq * 8, 128)];
      short8 b1 = *(const short8*)&Kl[sw16((sp + 1) * 16 + fr, ks * 32 + fq * 8, 128)];
      kk0 = MFMA16(aq, b0, kk0);
      kk1 = MFMA16(aq, b1, kk1);
    }
#pragma unroll
    for (int e = 0; e < 4; ++e) {
      const int t = tw * 16 + fq * 4 + e;
      const float Lt = Lc[t];
      const int s0 = sp * 16 + fr, s1 = s0 + 16;
      Gl[sw16(t, s0, 64)] = f2bf((s0 <= t) ? kk0[e] * __expf(Lt - Lc[s0]) : 0.f);
      Gl[sw16(t, s1, 64)] = f2bf((s1 <= t) ? kk1[e] * __expf(Lt - Lc[s1]) : 0.f);
    }
  }
  __syncthreads();

  // ---- o = G@delta ----
  {
    short8 ag0 = *(const short8*)&Gl[sw16(tw * 16 + fr, fq * 8, 64)];
    short8 ag1 = *(const short8*)&Gl[sw16(tw * 16 + fr, 32 + fq * 8, 64)];
#pragma unroll
    for (int dd = 0; dd < 4; ++dd) {
      const int d = (w >> 2) * 4 + dd;
      short8 bd0 = *(const short8*)&dTl[sw16(d * 16 + fr, fq * 8, 64)];
      short8 bd1 = *(const short8*)&dTl[sw16(d * 16 + fr, 32 + fq * 8, 64)];
      f32x4 oc = {};
      oc = MFMA16(ag0, bd0, oc);
      oc = MFMA16(ag1, bd1, oc);
#pragma unroll
      for (int e = 0; e < 4; ++e) of[(tw * 16 + fq * 4 + e) * 132 + d * 16 + fr] = oc[e];
    }
  }
  __syncthreads();

  // ---- fused gated RMSNorm: x = rmsnorm((of + o1) * silu(z)) * w ----
  {
    const int t = tid >> 3, q8 = tid & 7;
    const u16* zp = qkvz + (size_t)(t0 + t) * NTOT + 8192 + hv * DKK + q8 * 16;
    float xv[16];
    float ss = 0.f;
#pragma unroll
    for (int i = 0; i < 2; ++i) {
      u16x8 zv = *(const u16x8*)(zp + i * 8);
#pragma unroll
      for (int e = 0; e < 8; ++e) {
        const int dv = q8 * 16 + i * 8 + e;
        float z = b2f(zv[e]);
        float o = of[t * 132 + dv] + b2f(o1l[sw16(dv, t, 64)]);
        float xx = o * (z / (1.f + __expf(-z)));
        xv[i * 8 + e] = xx;
        ss = fmaf(xx, xx, ss);
      }
    }
    ss += __shfl_xor(ss, 1);
    ss += __shfl_xor(ss, 2);
    ss += __shfl_xor(ss, 4);
    const float scl = rsqrtf(ss * (1.f / 128.f) + 1e-6f);
    u16* xo = x + (size_t)(t0 + t) * 4096 + hv * DKK + q8 * 16;
#pragma unroll
    for (int i = 0; i < 2; ++i) {
      u16x8 pk;
#pragma unroll
      for (int e = 0; e < 8; ++e) pk[e] = f2bf(xv[i * 8 + e] * scl * Lw[q8 * 16 + i * 8 + e]);
      *(u16x8*)(xo + i * 8) = pk;
    }
  }
}

extern "C" void kernel_launch(void* const* d_in, const int* in_sizes, int n_in,
                              void* d_out, int out_size, void* d_ws, size_t ws_size,
                              hipStream_t stream) {
  const float* h    = (const float*)d_in[0];
  const float* Wq   = (const float*)d_in[1];
  const float* Wk   = (const float*)d_in[2];
  const float* Wv   = (const float*)d_in[3];
  const float* Wz   = (const float*)d_in[4];
  const float* Wb   = (const float*)d_in[5];
  const float* Wa   = (const float*)d_in[6];
  const float* Alog = (const float*)d_in[7];
  const float* dtb  = (const float*)d_in[8];
  const float* nw   = (const float*)d_in[9];
  const float* Wo   = (const float*)d_in[10];
  char* ws = (char*)d_ws;
  u16* h_bf  = (u16*)(ws);
  u16* Bfq   = (u16*)(ws + 16777216ull);      // [768 j16][64 kt][512] bf16 = 50.33MB
  u16* UM    = (u16*)(ws);                    // [2048][64][256] bf16 = 64MB (after GEMM)
  u16* Bfo   = (u16*)(ws + 67108864ull);      // [128 j16][128 kt][512] bf16 = 16.8MB
  u16* qkvz  = (u16*)(ws + 83886080ull);
  u16* o1g   = (u16*)(ws + 184549376ull);     // [2048][128dv][64t] bf16 = 32MB
  u16* xbuf  = (u16*)(ws + 16777216ull);      // aliases Bfq (dead after qkvz GEMM)
  float* beta  = (float*)(ws + 218103808ull);
  float* g     = (float*)(ws + 218103808ull + 524288ull);
  float* cumL  = (float*)(ws + 218103808ull + 1048576ull);

  k_cvt<<<8192, 256, 0, stream>>>(h, h_bf, LTOK * DHID);
  k_trf<<<2048, 256, 0, stream>>>(Wq, Bfq, 2048, 64, 0);
  k_trf<<<2048, 256, 0, stream>>>(Wk, Bfq, 2048, 64, 128);
  k_trf<<<4096, 256, 0, stream>>>(Wv, Bfq, 4096, 64, 256);
  k_trf<<<4096, 256, 0, stream>>>(Wz, Bfq, 4096, 64, 512);
  k_trf<<<4096, 256, 0, stream>>>(Wo, Bfo, 2048, 128, 0);
  k_g256<u16, 4><<<768, 512, 0, stream>>>(h_bf, Bfq, qkvz, 4096, 12288, 2048, 48);
  k_ba<<<1024, 256, 0, stream>>>(h, Wb, Wa, Alog, dtb, beta, g);
  k_l2n<<<32768, 256, 0, stream>>>(qkvz);
  k_r1<<<2048, 256, 0, stream>>>(qkvz, beta, g, UM, cumL);
  k_r2<<<128, 512, 0, stream>>>(qkvz, UM, cumL, o1g);
  k_r3<<<2048, 512, 0, stream>>>(qkvz, o1g, cumL, nw, xbuf);
  k_g256<float, 2><<<256, 512, 0, stream>>>(xbuf, Bfo, (float*)d_out, 4096, 2048, 4096, 16);
}

// Round 14
// 812.547 us; speedup vs baseline: 1.0096x; 1.0096x over previous
//
#include <hip/hip_runtime.h>

#define LTOK 4096
#define DHID 2048
#define HKN  16
#define HVN  32
#define DKK  128
#define NTOT 12288

typedef unsigned short u16;
typedef __attribute__((ext_vector_type(8))) short short8;
typedef __attribute__((ext_vector_type(8))) unsigned short u16x8;
typedef __attribute__((ext_vector_type(4))) unsigned short u16x4;
typedef __attribute__((ext_vector_type(4))) float f32x4;

__device__ __forceinline__ float b2f(u16 u) {
  unsigned int x = ((unsigned int)u) << 16;
  return __builtin_bit_cast(float, x);
}
__device__ __forceinline__ u16 f2bf(float f) {
  unsigned int u = __builtin_bit_cast(unsigned int, f);
  u += 0x7FFFu + ((u >> 16) & 1u);
  return (u16)(u >> 16);
}

template<int C> __device__ __forceinline__ float dppmv(float x) {
  int i = __builtin_amdgcn_update_dpp(0, __builtin_bit_cast(int, x), C, 0xF, 0xF, true);
  return __builtin_bit_cast(float, i);
}
__device__ __forceinline__ float red16(float x) {
  x += dppmv<0xB1>(x);
  x += dppmv<0x4E>(x);
  x += dppmv<0x124>(x);
  x += dppmv<0x128>(x);
  return x;
}

__device__ __forceinline__ void gld16(const void* g, void* l) {
  __builtin_amdgcn_global_load_lds((const __attribute__((address_space(1))) void*)g,
                                   (__attribute__((address_space(3))) void*)l, 16, 0, 0);
}

// pinned-order LDS vector read (addr VGPR + compile-time byte offset)
template<int OFF> __device__ __forceinline__ short8 dsr(unsigned a) {
  short8 r;
  asm volatile("ds_read_b128 %0, %1 offset:%2" : "=v"(r) : "v"(a), "n"(OFF));
  return r;
}
// pinned-order global vector load to VGPR (B fragments; counted in vmcnt manually)
__device__ __forceinline__ short8 gldx4(const u16* p) {
  short8 r;
  asm volatile("global_load_dwordx4 %0, %1, off" : "=v"(r) : "v"(p));
  return r;
}
// keep a register value live (rule #17) - blocks allocator reuse until this point
#define KEEPV(x) asm volatile("" :: "v"(x))

// swizzled LDS element offsets (XOR row-bits into 16B-slot bits); byte^=((r&7)<<4)
__device__ __forceinline__ int sw16(int r, int c, int rowc) { return (r * rowc + c) ^ ((r & 7) << 3); }

__device__ __forceinline__ void cstore(u16* C, size_t i, float v) { C[i] = f2bf(v); }
__device__ __forceinline__ void cstore(float* C, size_t i, float v) { C[i] = v; }

// ---------------- fp32 -> bf16 convert ----------------
__global__ __launch_bounds__(256)
void k_cvt(const float* __restrict__ s, u16* __restrict__ d, int n) {
  const int i = (blockIdx.x * 256 + threadIdx.x) * 4;
  const float4 v = *(const float4*)(s + i);
  ushort4 o;
  o.x = f2bf(v.x); o.y = f2bf(v.y); o.z = f2bf(v.z); o.w = f2bf(v.w);
  *(ushort4*)(d + i) = o;
}

// ---------------- fp32 W[K][N] -> bf16 B-fragment-major layout ----------------
__global__ __launch_bounds__(256)
void k_trf(const float* __restrict__ W, u16* __restrict__ Bf, int Ncols, int nkt, int j16base) {
  const int wv = threadIdx.x >> 6, lane = threadIdx.x & 63;
  const int frag = blockIdx.x * 4 + wv;
  const int j16 = frag / nkt, kt = frag % nkt;
  const int r0 = kt * 32 + (lane >> 4) * 8;
  const int c = j16 * 16 + (lane & 15);
  u16x8 o;
#pragma unroll
  for (int e = 0; e < 8; ++e) o[e] = f2bf(W[(size_t)(r0 + e) * Ncols + c]);
  *(u16x8*)(Bf + ((size_t)(j16base + j16) * nkt + kt) * 512 + lane * 8) = o;
}

#define MFMA16(a, b, c) __builtin_amdgcn_mfma_f32_16x16x32_bf16(a, b, c, 0, 0, 0)

// ---------------- (NWM*128)xBN bf16 MFMA GEMM, B-from-global (flatmm) ----------------
// A: LDS-staged gld16 (4 bufs, depth-3, T2 source-swizzle) + 1-tile-ahead reg frag
// prefetch. B: fragment-major global, 1-tile-ahead reg loads. R12 schedule (best
// measured): one barrier per K-tile, counted vmcnt(NWN+4) retires {B(kt), A(kt+2)}.
// NWM=2: 512 thr, 8 waves (2Mx4N). NWM=1: 256 thr, 4 waves (1Mx4N) - used for the
// out-proj so grid doubles to 512 blocks = 2 blocks/CU (R13 found it at 14% peak
// with 1 block/CU, latency fully exposed).
template<typename OutT, int NWM, int NWN>
__global__ __launch_bounds__(NWM * 256, 2)
void k_g256(const u16* __restrict__ A, const u16* __restrict__ Bf, OutT* __restrict__ C,
            int M, int N, int K, int NT) {
  constexpr int BN = NWN * 64;
  constexpr int BUFE = NWM * 4096;           // A elems per LDS buffer
  __shared__ u16 Lds[4 * BUFE];
  const int tid = threadIdx.x;
  const int lane = tid & 63, w = tid >> 6;
  const int fr = lane & 15, fq = lane >> 4;
  const int wm = (w >> 2) * 128, wn = (w & 3) * (NWN * 16);
  const int nkt = K >> 5;
  const size_t sK = (size_t)K;

  // supertile + XCD-aware ordering (bijective; gridDim.x % 8 == 0)
  const int MT = gridDim.x / NT;
  const int nts = (NT < 16) ? NT : 16;
  const int per_super = MT * nts;
  const int super = blockIdx.x / per_super;
  const int within = blockIdx.x % per_super;
  const int mtg = MT >> 3;
  const int q = within >> 3;
  const int mt = (within & 7) * mtg + (q % mtg);
  const int nt = super * nts + q / mtg;

  // A staging: thread covers row tid/4 (+NWM*64 for 2nd load); k-slot pre-swizzled (T2)
  const int kslot = ((tid & 3) ^ ((tid >> 3) & 3)) * 8;
  const u16* aS = A + (size_t)(mt * (NWM * 128) + (tid >> 2)) * sK + kslot;

  // B fragment base pointers (compile-time-indexed -> registers, rule #20)
  const int jw = nt * (BN / 16) + (w & 3) * NWN;
  const u16* bp[NWN];
#pragma unroll
  for (int j = 0; j < NWN; ++j) bp[j] = Bf + ((size_t)(jw + j) * nkt) * 512 + lane * 8;

  f32x4 acc[8][NWN] = {};

  auto STAGE = [&](int kt_) {
    const int sk = (kt_ < nkt) ? kt_ : nkt - 1;
    u16* base = &Lds[(kt_ & 3) * BUFE];
    gld16(aS + (size_t)sk * 32, base + tid * 8);
    gld16(aS + (size_t)(NWM * 64) * sK + (size_t)sk * 32, base + NWM * 2048 + tid * 8);
  };

#define LOADB(bset, kt_) {                                                    \
    const int sk2 = ((kt_) < nkt) ? (kt_) : (nkt - 1);                        \
    _Pragma("unroll")                                                         \
    for (int j = 0; j < NWN; ++j) bset[j] = gldx4(bp[j] + (size_t)sk2 * 512); }

  const int akey = (fr >> 1) & 3;            // read-side swizzle key
  const unsigned ldsBase = (unsigned)(size_t)(__attribute__((address_space(3))) void*)&Lds[0];
  const unsigned aA0 = ldsBase + 2u * (unsigned)((wm + fr) * 32 + ((fq ^ akey) << 3));

  short8 afA[8], afB[8], bs0[NWN], bs1[NWN];

#define RD(afX, kt_) {                                                        \
    const unsigned aAr = aA0 + (unsigned)(((kt_) & 3) * (BUFE * 2));          \
    afX[0] = dsr<0>(aAr);    afX[1] = dsr<1024>(aAr);                         \
    afX[2] = dsr<2048>(aAr); afX[3] = dsr<3072>(aAr);                         \
    afX[4] = dsr<4096>(aAr); afX[5] = dsr<5120>(aAr);                         \
    afX[6] = dsr<6144>(aAr); afX[7] = dsr<7168>(aAr); }

  // prologue: A0..A2 staged, B0 loaded, full drain, read A0 fragments
  STAGE(0); STAGE(1); STAGE(2);
  LOADB(bs0, 0)
  asm volatile("s_waitcnt vmcnt(0)" ::: "memory");
  __builtin_amdgcn_s_barrier();
  RD(afA, 0)
  asm volatile("s_waitcnt lgkmcnt(0)" ::: "memory");
  __builtin_amdgcn_sched_barrier(0);

  // per iter kt: issue [B(kt+1), A-stage(kt+3)]; vmcnt(NWN+4) -> {B(kt),A(kt+2)} landed;
  // barrier; read A(kt+1) frags into next set (no wait); MFMA(kt); lgkm(0)+sched_barrier.
#define ITER(kt_, afC, bC, afN, bN) {                                         \
    LOADB(bN, (kt_) + 1)                                                      \
    STAGE((kt_) + 3);                                                         \
    asm volatile("s_waitcnt vmcnt(%0)" :: "n"(NWN + 4) : "memory");           \
    __builtin_amdgcn_s_barrier();                                             \
    __builtin_amdgcn_sched_barrier(0);                                        \
    RD(afN, (kt_) + 1)                                                        \
    __builtin_amdgcn_sched_barrier(0);                                        \
    __builtin_amdgcn_s_setprio(1);                                            \
    _Pragma("unroll")                                                         \
    for (int i = 0; i < 8; ++i)                                               \
      _Pragma("unroll")                                                       \
      for (int j = 0; j < NWN; ++j)                                           \
        acc[i][j] = MFMA16(afC[i], bC[j], acc[i][j]);                         \
    __builtin_amdgcn_s_setprio(0);                                            \
    asm volatile("s_waitcnt lgkmcnt(0)" ::: "memory");                        \
    __builtin_amdgcn_sched_barrier(0); }

  for (int kt = 0; kt < nkt; kt += 2) {
    ITER(kt, afA, bs0, afB, bs1)
    ITER(kt + 1, afB, bs1, afA, bs0)
  }
#undef ITER
#undef RD
#undef LOADB

  // drain ALL in-flight vmem; keep unconsumed asm-load destinations alive past the
  // drain so the allocator cannot hand their registers to epilogue values while
  // loads are still landing (R11 fault).
  asm volatile("s_waitcnt vmcnt(0) lgkmcnt(0)" ::: "memory");
  __builtin_amdgcn_sched_barrier(0);
  KEEPV(bs0[0]); KEEPV(bs0[1]);
  if constexpr (NWN == 4) { KEEPV(bs0[2]); KEEPV(bs0[3]); }
  KEEPV(afA[0]); KEEPV(afA[1]); KEEPV(afA[2]); KEEPV(afA[3]);
  KEEPV(afA[4]); KEEPV(afA[5]); KEEPV(afA[6]); KEEPV(afA[7]);

  const int r0 = mt * (NWM * 128) + wm + fq * 4;
  const int c0 = nt * BN + wn + fr;
#pragma unroll
  for (int i = 0; i < 8; ++i)
#pragma unroll
    for (int j = 0; j < NWN; ++j)
#pragma unroll
      for (int e = 0; e < 4; ++e)
        cstore(C, (size_t)(r0 + i * 16 + e) * N + c0 + j * 16, acc[i][j][e]);
}

// ---------------- beta / g (log-decay): [L,2048]@[2048,32] x2 + activations ----------------
__global__ __launch_bounds__(256)
void k_ba(const float* __restrict__ h, const float* __restrict__ Wb, const float* __restrict__ Wa,
          const float* __restrict__ A_log, const float* __restrict__ dtb,
          float* __restrict__ beta, float* __restrict__ g_out) {
  const int w = threadIdx.x >> 6, lane = threadIdx.x & 63;
  const int t = blockIdx.x * 4 + w;
  const int j = lane & 31;
  const bool isB = lane < 32;
  const float* __restrict__ hr = h + (size_t)t * DHID;
  const float* Wc = isB ? Wb : Wa;
  float acc = 0.f;
  for (int kk = 0; kk < DHID; ++kk) acc = fmaf(hr[kk], Wc[(size_t)kk * HVN + j], acc);
  if (isB) {
    beta[(size_t)t * HVN + j] = 1.f / (1.f + expf(-acc));
  } else {
    float xx = acc + dtb[j];
    float sp = (xx > 20.f) ? xx : log1pf(expf(xx));
    g_out[(size_t)t * HVN + j] = -expf(A_log[j]) * sp;   // g = log(decay) <= 0
  }
}

// ---------------- in-place l2norm of q (scaled) and k heads ----------------
__global__ __launch_bounds__(256)
void k_l2n(u16* __restrict__ qkvz) {
  const int w = threadIdx.x >> 6, lane = threadIdx.x & 63;
  const int r = blockIdx.x * 4 + w;
  const int isK = r >> 16;
  const int rr = r & 65535;
  const int t = rr >> 4, hd = rr & 15;
  u16* p = qkvz + (size_t)t * NTOT + isK * 2048 + hd * DKK + lane * 2;
  float a = b2f(p[0]), b = b2f(p[1]);
  float ss = a * a + b * b;
  ss = red16(ss);
  ss += __shfl_xor(ss, 16);
  ss += __shfl_xor(ss, 32);
  const float sc = rsqrtf(ss + 1e-6f) * (isK ? 1.f : 0.08838834764831845f);
  p[0] = f2bf(a * sc); p[1] = f2bf(b * sc);
}

// ---------------- chunk solve (parallel): per (hv, chunk n) ----------------
__global__ __launch_bounds__(256)
void k_r1(const u16* __restrict__ qkvz, const float* __restrict__ beta_g,
          const float* __restrict__ g_g, u16* __restrict__ UM_g, float* __restrict__ cumL_g) {
  const int pair = blockIdx.x;          // hv*64 + n
  const int hv = pair >> 6, n = pair & 63;
  const int hk = hv >> 1;
  const int t0 = n * 64;
  const int tid = threadIdx.x, lane = tid & 63, wv = tid >> 6;
  const int fr = lane & 15, fq = lane >> 4;

  __shared__ __align__(16) u16 Xb[256 * 64];
  __shared__ __align__(16) u16 Dbuf0[64 * 64 * 2];
  __shared__ __align__(16) u16 Dbuf1[64 * 64 * 2];
  __shared__ float Lc[64];
  __shared__ float Bc[64];
  u16* Kl = Dbuf0;

  const int j = tid & 63, h = tid >> 6;
  const u16* kg = qkvz + (size_t)(t0 + j) * NTOT + 2048 + hk * DKK + h * 32;
  const u16* vg = qkvz + (size_t)(t0 + j) * NTOT + 4096 + hv * DKK + h * 32;
  u16x8 kv[4], vv[4];
#pragma unroll
  for (int i = 0; i < 4; ++i) { kv[i] = *(const u16x8*)(kg + i * 8); vv[i] = *(const u16x8*)(vg + i * 8); }
  if (tid < 64) {
    Lc[tid] = g_g[(size_t)(t0 + tid) * HVN + hv];
    Bc[tid] = beta_g[(size_t)(t0 + tid) * HVN + hv];
  }
#pragma unroll
  for (int i = 0; i < 4; ++i) *(u16x8*)&Kl[sw16(j, h * 32 + i * 8, 128)] = kv[i];
  __syncthreads();
  if (tid == 0) { float a = 0.f; for (int t = 0; t < 64; ++t) { a += Lc[t]; Lc[t] = a; } }
  __syncthreads();
  if (tid < 64) cumL_g[(size_t)pair * 64 + tid] = Lc[tid];

  {
    const float bj = Bc[j];
    const float mj = bj * __expf(Lc[j]);
#pragma unroll
    for (int i = 0; i < 4; ++i)
#pragma unroll
      for (int e = 0; e < 8; ++e) {
        int c = h * 32 + i * 8 + e;
        Xb[sw16(c, j, 64)] = f2bf(bj * b2f(vv[i][e]));
        Xb[sw16(128 + c, j, 64)] = f2bf(mj * b2f(kv[i][e]));
      }
  }
  f32x4 kk[4] = {};
#pragma unroll
  for (int ks = 0; ks < 4; ++ks) {
    short8 afr = *(const short8*)&Kl[sw16(wv * 16 + fr, ks * 32 + fq * 8, 128)];
#pragma unroll
    for (int ct = 0; ct < 4; ++ct) {
      short8 bfr = *(const short8*)&Kl[sw16(ct * 16 + fr, ks * 32 + fq * 8, 128)];
      kk[ct] = MFMA16(afr, bfr, kk[ct]);
    }
  }
  __syncthreads();

  f32x4 acc[16];
#pragma unroll
  for (int ct = 0; ct < 16; ++ct) {
    u16x4 xi = *(const u16x4*)&Xb[sw16(ct * 16 + fr, wv * 16 + fq * 4, 64)];
    acc[ct][0] = b2f(xi[0]); acc[ct][1] = b2f(xi[1]); acc[ct][2] = b2f(xi[2]); acc[ct][3] = b2f(xi[3]);
  }
#pragma unroll
  for (int ct = 0; ct < 4; ++ct) {
    const int s = ct * 16 + fr;
    u16x4 pk;
#pragma unroll
    for (int e = 0; e < 4; ++e) {
      const int t = wv * 16 + fq * 4 + e;
      float v = (s < t) ? -Bc[t] * __expf(Lc[t] - Lc[s]) * kk[ct][e] : 0.f;
      pk[e] = f2bf(v);
      Dbuf0[sw16(t, s, 64)] = pk[e];
    }
    *(u16x4*)&Dbuf0[4096 + sw16(s, wv * 16 + fq * 4, 64)] = pk;
  }
  __syncthreads();

  u16* DA = Dbuf0;
  u16* DB = Dbuf1;
  for (int stg = 0; stg < 6; ++stg) {
    u16* Dr = DA;
    u16* Dc = DA + 4096;
    short8 da0 = *(const short8*)&Dr[sw16(wv * 16 + fr, 0 + fq * 8, 64)];
    short8 da1 = *(const short8*)&Dr[sw16(wv * 16 + fr, 32 + fq * 8, 64)];
#pragma unroll
    for (int ct = 0; ct < 16; ++ct) {
      short8 b0 = *(const short8*)&Xb[sw16(ct * 16 + fr, 0 + fq * 8, 64)];
      short8 b1 = *(const short8*)&Xb[sw16(ct * 16 + fr, 32 + fq * 8, 64)];
      acc[ct] = MFMA16(da0, b0, acc[ct]);
      acc[ct] = MFMA16(da1, b1, acc[ct]);
    }
    f32x4 sq[4] = {};
    if (stg < 5) {
#pragma unroll
      for (int ct = 0; ct < 4; ++ct) {
        short8 sb0 = *(const short8*)&Dc[sw16(ct * 16 + fr, 0 + fq * 8, 64)];
        short8 sb1 = *(const short8*)&Dc[sw16(ct * 16 + fr, 32 + fq * 8, 64)];
        sq[ct] = MFMA16(da0, sb0, sq[ct]);
        sq[ct] = MFMA16(da1, sb1, sq[ct]);
      }
    }
    __syncthreads();
#pragma unroll
    for (int ct = 0; ct < 16; ++ct) {
      u16x4 pk;
      pk[0] = f2bf(acc[ct][0]); pk[1] = f2bf(acc[ct][1]); pk[2] = f2bf(acc[ct][2]); pk[3] = f2bf(acc[ct][3]);
      *(u16x4*)&Xb[sw16(ct * 16 + fr, wv * 16 + fq * 4, 64)] = pk;
    }
    if (stg < 5) {
#pragma unroll
      for (int ct = 0; ct < 4; ++ct) {
        u16x4 pk;
        pk[0] = f2bf(sq[ct][0]); pk[1] = f2bf(sq[ct][1]); pk[2] = f2bf(sq[ct][2]); pk[3] = f2bf(sq[ct][3]);
        *(u16x4*)&(DB + 4096)[sw16(ct * 16 + fr, wv * 16 + fq * 4, 64)] = pk;
#pragma unroll
        for (int e = 0; e < 4; ++e) DB[sw16(wv * 16 + fq * 4 + e, ct * 16 + fr, 64)] = pk[e];
      }
    }
    __syncthreads();
    u16* tmp = DA; DA = DB; DB = tmp;
  }

#pragma unroll
  for (int ct = 0; ct < 16; ++ct) {
    const int c = ct * 16 + fr;
#pragma unroll
    for (int e = 0; e < 4; ++e) {
      const int t = wv * 16 + fq * 4 + e;
      float v = acc[ct][e];
      if (ct >= 8) v = -v;
      UM_g[((size_t)pair * 64 + t) * 256 + c] = f2bf(v);
    }
  }
}

// ---------------- sequential chunk scan: 128 blocks = (hv, dv-quarter cs) ----------------
__global__ __launch_bounds__(512)
void k_r2(u16* __restrict__ qkvz, const u16* __restrict__ UM_g,
          const float* __restrict__ cumL_g, u16* __restrict__ o1_g) {
  const int hv = blockIdx.x >> 2, cs = blockIdx.x & 3;
  const int hk = hv >> 1;
  const int tid = threadIdx.x, lane = tid & 63, w = tid >> 6;   // 8 waves
  const int fr = lane & 15, fq = lane >> 4;
  const int j = tid & 63, h = tid >> 6;                          // staging coords
  const int tw = w & 3, dwv = w >> 2;                            // ph1 tile coords

  __shared__ __align__(16) u16 Ml2[2][8192];   // -M rows [t][dk] swz
  __shared__ __align__(16) u16 Ql2[2][8192];   // q rows
  __shared__ __align__(16) u16 Kt2[2][8192];   // Kbar^T [dk][t] swz
  __shared__ __align__(16) u16 dT[2048];       // delta^T [32 ldv][64 t] swz
  __shared__ __align__(16) u16 SbT[4096];      // S^T [32 ldv][128 dk] swz
  __shared__ __align__(16) u16 o1b[2048];      // o1 [32 ldv][64 t] swz
  __shared__ float Lc2[2][64];

  f32x4 sacc[2];
#pragma unroll
  for (int d = 0; d < 2; ++d) sacc[d] = (f32x4){0.f, 0.f, 0.f, 0.f};
  for (int i = tid; i < 4096; i += 512) SbT[i] = 0;

  u16x8 pQ0, pQ1, pK0, pK1, pM0, pM1;
  u16 pUn0, pUn1, pUn2, pUn3, pUc0, pUc1, pUc2, pUc3;
  float pL, pL63;

#define PREF(nn) {                                                            \
    const int nc = ((nn) < 64) ? (nn) : 63;                                   \
    const int pr = hv * 64 + nc; const int tt0 = nc * 64;                     \
    const u16* qg = qkvz + (size_t)(tt0 + j) * NTOT + hk * DKK + h * 16;      \
    pQ0 = *(const u16x8*)qg;          pQ1 = *(const u16x8*)(qg + 8);          \
    pK0 = *(const u16x8*)(qg + 2048); pK1 = *(const u16x8*)(qg + 2056);       \
    const u16* mg = UM_g + ((size_t)pr * 64 + j) * 256;                       \
    pM0 = *(const u16x8*)(mg + 128 + h * 16);                                 \
    pM1 = *(const u16x8*)(mg + 136 + h * 16);                                 \
    const u16* ug = UM_g + ((size_t)pr * 64 + tw * 16 + fq * 4) * 256         \
                    + cs * 32 + dwv * 16 + fr;                                \
    pUn0 = ug[0]; pUn1 = ug[256]; pUn2 = ug[512]; pUn3 = ug[768];             \
    pL = cumL_g[(size_t)pr * 64 + j]; pL63 = cumL_g[(size_t)pr * 64 + 63]; }

#define STW(b) {                                                              \
    *(u16x8*)&Ql2[b][sw16(j, h * 16, 128)] = pQ0;                             \
    *(u16x8*)&Ql2[b][sw16(j, h * 16 + 8, 128)] = pQ1;                         \
    *(u16x8*)&Ml2[b][sw16(j, h * 16, 128)] = pM0;                             \
    *(u16x8*)&Ml2[b][sw16(j, h * 16 + 8, 128)] = pM1;                         \
    const float scK = __expf(pL63 - pL);                                      \
    _Pragma("unroll")                                                         \
    for (int e = 0; e < 8; ++e) {                                             \
      Kt2[b][sw16(h * 16 + e, j, 64)] = f2bf(scK * b2f(pK0[e]));              \
      Kt2[b][sw16(h * 16 + 8 + e, j, 64)] = f2bf(scK * b2f(pK1[e]));          \
    }                                                                         \
    if (h == 0) Lc2[b][j] = pL; }

  PREF(0)
  STW(0)
  __syncthreads();

  for (int n = 0; n < 64; ++n) {
    const int cur = n & 1;
    const int pair = hv * 64 + n, t0 = n * 64;
    pUc0 = pUn0; pUc1 = pUn1; pUc2 = pUn2; pUc3 = pUn3;
    const float curL63 = pL63;
    PREF(n + 1)

    // ---- ph1: delta = U + (-M)@S ; o1 = e^{Lt}(Q@S) ----
    short8 amf[4], aqf[4];
#pragma unroll
    for (int ks = 0; ks < 4; ++ks) {
      amf[ks] = *(const short8*)&Ml2[cur][sw16(tw * 16 + fr, ks * 32 + fq * 8, 128)];
      aqf[ks] = *(const short8*)&Ql2[cur][sw16(tw * 16 + fr, ks * 32 + fq * 8, 128)];
    }
    float el[4];
#pragma unroll
    for (int e = 0; e < 4; ++e) el[e] = __expf(Lc2[cur][tw * 16 + fq * 4 + e]);
    {
      f32x4 dc;
      dc[0] = b2f(pUc0); dc[1] = b2f(pUc1); dc[2] = b2f(pUc2); dc[3] = b2f(pUc3);
      f32x4 oc = {};
#pragma unroll
      for (int ks = 0; ks < 4; ++ks) {
        short8 bs = *(const short8*)&SbT[sw16(dwv * 16 + fr, ks * 32 + fq * 8, 128)];
        dc = MFMA16(amf[ks], bs, dc);
        oc = MFMA16(aqf[ks], bs, oc);
      }
      u16x4 pkd;
      pkd[0] = f2bf(dc[0]); pkd[1] = f2bf(dc[1]); pkd[2] = f2bf(dc[2]); pkd[3] = f2bf(dc[3]);
      *(u16x4*)&dT[sw16(dwv * 16 + fr, tw * 16 + fq * 4, 64)] = pkd;
      u16x4 pko;
#pragma unroll
      for (int e = 0; e < 4; ++e) pko[e] = f2bf(oc[e] * el[e]);
      *(u16x4*)&o1b[sw16(dwv * 16 + fr, tw * 16 + fq * 4, 64)] = pko;
    }
    __syncthreads();

    // ---- ph2: flush delta/o1 to global; stage next; S-update ----
    {
      const int i = tid * 4;
      u16x4 vd = *(const u16x4*)&dT[i];
      const int f = cs * 2048 + i;
      *(u16x4*)(qkvz + (size_t)(t0 + (f >> 7)) * NTOT + 4096 + hv * DKK + (f & 127)) = vd;
      u16x4 vo = *(const u16x4*)&o1b[i];
      *(u16x4*)(o1_g + (size_t)pair * 8192 + cs * 2048 + i) = vo;
    }
    STW(cur ^ 1)
    {
      const float eC = __expf(curL63);
      short8 ak0 = *(const short8*)&Kt2[cur][sw16(w * 16 + fr, fq * 8, 64)];
      short8 ak1 = *(const short8*)&Kt2[cur][sw16(w * 16 + fr, 32 + fq * 8, 64)];
#pragma unroll
      for (int d = 0; d < 2; ++d) {
        short8 bd0 = *(const short8*)&dT[sw16(d * 16 + fr, fq * 8, 64)];
        short8 bd1 = *(const short8*)&dT[sw16(d * 16 + fr, 32 + fq * 8, 64)];
        f32x4 sa = sacc[d];
#pragma unroll
        for (int e = 0; e < 4; ++e) sa[e] *= eC;
        sa = MFMA16(ak0, bd0, sa);
        sa = MFMA16(ak1, bd1, sa);
        sacc[d] = sa;
        u16x4 pk;
        pk[0] = f2bf(sa[0]); pk[1] = f2bf(sa[1]); pk[2] = f2bf(sa[2]); pk[3] = f2bf(sa[3]);
        *(u16x4*)&SbT[sw16(d * 16 + fr, w * 16 + fq * 4, 128)] = pk;
      }
    }
    __syncthreads();
  }
#undef PREF
#undef STW
}

// ---------------- parallel epilogue: o = o1 + G@delta, fused gated RMSNorm ----------------
__global__ __launch_bounds__(512)
void k_r3(const u16* __restrict__ qkvz, const u16* __restrict__ o1_g,
          const float* __restrict__ cumL_g, const float* __restrict__ nw,
          u16* __restrict__ x) {
  const int pair = blockIdx.x, hv = pair >> 6, n = pair & 63, hk = hv >> 1, t0 = n * 64;
  const int tid = threadIdx.x, lane = tid & 63, w = tid >> 6;
  const int fr = lane & 15, fq = lane >> 4;
  const int j = tid & 63, h = tid >> 6;   // h 0..7

  __shared__ __align__(16) u16 Ql[8192];
  __shared__ __align__(16) u16 Kl[8192];
  __shared__ __align__(16) u16 Gl[4096];
  __shared__ __align__(16) u16 dTl[8192];
  __shared__ __align__(16) u16 o1l[8192];      // o1 [dv][t] swz (raw block from k_r2)
  __shared__ __align__(16) float of[64 * 132];
  __shared__ float Lc[64];
  __shared__ float Lw[128];

  {
    const u16* qg = qkvz + (size_t)(t0 + j) * NTOT + hk * DKK + h * 16;
    u16x8 q0 = *(const u16x8*)qg, q1 = *(const u16x8*)(qg + 8);
    u16x8 k0 = *(const u16x8*)(qg + 2048), k1 = *(const u16x8*)(qg + 2056);
    *(u16x8*)&Ql[sw16(j, h * 16, 128)] = q0;
    *(u16x8*)&Ql[sw16(j, h * 16 + 8, 128)] = q1;
    *(u16x8*)&Kl[sw16(j, h * 16, 128)] = k0;
    *(u16x8*)&Kl[sw16(j, h * 16 + 8, 128)] = k1;
  }
#pragma unroll
  for (int it = 0; it < 2; ++it) {
    const int f = ((w * 2 + it) * 64 + lane) * 8;
    gld16(qkvz + (size_t)(t0 + (f >> 7)) * NTOT + 4096 + hv * DKK + (f & 127),
          (char*)dTl + (w * 2 + it) * 1024);
    gld16(o1_g + (size_t)pair * 8192 + f, (char*)o1l + (w * 2 + it) * 1024);
  }
  if (tid < 64) Lc[tid] = cumL_g[(size_t)pair * 64 + tid];
  if (tid < 128) Lw[tid] = nw[tid];
  __syncthreads();

  // ---- G = tril(e^{Lt-Ls} * QK^T) ----
  const int tw = w & 3, sp = (w >> 2) * 2;
  {
    f32x4 kk0 = {}, kk1 = {};
#pragma unroll
    for (int ks = 0; ks < 4; ++ks) {
      short8 aq = *(const short8*)&Ql[sw16(tw * 16 + fr, ks * 32 + fq * 8, 128)];
      short8 b0 = *(const short8*)&Kl[sw16(sp * 16 + fr, ks * 32 + fq * 8, 128)];
      short8 b1 = *(const short8*)&Kl[sw16((sp + 1) * 16 + fr, ks * 32 + fq * 8, 128)];
      kk0 = MFMA16(aq, b0, kk0);
      kk1 = MFMA16(aq, b1, kk1);
    }
#pragma unroll
    for (int e = 0; e < 4; ++e) {
      const int t = tw * 16 + fq * 4 + e;
      const float Lt = Lc[t];
      const int s0 = sp * 16 + fr, s1 = s0 + 16;
      Gl[sw16(t, s0, 64)] = f2bf((s0 <= t) ? kk0[e] * __expf(Lt - Lc[s0]) : 0.f);
      Gl[sw16(t, s1, 64)] = f2bf((s1 <= t) ? kk1[e] * __expf(Lt - Lc[s1]) : 0.f);
    }
  }
  __syncthreads();

  // ---- o = G@delta ----
  {
    short8 ag0 = *(const short8*)&Gl[sw16(tw * 16 + fr, fq * 8, 64)];
    short8 ag1 = *(const short8*)&Gl[sw16(tw * 16 + fr, 32 + fq * 8, 64)];
#pragma unroll
    for (int dd = 0; dd < 4; ++dd) {
      const int d = (w >> 2) * 4 + dd;
      short8 bd0 = *(const short8*)&dTl[sw16(d * 16 + fr, fq * 8, 64)];
      short8 bd1 = *(const short8*)&dTl[sw16(d * 16 + fr, 32 + fq * 8, 64)];
      f32x4 oc = {};
      oc = MFMA16(ag0, bd0, oc);
      oc = MFMA16(ag1, bd1, oc);
#pragma unroll
      for (int e = 0; e < 4; ++e) of[(tw * 16 + fq * 4 + e) * 132 + d * 16 + fr] = oc[e];
    }
  }
  __syncthreads();

  // ---- fused gated RMSNorm: x = rmsnorm((of + o1) * silu(z)) * w ----
  {
    const int t = tid >> 3, q8 = tid & 7;
    const u16* zp = qkvz + (size_t)(t0 + t) * NTOT + 8192 + hv * DKK + q8 * 16;
    float xv[16];
    float ss = 0.f;
#pragma unroll
    for (int i = 0; i < 2; ++i) {
      u16x8 zv = *(const u16x8*)(zp + i * 8);
#pragma unroll
      for (int e = 0; e < 8; ++e) {
        const int dv = q8 * 16 + i * 8 + e;
        float z = b2f(zv[e]);
        float o = of[t * 132 + dv] + b2f(o1l[sw16(dv, t, 64)]);
        float xx = o * (z / (1.f + __expf(-z)));
        xv[i * 8 + e] = xx;
        ss = fmaf(xx, xx, ss);
      }
    }
    ss += __shfl_xor(ss, 1);
    ss += __shfl_xor(ss, 2);
    ss += __shfl_xor(ss, 4);
    const float scl = rsqrtf(ss * (1.f / 128.f) + 1e-6f);
    u16* xo = x + (size_t)(t0 + t) * 4096 + hv * DKK + q8 * 16;
#pragma unroll
    for (int i = 0; i < 2; ++i) {
      u16x8 pk;
#pragma unroll
      for (int e = 0; e < 8; ++e) pk[e] = f2bf(xv[i * 8 + e] * scl * Lw[q8 * 16 + i * 8 + e]);
      *(u16x8*)(xo + i * 8) = pk;
    }
  }
}

extern "C" void kernel_launch(void* const* d_in, const int* in_sizes, int n_in,
                              void* d_out, int out_size, void* d_ws, size_t ws_size,
                              hipStream_t stream) {
  const float* h    = (const float*)d_in[0];
  const float* Wq   = (const float*)d_in[1];
  const float* Wk   = (const float*)d_in[2];
  const float* Wv   = (const float*)d_in[3];
  const float* Wz   = (const float*)d_in[4];
  const float* Wb   = (const float*)d_in[5];
  const float* Wa   = (const float*)d_in[6];
  const float* Alog = (const float*)d_in[7];
  const float* dtb  = (const float*)d_in[8];
  const float* nw   = (const float*)d_in[9];
  const float* Wo   = (const float*)d_in[10];
  char* ws = (char*)d_ws;
  u16* h_bf  = (u16*)(ws);
  u16* Bfq   = (u16*)(ws + 16777216ull);      // [768 j16][64 kt][512] bf16 = 50.33MB
  u16* UM    = (u16*)(ws);                    // [2048][64][256] bf16 = 64MB (after GEMM)
  u16* Bfo   = (u16*)(ws + 67108864ull);      // [128 j16][128 kt][512] bf16 = 16.8MB
  u16* qkvz  = (u16*)(ws + 83886080ull);
  u16* o1g   = (u16*)(ws + 184549376ull);     // [2048][128dv][64t] bf16 = 32MB
  u16* xbuf  = (u16*)(ws + 16777216ull);      // aliases Bfq (dead after qkvz GEMM)
  float* beta  = (float*)(ws + 218103808ull);
  float* g     = (float*)(ws + 218103808ull + 524288ull);
  float* cumL  = (float*)(ws + 218103808ull + 1048576ull);

  k_cvt<<<8192, 256, 0, stream>>>(h, h_bf, LTOK * DHID);
  k_trf<<<2048, 256, 0, stream>>>(Wq, Bfq, 2048, 64, 0);
  k_trf<<<2048, 256, 0, stream>>>(Wk, Bfq, 2048, 64, 128);
  k_trf<<<4096, 256, 0, stream>>>(Wv, Bfq, 4096, 64, 256);
  k_trf<<<4096, 256, 0, stream>>>(Wz, Bfq, 4096, 64, 512);
  k_trf<<<4096, 256, 0, stream>>>(Wo, Bfo, 2048, 128, 0);
  k_g256<u16, 2, 4><<<768, 512, 0, stream>>>(h_bf, Bfq, qkvz, 4096, 12288, 2048, 48);
  k_ba<<<1024, 256, 0, stream>>>(h, Wb, Wa, Alog, dtb, beta, g);
  k_l2n<<<32768, 256, 0, stream>>>(qkvz);
  k_r1<<<2048, 256, 0, stream>>>(qkvz, beta, g, UM, cumL);
  k_r2<<<128, 512, 0, stream>>>(qkvz, UM, cumL, o1g);
  k_r3<<<2048, 512, 0, stream>>>(qkvz, o1g, cumL, nw, xbuf);
  k_g256<float, 1, 2><<<512, 256, 0, stream>>>(xbuf, Bfo, (float*)d_out, 4096, 2048, 4096, 16);
}

// Round 15
// 807.984 us; speedup vs baseline: 1.0153x; 1.0056x over previous
//
#include <hip/hip_runtime.h>

#define LTOK 4096
#define DHID 2048
#define HKN  16
#define HVN  32
#define DKK  128
#define NTOT 12288

typedef unsigned short u16;
typedef __attribute__((ext_vector_type(8))) short short8;
typedef __attribute__((ext_vector_type(8))) unsigned short u16x8;
typedef __attribute__((ext_vector_type(4))) unsigned short u16x4;
typedef __attribute__((ext_vector_type(4))) float f32x4;

__device__ __forceinline__ float b2f(u16 u) {
  unsigned int x = ((unsigned int)u) << 16;
  return __builtin_bit_cast(float, x);
}
__device__ __forceinline__ u16 f2bf(float f) {
  unsigned int u = __builtin_bit_cast(unsigned int, f);
  u += 0x7FFFu + ((u >> 16) & 1u);
  return (u16)(u >> 16);
}

template<int C> __device__ __forceinline__ float dppmv(float x) {
  int i = __builtin_amdgcn_update_dpp(0, __builtin_bit_cast(int, x), C, 0xF, 0xF, true);
  return __builtin_bit_cast(float, i);
}
__device__ __forceinline__ float red16(float x) {
  x += dppmv<0xB1>(x);
  x += dppmv<0x4E>(x);
  x += dppmv<0x124>(x);
  x += dppmv<0x128>(x);
  return x;
}

__device__ __forceinline__ void gld16(const void* g, void* l) {
  __builtin_amdgcn_global_load_lds((const __attribute__((address_space(1))) void*)g,
                                   (__attribute__((address_space(3))) void*)l, 16, 0, 0);
}

// pinned-order LDS vector read (addr VGPR + compile-time byte offset)
template<int OFF> __device__ __forceinline__ short8 dsr(unsigned a) {
  short8 r;
  asm volatile("ds_read_b128 %0, %1 offset:%2" : "=v"(r) : "v"(a), "n"(OFF));
  return r;
}
// pinned-order global vector load to VGPR (B fragments; counted in vmcnt manually)
__device__ __forceinline__ short8 gldx4(const u16* p) {
  short8 r;
  asm volatile("global_load_dwordx4 %0, %1, off" : "=v"(r) : "v"(p));
  return r;
}
// keep a register value live (rule #17) - blocks allocator reuse until this point
#define KEEPV(x) asm volatile("" :: "v"(x))

// swizzled LDS element offsets (XOR row-bits into 16B-slot bits); byte^=((r&7)<<4)
__device__ __forceinline__ int sw16(int r, int c, int rowc) { return (r * rowc + c) ^ ((r & 7) << 3); }

__device__ __forceinline__ void cstore(u16* C, size_t i, float v) { C[i] = f2bf(v); }
__device__ __forceinline__ void cstore(float* C, size_t i, float v) { C[i] = v; }

// ---------------- fp32 -> bf16 convert ----------------
__global__ __launch_bounds__(256)
void k_cvt(const float* __restrict__ s, u16* __restrict__ d, int n) {
  const int i = (blockIdx.x * 256 + threadIdx.x) * 4;
  const float4 v = *(const float4*)(s + i);
  ushort4 o;
  o.x = f2bf(v.x); o.y = f2bf(v.y); o.z = f2bf(v.z); o.w = f2bf(v.w);
  *(ushort4*)(d + i) = o;
}

// ---------------- fp32 W[K][N] -> bf16 B-fragment-major layout ----------------
__global__ __launch_bounds__(256)
void k_trf(const float* __restrict__ W, u16* __restrict__ Bf, int Ncols, int nkt, int j16base) {
  const int wv = threadIdx.x >> 6, lane = threadIdx.x & 63;
  const int frag = blockIdx.x * 4 + wv;
  const int j16 = frag / nkt, kt = frag % nkt;
  const int r0 = kt * 32 + (lane >> 4) * 8;
  const int c = j16 * 16 + (lane & 15);
  u16x8 o;
#pragma unroll
  for (int e = 0; e < 8; ++e) o[e] = f2bf(W[(size_t)(r0 + e) * Ncols + c]);
  *(u16x8*)(Bf + ((size_t)(j16base + j16) * nkt + kt) * 512 + lane * 8) = o;
}

#define MFMA16(a, b, c) __builtin_amdgcn_mfma_f32_16x16x32_bf16(a, b, c, 0, 0, 0)

// ---------------- (NWM*128)xBN bf16 MFMA GEMM, B-from-global (flatmm) ----------------
// A: LDS-staged gld16 (4 bufs, depth-3, T2 source-swizzle) + 1-tile-ahead reg frag
// prefetch. B: fragment-major global, now TWO-tile-ahead: ITER(kt) consumes set kt&1
// and reloads it with B(kt+2) AFTER the MFMA block (old value dead) -> ~1.8 iters of
// latency slack for the L3/HBM-resident weight loads (was ~1 iter; R14 plateau at 51%
// MfmaUtil diagnosed as B-load latency > slack). FIFO audit: at ITER(kt)'s wait,
// in-flight = {S(kt+1),B(kt)},{S(kt+2),B(kt+1)},{S(kt+3)} = 6+2N; drain oldest 2+N
// -> vmcnt(N+4) unchanged.
template<typename OutT, int NWM, int NWN>
__global__ __launch_bounds__(NWM * 256, 2)
void k_g256(const u16* __restrict__ A, const u16* __restrict__ Bf, OutT* __restrict__ C,
            int M, int N, int K, int NT) {
  constexpr int BN = NWN * 64;
  constexpr int BUFE = NWM * 4096;           // A elems per LDS buffer
  __shared__ u16 Lds[4 * BUFE];
  const int tid = threadIdx.x;
  const int lane = tid & 63, w = tid >> 6;
  const int fr = lane & 15, fq = lane >> 4;
  const int wm = (w >> 2) * 128, wn = (w & 3) * (NWN * 16);
  const int nkt = K >> 5;
  const size_t sK = (size_t)K;

  // supertile + XCD-aware ordering (bijective; gridDim.x % 8 == 0)
  const int MT = gridDim.x / NT;
  const int nts = (NT < 16) ? NT : 16;
  const int per_super = MT * nts;
  const int super = blockIdx.x / per_super;
  const int within = blockIdx.x % per_super;
  const int mtg = MT >> 3;
  const int q = within >> 3;
  const int mt = (within & 7) * mtg + (q % mtg);
  const int nt = super * nts + q / mtg;

  // A staging: thread covers row tid/4 (+NWM*64 for 2nd load); k-slot pre-swizzled (T2)
  const int kslot = ((tid & 3) ^ ((tid >> 3) & 3)) * 8;
  const u16* aS = A + (size_t)(mt * (NWM * 128) + (tid >> 2)) * sK + kslot;

  // B fragment base pointers (compile-time-indexed -> registers, rule #20)
  const int jw = nt * (BN / 16) + (w & 3) * NWN;
  const u16* bp[NWN];
#pragma unroll
  for (int j = 0; j < NWN; ++j) bp[j] = Bf + ((size_t)(jw + j) * nkt) * 512 + lane * 8;

  f32x4 acc[8][NWN] = {};

  auto STAGE = [&](int kt_) {
    const int sk = (kt_ < nkt) ? kt_ : nkt - 1;
    u16* base = &Lds[(kt_ & 3) * BUFE];
    gld16(aS + (size_t)sk * 32, base + tid * 8);
    gld16(aS + (size_t)(NWM * 64) * sK + (size_t)sk * 32, base + NWM * 2048 + tid * 8);
  };

#define LOADB(bset, kt_) {                                                    \
    const int sk2 = ((kt_) < nkt) ? (kt_) : (nkt - 1);                        \
    _Pragma("unroll")                                                         \
    for (int j = 0; j < NWN; ++j) bset[j] = gldx4(bp[j] + (size_t)sk2 * 512); }

  const int akey = (fr >> 1) & 3;            // read-side swizzle key
  const unsigned ldsBase = (unsigned)(size_t)(__attribute__((address_space(3))) void*)&Lds[0];
  const unsigned aA0 = ldsBase + 2u * (unsigned)((wm + fr) * 32 + ((fq ^ akey) << 3));

  short8 afA[8], afB[8], bs0[NWN], bs1[NWN];

#define RD(afX, kt_) {                                                        \
    const unsigned aAr = aA0 + (unsigned)(((kt_) & 3) * (BUFE * 2));          \
    afX[0] = dsr<0>(aAr);    afX[1] = dsr<1024>(aAr);                         \
    afX[2] = dsr<2048>(aAr); afX[3] = dsr<3072>(aAr);                         \
    afX[4] = dsr<4096>(aAr); afX[5] = dsr<5120>(aAr);                         \
    afX[6] = dsr<6144>(aAr); afX[7] = dsr<7168>(aAr); }

  // prologue: A0..A2 staged, B0+B1 loaded, full drain, read A0 fragments
  STAGE(0); STAGE(1); STAGE(2);
  LOADB(bs0, 0)
  LOADB(bs1, 1)
  asm volatile("s_waitcnt vmcnt(0)" ::: "memory");
  __builtin_amdgcn_s_barrier();
  RD(afA, 0)
  asm volatile("s_waitcnt lgkmcnt(0)" ::: "memory");
  __builtin_amdgcn_sched_barrier(0);

  // per iter kt: STAGE(kt+3); vmcnt(N+4) -> {A(kt+1),B(kt)} landed; barrier; read
  // A(kt+1) frags into next set (no wait); MFMA(kt); then reload the just-consumed
  // B set with B(kt+2); lgkm(0)+sched_barrier (rule #18).
#define ITER(kt_, afC, bC, afN) {                                             \
    STAGE((kt_) + 3);                                                         \
    asm volatile("s_waitcnt vmcnt(%0)" :: "n"(NWN + 4) : "memory");           \
    __builtin_amdgcn_s_barrier();                                             \
    __builtin_amdgcn_sched_barrier(0);                                        \
    RD(afN, (kt_) + 1)                                                        \
    __builtin_amdgcn_sched_barrier(0);                                        \
    __builtin_amdgcn_s_setprio(1);                                            \
    _Pragma("unroll")                                                         \
    for (int i = 0; i < 8; ++i)                                               \
      _Pragma("unroll")                                                       \
      for (int j = 0; j < NWN; ++j)                                           \
        acc[i][j] = MFMA16(afC[i], bC[j], acc[i][j]);                         \
    __builtin_amdgcn_s_setprio(0);                                            \
    LOADB(bC, (kt_) + 2)                                                      \
    asm volatile("s_waitcnt lgkmcnt(0)" ::: "memory");                        \
    __builtin_amdgcn_sched_barrier(0); }

  for (int kt = 0; kt < nkt; kt += 2) {
    ITER(kt, afA, bs0, afB)
    ITER(kt + 1, afB, bs1, afA)
  }
#undef ITER
#undef RD
#undef LOADB

  // drain ALL in-flight vmem; keep unconsumed asm-load destinations alive past the
  // drain so the allocator cannot hand their registers to epilogue values while
  // loads are still landing (R11 fault). Both B sets have tail loads in flight.
  asm volatile("s_waitcnt vmcnt(0) lgkmcnt(0)" ::: "memory");
  __builtin_amdgcn_sched_barrier(0);
  KEEPV(bs0[0]); KEEPV(bs0[1]);
  if constexpr (NWN == 4) { KEEPV(bs0[2]); KEEPV(bs0[3]); }
  KEEPV(bs1[0]); KEEPV(bs1[1]);
  if constexpr (NWN == 4) { KEEPV(bs1[2]); KEEPV(bs1[3]); }
  KEEPV(afA[0]); KEEPV(afA[1]); KEEPV(afA[2]); KEEPV(afA[3]);
  KEEPV(afA[4]); KEEPV(afA[5]); KEEPV(afA[6]); KEEPV(afA[7]);
  KEEPV(afB[0]); KEEPV(afB[1]); KEEPV(afB[2]); KEEPV(afB[3]);
  KEEPV(afB[4]); KEEPV(afB[5]); KEEPV(afB[6]); KEEPV(afB[7]);

  const int r0 = mt * (NWM * 128) + wm + fq * 4;
  const int c0 = nt * BN + wn + fr;
#pragma unroll
  for (int i = 0; i < 8; ++i)
#pragma unroll
    for (int j = 0; j < NWN; ++j)
#pragma unroll
      for (int e = 0; e < 4; ++e)
        cstore(C, (size_t)(r0 + i * 16 + e) * N + c0 + j * 16, acc[i][j][e]);
}

// ---------------- beta / g (log-decay): [L,2048]@[2048,32] x2 + activations ----------------
__global__ __launch_bounds__(256)
void k_ba(const float* __restrict__ h, const float* __restrict__ Wb, const float* __restrict__ Wa,
          const float* __restrict__ A_log, const float* __restrict__ dtb,
          float* __restrict__ beta, float* __restrict__ g_out) {
  const int w = threadIdx.x >> 6, lane = threadIdx.x & 63;
  const int t = blockIdx.x * 4 + w;
  const int j = lane & 31;
  const bool isB = lane < 32;
  const float* __restrict__ hr = h + (size_t)t * DHID;
  const float* Wc = isB ? Wb : Wa;
  float acc = 0.f;
  for (int kk = 0; kk < DHID; ++kk) acc = fmaf(hr[kk], Wc[(size_t)kk * HVN + j], acc);
  if (isB) {
    beta[(size_t)t * HVN + j] = 1.f / (1.f + expf(-acc));
  } else {
    float xx = acc + dtb[j];
    float sp = (xx > 20.f) ? xx : log1pf(expf(xx));
    g_out[(size_t)t * HVN + j] = -expf(A_log[j]) * sp;   // g = log(decay) <= 0
  }
}

// ---------------- in-place l2norm of q (scaled) and k heads ----------------
__global__ __launch_bounds__(256)
void k_l2n(u16* __restrict__ qkvz) {
  const int w = threadIdx.x >> 6, lane = threadIdx.x & 63;
  const int r = blockIdx.x * 4 + w;
  const int isK = r >> 16;
  const int rr = r & 65535;
  const int t = rr >> 4, hd = rr & 15;
  u16* p = qkvz + (size_t)t * NTOT + isK * 2048 + hd * DKK + lane * 2;
  float a = b2f(p[0]), b = b2f(p[1]);
  float ss = a * a + b * b;
  ss = red16(ss);
  ss += __shfl_xor(ss, 16);
  ss += __shfl_xor(ss, 32);
  const float sc = rsqrtf(ss + 1e-6f) * (isK ? 1.f : 0.08838834764831845f);
  p[0] = f2bf(a * sc); p[1] = f2bf(b * sc);
}

// ---------------- chunk solve (parallel): per (hv, chunk n) ----------------
__global__ __launch_bounds__(256)
void k_r1(const u16* __restrict__ qkvz, const float* __restrict__ beta_g,
          const float* __restrict__ g_g, u16* __restrict__ UM_g, float* __restrict__ cumL_g) {
  const int pair = blockIdx.x;          // hv*64 + n
  const int hv = pair >> 6, n = pair & 63;
  const int hk = hv >> 1;
  const int t0 = n * 64;
  const int tid = threadIdx.x, lane = tid & 63, wv = tid >> 6;
  const int fr = lane & 15, fq = lane >> 4;

  __shared__ __align__(16) u16 Xb[256 * 64];
  __shared__ __align__(16) u16 Dbuf0[64 * 64 * 2];
  __shared__ __align__(16) u16 Dbuf1[64 * 64 * 2];
  __shared__ float Lc[64];
  __shared__ float Bc[64];
  u16* Kl = Dbuf0;

  const int j = tid & 63, h = tid >> 6;
  const u16* kg = qkvz + (size_t)(t0 + j) * NTOT + 2048 + hk * DKK + h * 32;
  const u16* vg = qkvz + (size_t)(t0 + j) * NTOT + 4096 + hv * DKK + h * 32;
  u16x8 kv[4], vv[4];
#pragma unroll
  for (int i = 0; i < 4; ++i) { kv[i] = *(const u16x8*)(kg + i * 8); vv[i] = *(const u16x8*)(vg + i * 8); }
  if (tid < 64) {
    Lc[tid] = g_g[(size_t)(t0 + tid) * HVN + hv];
    Bc[tid] = beta_g[(size_t)(t0 + tid) * HVN + hv];
  }
#pragma unroll
  for (int i = 0; i < 4; ++i) *(u16x8*)&Kl[sw16(j, h * 32 + i * 8, 128)] = kv[i];
  __syncthreads();
  if (tid == 0) { float a = 0.f; for (int t = 0; t < 64; ++t) { a += Lc[t]; Lc[t] = a; } }
  __syncthreads();
  if (tid < 64) cumL_g[(size_t)pair * 64 + tid] = Lc[tid];

  {
    const float bj = Bc[j];
    const float mj = bj * __expf(Lc[j]);
#pragma unroll
    for (int i = 0; i < 4; ++i)
#pragma unroll
      for (int e = 0; e < 8; ++e) {
        int c = h * 32 + i * 8 + e;
        Xb[sw16(c, j, 64)] = f2bf(bj * b2f(vv[i][e]));
        Xb[sw16(128 + c, j, 64)] = f2bf(mj * b2f(kv[i][e]));
      }
  }
  f32x4 kk[4] = {};
#pragma unroll
  for (int ks = 0; ks < 4; ++ks) {
    short8 afr = *(const short8*)&Kl[sw16(wv * 16 + fr, ks * 32 + fq * 8, 128)];
#pragma unroll
    for (int ct = 0; ct < 4; ++ct) {
      short8 bfr = *(const short8*)&Kl[sw16(ct * 16 + fr, ks * 32 + fq * 8, 128)];
      kk[ct] = MFMA16(afr, bfr, kk[ct]);
    }
  }
  __syncthreads();

  f32x4 acc[16];
#pragma unroll
  for (int ct = 0; ct < 16; ++ct) {
    u16x4 xi = *(const u16x4*)&Xb[sw16(ct * 16 + fr, wv * 16 + fq * 4, 64)];
    acc[ct][0] = b2f(xi[0]); acc[ct][1] = b2f(xi[1]); acc[ct][2] = b2f(xi[2]); acc[ct][3] = b2f(xi[3]);
  }
#pragma unroll
  for (int ct = 0; ct < 4; ++ct) {
    const int s = ct * 16 + fr;
    u16x4 pk;
#pragma unroll
    for (int e = 0; e < 4; ++e) {
      const int t = wv * 16 + fq * 4 + e;
      float v = (s < t) ? -Bc[t] * __expf(Lc[t] - Lc[s]) * kk[ct][e] : 0.f;
      pk[e] = f2bf(v);
      Dbuf0[sw16(t, s, 64)] = pk[e];
    }
    *(u16x4*)&Dbuf0[4096 + sw16(s, wv * 16 + fq * 4, 64)] = pk;
  }
  __syncthreads();

  u16* DA = Dbuf0;
  u16* DB = Dbuf1;
  for (int stg = 0; stg < 6; ++stg) {
    u16* Dr = DA;
    u16* Dc = DA + 4096;
    short8 da0 = *(const short8*)&Dr[sw16(wv * 16 + fr, 0 + fq * 8, 64)];
    short8 da1 = *(const short8*)&Dr[sw16(wv * 16 + fr, 32 + fq * 8, 64)];
#pragma unroll
    for (int ct = 0; ct < 16; ++ct) {
      short8 b0 = *(const short8*)&Xb[sw16(ct * 16 + fr, 0 + fq * 8, 64)];
      short8 b1 = *(const short8*)&Xb[sw16(ct * 16 + fr, 32 + fq * 8, 64)];
      acc[ct] = MFMA16(da0, b0, acc[ct]);
      acc[ct] = MFMA16(da1, b1, acc[ct]);
    }
    f32x4 sq[4] = {};
    if (stg < 5) {
#pragma unroll
      for (int ct = 0; ct < 4; ++ct) {
        short8 sb0 = *(const short8*)&Dc[sw16(ct * 16 + fr, 0 + fq * 8, 64)];
        short8 sb1 = *(const short8*)&Dc[sw16(ct * 16 + fr, 32 + fq * 8, 64)];
        sq[ct] = MFMA16(da0, sb0, sq[ct]);
        sq[ct] = MFMA16(da1, sb1, sq[ct]);
      }
    }
    __syncthreads();
#pragma unroll
    for (int ct = 0; ct < 16; ++ct) {
      u16x4 pk;
      pk[0] = f2bf(acc[ct][0]); pk[1] = f2bf(acc[ct][1]); pk[2] = f2bf(acc[ct][2]); pk[3] = f2bf(acc[ct][3]);
      *(u16x4*)&Xb[sw16(ct * 16 + fr, wv * 16 + fq * 4, 64)] = pk;
    }
    if (stg < 5) {
#pragma unroll
      for (int ct = 0; ct < 4; ++ct) {
        u16x4 pk;
        pk[0] = f2bf(sq[ct][0]); pk[1] = f2bf(sq[ct][1]); pk[2] = f2bf(sq[ct][2]); pk[3] = f2bf(sq[ct][3]);
        *(u16x4*)&(DB + 4096)[sw16(ct * 16 + fr, wv * 16 + fq * 4, 64)] = pk;
#pragma unroll
        for (int e = 0; e < 4; ++e) DB[sw16(wv * 16 + fq * 4 + e, ct * 16 + fr, 64)] = pk[e];
      }
    }
    __syncthreads();
    u16* tmp = DA; DA = DB; DB = tmp;
  }

#pragma unroll
  for (int ct = 0; ct < 16; ++ct) {
    const int c = ct * 16 + fr;
#pragma unroll
    for (int e = 0; e < 4; ++e) {
      const int t = wv * 16 + fq * 4 + e;
      float v = acc[ct][e];
      if (ct >= 8) v = -v;
      UM_g[((size_t)pair * 64 + t) * 256 + c] = f2bf(v);
    }
  }
}

// ---------------- sequential chunk scan: 128 blocks = (hv, dv-quarter cs) ----------------
__global__ __launch_bounds__(512)
void k_r2(u16* __restrict__ qkvz, const u16* __restrict__ UM_g,
          const float* __restrict__ cumL_g, u16* __restrict__ o1_g) {
  const int hv = blockIdx.x >> 2, cs = blockIdx.x & 3;
  const int hk = hv >> 1;
  const int tid = threadIdx.x, lane = tid & 63, w = tid >> 6;   // 8 waves
  const int fr = lane & 15, fq = lane >> 4;
  const int j = tid & 63, h = tid >> 6;                          // staging coords
  const int tw = w & 3, dwv = w >> 2;                            // ph1 tile coords

  __shared__ __align__(16) u16 Ml2[2][8192];   // -M rows [t][dk] swz
  __shared__ __align__(16) u16 Ql2[2][8192];   // q rows
  __shared__ __align__(16) u16 Kt2[2][8192];   // Kbar^T [dk][t] swz
  __shared__ __align__(16) u16 dT[2048];       // delta^T [32 ldv][64 t] swz
  __shared__ __align__(16) u16 SbT[4096];      // S^T [32 ldv][128 dk] swz
  __shared__ __align__(16) u16 o1b[2048];      // o1 [32 ldv][64 t] swz
  __shared__ float Lc2[2][64];

  f32x4 sacc[2];
#pragma unroll
  for (int d = 0; d < 2; ++d) sacc[d] = (f32x4){0.f, 0.f, 0.f, 0.f};
  for (int i = tid; i < 4096; i += 512) SbT[i] = 0;

  u16x8 pQ0, pQ1, pK0, pK1, pM0, pM1;
  u16 pUn0, pUn1, pUn2, pUn3, pUc0, pUc1, pUc2, pUc3;
  float pL, pL63;

#define PREF(nn) {                                                            \
    const int nc = ((nn) < 64) ? (nn) : 63;                                   \
    const int pr = hv * 64 + nc; const int tt0 = nc * 64;                     \
    const u16* qg = qkvz + (size_t)(tt0 + j) * NTOT + hk * DKK + h * 16;      \
    pQ0 = *(const u16x8*)qg;          pQ1 = *(const u16x8*)(qg + 8);          \
    pK0 = *(const u16x8*)(qg + 2048); pK1 = *(const u16x8*)(qg + 2056);       \
    const u16* mg = UM_g + ((size_t)pr * 64 + j) * 256;                       \
    pM0 = *(const u16x8*)(mg + 128 + h * 16);                                 \
    pM1 = *(const u16x8*)(mg + 136 + h * 16);                                 \
    const u16* ug = UM_g + ((size_t)pr * 64 + tw * 16 + fq * 4) * 256         \
                    + cs * 32 + dwv * 16 + fr;                                \
    pUn0 = ug[0]; pUn1 = ug[256]; pUn2 = ug[512]; pUn3 = ug[768];             \
    pL = cumL_g[(size_t)pr * 64 + j]; pL63 = cumL_g[(size_t)pr * 64 + 63]; }

#define STW(b) {                                                              \
    *(u16x8*)&Ql2[b][sw16(j, h * 16, 128)] = pQ0;                             \
    *(u16x8*)&Ql2[b][sw16(j, h * 16 + 8, 128)] = pQ1;                         \
    *(u16x8*)&Ml2[b][sw16(j, h * 16, 128)] = pM0;                             \
    *(u16x8*)&Ml2[b][sw16(j, h * 16 + 8, 128)] = pM1;                         \
    const float scK = __expf(pL63 - pL);                                      \
    _Pragma("unroll")                                                         \
    for (int e = 0; e < 8; ++e) {                                             \
      Kt2[b][sw16(h * 16 + e, j, 64)] = f2bf(scK * b2f(pK0[e]));              \
      Kt2[b][sw16(h * 16 + 8 + e, j, 64)] = f2bf(scK * b2f(pK1[e]));          \
    }                                                                         \
    if (h == 0) Lc2[b][j] = pL; }

  PREF(0)
  STW(0)
  __syncthreads();

  for (int n = 0; n < 64; ++n) {
    const int cur = n & 1;
    const int pair = hv * 64 + n, t0 = n * 64;
    pUc0 = pUn0; pUc1 = pUn1; pUc2 = pUn2; pUc3 = pUn3;
    const float curL63 = pL63;
    PREF(n + 1)

    // ---- ph1: delta = U + (-M)@S ; o1 = e^{Lt}(Q@S) ----
    short8 amf[4], aqf[4];
#pragma unroll
    for (int ks = 0; ks < 4; ++ks) {
      amf[ks] = *(const short8*)&Ml2[cur][sw16(tw * 16 + fr, ks * 32 + fq * 8, 128)];
      aqf[ks] = *(const short8*)&Ql2[cur][sw16(tw * 16 + fr, ks * 32 + fq * 8, 128)];
    }
    float el[4];
#pragma unroll
    for (int e = 0; e < 4; ++e) el[e] = __expf(Lc2[cur][tw * 16 + fq * 4 + e]);
    {
      f32x4 dc;
      dc[0] = b2f(pUc0); dc[1] = b2f(pUc1); dc[2] = b2f(pUc2); dc[3] = b2f(pUc3);
      f32x4 oc = {};
#pragma unroll
      for (int ks = 0; ks < 4; ++ks) {
        short8 bs = *(const short8*)&SbT[sw16(dwv * 16 + fr, ks * 32 + fq * 8, 128)];
        dc = MFMA16(amf[ks], bs, dc);
        oc = MFMA16(aqf[ks], bs, oc);
      }
      u16x4 pkd;
      pkd[0] = f2bf(dc[0]); pkd[1] = f2bf(dc[1]); pkd[2] = f2bf(dc[2]); pkd[3] = f2bf(dc[3]);
      *(u16x4*)&dT[sw16(dwv * 16 + fr, tw * 16 + fq * 4, 64)] = pkd;
      u16x4 pko;
#pragma unroll
      for (int e = 0; e < 4; ++e) pko[e] = f2bf(oc[e] * el[e]);
      *(u16x4*)&o1b[sw16(dwv * 16 + fr, tw * 16 + fq * 4, 64)] = pko;
    }
    __syncthreads();

    // ---- ph2: flush delta/o1 to global; stage next; S-update ----
    {
      const int i = tid * 4;
      u16x4 vd = *(const u16x4*)&dT[i];
      const int f = cs * 2048 + i;
      *(u16x4*)(qkvz + (size_t)(t0 + (f >> 7)) * NTOT + 4096 + hv * DKK + (f & 127)) = vd;
      u16x4 vo = *(const u16x4*)&o1b[i];
      *(u16x4*)(o1_g + (size_t)pair * 8192 + cs * 2048 + i) = vo;
    }
    STW(cur ^ 1)
    {
      const float eC = __expf(curL63);
      short8 ak0 = *(const short8*)&Kt2[cur][sw16(w * 16 + fr, fq * 8, 64)];
      short8 ak1 = *(const short8*)&Kt2[cur][sw16(w * 16 + fr, 32 + fq * 8, 64)];
#pragma unroll
      for (int d = 0; d < 2; ++d) {
        short8 bd0 = *(const short8*)&dT[sw16(d * 16 + fr, fq * 8, 64)];
        short8 bd1 = *(const short8*)&dT[sw16(d * 16 + fr, 32 + fq * 8, 64)];
        f32x4 sa = sacc[d];
#pragma unroll
        for (int e = 0; e < 4; ++e) sa[e] *= eC;
        sa = MFMA16(ak0, bd0, sa);
        sa = MFMA16(ak1, bd1, sa);
        sacc[d] = sa;
        u16x4 pk;
        pk[0] = f2bf(sa[0]); pk[1] = f2bf(sa[1]); pk[2] = f2bf(sa[2]); pk[3] = f2bf(sa[3]);
        *(u16x4*)&SbT[sw16(d * 16 + fr, w * 16 + fq * 4, 128)] = pk;
      }
    }
    __syncthreads();
  }
#undef PREF
#undef STW
}

// ---------------- parallel epilogue: o = o1 + G@delta, fused gated RMSNorm ----------------
__global__ __launch_bounds__(512)
void k_r3(const u16* __restrict__ qkvz, const u16* __restrict__ o1_g,
          const float* __restrict__ cumL_g, const float* __restrict__ nw,
          u16* __restrict__ x) {
  const int pair = blockIdx.x, hv = pair >> 6, n = pair & 63, hk = hv >> 1, t0 = n * 64;
  const int tid = threadIdx.x, lane = tid & 63, w = tid >> 6;
  const int fr = lane & 15, fq = lane >> 4;
  const int j = tid & 63, h = tid >> 6;   // h 0..7

  __shared__ __align__(16) u16 Ql[8192];
  __shared__ __align__(16) u16 Kl[8192];
  __shared__ __align__(16) u16 Gl[4096];
  __shared__ __align__(16) u16 dTl[8192];
  __shared__ __align__(16) u16 o1l[8192];      // o1 [dv][t] swz (raw block from k_r2)
  __shared__ __align__(16) float of[64 * 132];
  __shared__ float Lc[64];
  __shared__ float Lw[128];

  {
    const u16* qg = qkvz + (size_t)(t0 + j) * NTOT + hk * DKK + h * 16;
    u16x8 q0 = *(const u16x8*)qg, q1 = *(const u16x8*)(qg + 8);
    u16x8 k0 = *(const u16x8*)(qg + 2048), k1 = *(const u16x8*)(qg + 2056);
    *(u16x8*)&Ql[sw16(j, h * 16, 128)] = q0;
    *(u16x8*)&Ql[sw16(j, h * 16 + 8, 128)] = q1;
    *(u16x8*)&Kl[sw16(j, h * 16, 128)] = k0;
    *(u16x8*)&Kl[sw16(j, h * 16 + 8, 128)] = k1;
  }
#pragma unroll
  for (int it = 0; it < 2; ++it) {
    const int f = ((w * 2 + it) * 64 + lane) * 8;
    gld16(qkvz + (size_t)(t0 + (f >> 7)) * NTOT + 4096 + hv * DKK + (f & 127),
          (char*)dTl + (w * 2 + it) * 1024);
    gld16(o1_g + (size_t)pair * 8192 + f, (char*)o1l + (w * 2 + it) * 1024);
  }
  if (tid < 64) Lc[tid] = cumL_g[(size_t)pair * 64 + tid];
  if (tid < 128) Lw[tid] = nw[tid];
  __syncthreads();

  // ---- G = tril(e^{Lt-Ls} * QK^T) ----
  const int tw = w & 3, sp = (w >> 2) * 2;
  {
    f32x4 kk0 = {}, kk1 = {};
#pragma unroll
    for (int ks = 0; ks < 4; ++ks) {
      short8 aq = *(const short8*)&Ql[sw16(tw * 16 + fr, ks * 32 + fq * 8, 128)];
      short8 b0 = *(const short8*)&Kl[sw16(sp * 16 + fr, ks * 32 + fq * 8, 128)];
      short8 b1 = *(const short8*)&Kl[sw16((sp + 1) * 16 + fr, ks * 32 + fq * 8, 128)];
      kk0 = MFMA16(aq, b0, kk0);
      kk1 = MFMA16(aq, b1, kk1);
    }
#pragma unroll
    for (int e = 0; e < 4; ++e) {
      const int t = tw * 16 + fq * 4 + e;
      const float Lt = Lc[t];
      const int s0 = sp * 16 + fr, s1 = s0 + 16;
      Gl[sw16(t, s0, 64)] = f2bf((s0 <= t) ? kk0[e] * __expf(Lt - Lc[s0]) : 0.f);
      Gl[sw16(t, s1, 64)] = f2bf((s1 <= t) ? kk1[e] * __expf(Lt - Lc[s1]) : 0.f);
    }
  }
  __syncthreads();

  // ---- o = G@delta ----
  {
    short8 ag0 = *(const short8*)&Gl[sw16(tw * 16 + fr, fq * 8, 64)];
    short8 ag1 = *(const short8*)&Gl[sw16(tw * 16 + fr, 32 + fq * 8, 64)];
#pragma unroll
    for (int dd = 0; dd < 4; ++dd) {
      const int d = (w >> 2) * 4 + dd;
      short8 bd0 = *(const short8*)&dTl[sw16(d * 16 + fr, fq * 8, 64)];
      short8 bd1 = *(const short8*)&dTl[sw16(d * 16 + fr, 32 + fq * 8, 64)];
      f32x4 oc = {};
      oc = MFMA16(ag0, bd0, oc);
      oc = MFMA16(ag1, bd1, oc);
#pragma unroll
      for (int e = 0; e < 4; ++e) of[(tw * 16 + fq * 4 + e) * 132 + d * 16 + fr] = oc[e];
    }
  }
  __syncthreads();

  // ---- fused gated RMSNorm: x = rmsnorm((of + o1) * silu(z)) * w ----
  {
    const int t = tid >> 3, q8 = tid & 7;
    const u16* zp = qkvz + (size_t)(t0 + t) * NTOT + 8192 + hv * DKK + q8 * 16;
    float xv[16];
    float ss = 0.f;
#pragma unroll
    for (int i = 0; i < 2; ++i) {
      u16x8 zv = *(const u16x8*)(zp + i * 8);
#pragma unroll
      for (int e = 0; e < 8; ++e) {
        const int dv = q8 * 16 + i * 8 + e;
        float z = b2f(zv[e]);
        float o = of[t * 132 + dv] + b2f(o1l[sw16(dv, t, 64)]);
        float xx = o * (z / (1.f + __expf(-z)));
        xv[i * 8 + e] = xx;
        ss = fmaf(xx, xx, ss);
      }
    }
    ss += __shfl_xor(ss, 1);
    ss += __shfl_xor(ss, 2);
    ss += __shfl_xor(ss, 4);
    const float scl = rsqrtf(ss * (1.f / 128.f) + 1e-6f);
    u16* xo = x + (size_t)(t0 + t) * 4096 + hv * DKK + q8 * 16;
#pragma unroll
    for (int i = 0; i < 2; ++i) {
      u16x8 pk;
#pragma unroll
      for (int e = 0; e < 8; ++e) pk[e] = f2bf(xv[i * 8 + e] * scl * Lw[q8 * 16 + i * 8 + e]);
      *(u16x8*)(xo + i * 8) = pk;
    }
  }
}

extern "C" void kernel_launch(void* const* d_in, const int* in_sizes, int n_in,
                              void* d_out, int out_size, void* d_ws, size_t ws_size,
                              hipStream_t stream) {
  const float* h    = (const float*)d_in[0];
  const float* Wq   = (const float*)d_in[1];
  const float* Wk   = (const float*)d_in[2];
  const float* Wv   = (const float*)d_in[3];
  const float* Wz   = (const float*)d_in[4];
  const float* Wb   = (const float*)d_in[5];
  const float* Wa   = (const float*)d_in[6];
  const float* Alog = (const float*)d_in[7];
  const float* dtb  = (const float*)d_in[8];
  const float* nw   = (const float*)d_in[9];
  const float* Wo   = (const float*)d_in[10];
  char* ws = (char*)d_ws;
  u16* h_bf  = (u16*)(ws);
  u16* Bfq   = (u16*)(ws + 16777216ull);      // [768 j16][64 kt][512] bf16 = 50.33MB
  u16* UM    = (u16*)(ws);                    // [2048][64][256] bf16 = 64MB (after GEMM)
  u16* Bfo   = (u16*)(ws + 67108864ull);      // [128 j16][128 kt][512] bf16 = 16.8MB
  u16* qkvz  = (u16*)(ws + 83886080ull);
  u16* o1g   = (u16*)(ws + 184549376ull);     // [2048][128dv][64t] bf16 = 32MB
  u16* xbuf  = (u16*)(ws + 16777216ull);      // aliases Bfq (dead after qkvz GEMM)
  float* beta  = (float*)(ws + 218103808ull);
  float* g     = (float*)(ws + 218103808ull + 524288ull);
  float* cumL  = (float*)(ws + 218103808ull + 1048576ull);

  k_cvt<<<8192, 256, 0, stream>>>(h, h_bf, LTOK * DHID);
  k_trf<<<2048, 256, 0, stream>>>(Wq, Bfq, 2048, 64, 0);
  k_trf<<<2048, 256, 0, stream>>>(Wk, Bfq, 2048, 64, 128);
  k_trf<<<4096, 256, 0, stream>>>(Wv, Bfq, 4096, 64, 256);
  k_trf<<<4096, 256, 0, stream>>>(Wz, Bfq, 4096, 64, 512);
  k_trf<<<4096, 256, 0, stream>>>(Wo, Bfo, 2048, 128, 0);
  k_g256<u16, 2, 4><<<768, 512, 0, stream>>>(h_bf, Bfq, qkvz, 4096, 12288, 2048, 48);
  k_ba<<<1024, 256, 0, stream>>>(h, Wb, Wa, Alog, dtb, beta, g);
  k_l2n<<<32768, 256, 0, stream>>>(qkvz);
  k_r1<<<2048, 256, 0, stream>>>(qkvz, beta, g, UM, cumL);
  k_r2<<<128, 512, 0, stream>>>(qkvz, UM, cumL, o1g);
  k_r3<<<2048, 512, 0, stream>>>(qkvz, o1g, cumL, nw, xbuf);
  k_g256<float, 1, 2><<<512, 256, 0, stream>>>(xbuf, Bfo, (float*)d_out, 4096, 2048, 4096, 16);
}

// Round 16
// 803.742 us; speedup vs baseline: 1.0207x; 1.0053x over previous
//
#include <hip/hip_runtime.h>

#define LTOK 4096
#define DHID 2048
#define HKN  16
#define HVN  32
#define DKK  128
#define NTOT 12288

typedef unsigned short u16;
typedef __attribute__((ext_vector_type(8))) short short8;
typedef __attribute__((ext_vector_type(8))) unsigned short u16x8;
typedef __attribute__((ext_vector_type(4))) unsigned short u16x4;
typedef __attribute__((ext_vector_type(4))) float f32x4;

__device__ __forceinline__ float b2f(u16 u) {
  unsigned int x = ((unsigned int)u) << 16;
  return __builtin_bit_cast(float, x);
}
__device__ __forceinline__ u16 f2bf(float f) {
  unsigned int u = __builtin_bit_cast(unsigned int, f);
  u += 0x7FFFu + ((u >> 16) & 1u);
  return (u16)(u >> 16);
}

template<int C> __device__ __forceinline__ float dppmv(float x) {
  int i = __builtin_amdgcn_update_dpp(0, __builtin_bit_cast(int, x), C, 0xF, 0xF, true);
  return __builtin_bit_cast(float, i);
}
__device__ __forceinline__ float red16(float x) {
  x += dppmv<0xB1>(x);
  x += dppmv<0x4E>(x);
  x += dppmv<0x124>(x);
  x += dppmv<0x128>(x);
  return x;
}

__device__ __forceinline__ void gld16(const void* g, void* l) {
  __builtin_amdgcn_global_load_lds((const __attribute__((address_space(1))) void*)g,
                                   (__attribute__((address_space(3))) void*)l, 16, 0, 0);
}

// pinned-order LDS vector read (addr VGPR + compile-time byte offset)
template<int OFF> __device__ __forceinline__ short8 dsr(unsigned a) {
  short8 r;
  asm volatile("ds_read_b128 %0, %1 offset:%2" : "=v"(r) : "v"(a), "n"(OFF));
  return r;
}
// pinned-order global vector load to VGPR (B fragments; counted in vmcnt manually)
__device__ __forceinline__ short8 gldx4(const u16* p) {
  short8 r;
  asm volatile("global_load_dwordx4 %0, %1, off" : "=v"(r) : "v"(p));
  return r;
}
// keep a register value live (rule #17) - blocks allocator reuse until this point
#define KEEPV(x) asm volatile("" :: "v"(x))

// swizzled LDS element offsets (XOR row-bits into 16B-slot bits); byte^=((r&7)<<4)
__device__ __forceinline__ int sw16(int r, int c, int rowc) { return (r * rowc + c) ^ ((r & 7) << 3); }

__device__ __forceinline__ void cstore(u16* C, size_t i, float v) { C[i] = f2bf(v); }
__device__ __forceinline__ void cstore(float* C, size_t i, float v) { C[i] = v; }

// ---------------- fp32 -> bf16 convert ----------------
__global__ __launch_bounds__(256)
void k_cvt(const float* __restrict__ s, u16* __restrict__ d, int n) {
  const int i = (blockIdx.x * 256 + threadIdx.x) * 4;
  const float4 v = *(const float4*)(s + i);
  ushort4 o;
  o.x = f2bf(v.x); o.y = f2bf(v.y); o.z = f2bf(v.z); o.w = f2bf(v.w);
  *(ushort4*)(d + i) = o;
}

// ---------------- fp32 W[K][N] -> bf16 B-fragment-major layout ----------------
__global__ __launch_bounds__(256)
void k_trf(const float* __restrict__ W, u16* __restrict__ Bf, int Ncols, int nkt, int j16base) {
  const int wv = threadIdx.x >> 6, lane = threadIdx.x & 63;
  const int frag = blockIdx.x * 4 + wv;
  const int j16 = frag / nkt, kt = frag % nkt;
  const int r0 = kt * 32 + (lane >> 4) * 8;
  const int c = j16 * 16 + (lane & 15);
  u16x8 o;
#pragma unroll
  for (int e = 0; e < 8; ++e) o[e] = f2bf(W[(size_t)(r0 + e) * Ncols + c]);
  *(u16x8*)(Bf + ((size_t)(j16base + j16) * nkt + kt) * 512 + lane * 8) = o;
}

#define MFMA16(a, b, c) __builtin_amdgcn_mfma_f32_16x16x32_bf16(a, b, c, 0, 0, 0)

// ---------------- (NWM*128)xBN bf16 MFMA GEMM, B-from-global (flatmm) ----------------
template<typename OutT, int NWM, int NWN>
__global__ __launch_bounds__(NWM * 256, 2)
void k_g256(const u16* __restrict__ A, const u16* __restrict__ Bf, OutT* __restrict__ C,
            int M, int N, int K, int NT) {
  constexpr int BN = NWN * 64;
  constexpr int BUFE = NWM * 4096;           // A elems per LDS buffer
  __shared__ u16 Lds[4 * BUFE];
  const int tid = threadIdx.x;
  const int lane = tid & 63, w = tid >> 6;
  const int fr = lane & 15, fq = lane >> 4;
  const int wm = (w >> 2) * 128, wn = (w & 3) * (NWN * 16);
  const int nkt = K >> 5;
  const size_t sK = (size_t)K;

  // supertile + XCD-aware ordering (bijective; gridDim.x % 8 == 0)
  const int MT = gridDim.x / NT;
  const int nts = (NT < 16) ? NT : 16;
  const int per_super = MT * nts;
  const int super = blockIdx.x / per_super;
  const int within = blockIdx.x % per_super;
  const int mtg = MT >> 3;
  const int q = within >> 3;
  const int mt = (within & 7) * mtg + (q % mtg);
  const int nt = super * nts + q / mtg;

  // A staging: thread covers row tid/4 (+NWM*64 for 2nd load); k-slot pre-swizzled (T2)
  const int kslot = ((tid & 3) ^ ((tid >> 3) & 3)) * 8;
  const u16* aS = A + (size_t)(mt * (NWM * 128) + (tid >> 2)) * sK + kslot;

  // B fragment base pointers (compile-time-indexed -> registers, rule #20)
  const int jw = nt * (BN / 16) + (w & 3) * NWN;
  const u16* bp[NWN];
#pragma unroll
  for (int j = 0; j < NWN; ++j) bp[j] = Bf + ((size_t)(jw + j) * nkt) * 512 + lane * 8;

  f32x4 acc[8][NWN] = {};

  auto STAGE = [&](int kt_) {
    const int sk = (kt_ < nkt) ? kt_ : nkt - 1;
    u16* base = &Lds[(kt_ & 3) * BUFE];
    gld16(aS + (size_t)sk * 32, base + tid * 8);
    gld16(aS + (size_t)(NWM * 64) * sK + (size_t)sk * 32, base + NWM * 2048 + tid * 8);
  };

#define LOADB(bset, kt_) {                                                    \
    const int sk2 = ((kt_) < nkt) ? (kt_) : (nkt - 1);                        \
    _Pragma("unroll")                                                         \
    for (int j = 0; j < NWN; ++j) bset[j] = gldx4(bp[j] + (size_t)sk2 * 512); }

  const int akey = (fr >> 1) & 3;            // read-side swizzle key
  const unsigned ldsBase = (unsigned)(size_t)(__attribute__((address_space(3))) void*)&Lds[0];
  const unsigned aA0 = ldsBase + 2u * (unsigned)((wm + fr) * 32 + ((fq ^ akey) << 3));

  short8 afA[8], afB[8], bs0[NWN], bs1[NWN];

#define RD(afX, kt_) {                                                        \
    const unsigned aAr = aA0 + (unsigned)(((kt_) & 3) * (BUFE * 2));          \
    afX[0] = dsr<0>(aAr);    afX[1] = dsr<1024>(aAr);                         \
    afX[2] = dsr<2048>(aAr); afX[3] = dsr<3072>(aAr);                         \
    afX[4] = dsr<4096>(aAr); afX[5] = dsr<5120>(aAr);                         \
    afX[6] = dsr<6144>(aAr); afX[7] = dsr<7168>(aAr); }

  // prologue: A0..A2 staged, B0+B1 loaded, full drain, read A0 fragments
  STAGE(0); STAGE(1); STAGE(2);
  LOADB(bs0, 0)
  LOADB(bs1, 1)
  asm volatile("s_waitcnt vmcnt(0)" ::: "memory");
  __builtin_amdgcn_s_barrier();
  RD(afA, 0)
  asm volatile("s_waitcnt lgkmcnt(0)" ::: "memory");
  __builtin_amdgcn_sched_barrier(0);

#define ITER(kt_, afC, bC, afN) {                                             \
    STAGE((kt_) + 3);                                                         \
    asm volatile("s_waitcnt vmcnt(%0)" :: "n"(NWN + 4) : "memory");           \
    __builtin_amdgcn_s_barrier();                                             \
    __builtin_amdgcn_sched_barrier(0);                                        \
    RD(afN, (kt_) + 1)                                                        \
    __builtin_amdgcn_sched_barrier(0);                                        \
    __builtin_amdgcn_s_setprio(1);                                            \
    _Pragma("unroll")                                                         \
    for (int i = 0; i < 8; ++i)                                               \
      _Pragma("unroll")                                                       \
      for (int j = 0; j < NWN; ++j)                                           \
        acc[i][j] = MFMA16(afC[i], bC[j], acc[i][j]);                         \
    __builtin_amdgcn_s_setprio(0);                                            \
    LOADB(bC, (kt_) + 2)                                                      \
    asm volatile("s_waitcnt lgkmcnt(0)" ::: "memory");                        \
    __builtin_amdgcn_sched_barrier(0); }

  for (int kt = 0; kt < nkt; kt += 2) {
    ITER(kt, afA, bs0, afB)
    ITER(kt + 1, afB, bs1, afA)
  }
#undef ITER
#undef RD
#undef LOADB

  asm volatile("s_waitcnt vmcnt(0) lgkmcnt(0)" ::: "memory");
  __builtin_amdgcn_sched_barrier(0);
  KEEPV(bs0[0]); KEEPV(bs0[1]);
  if constexpr (NWN == 4) { KEEPV(bs0[2]); KEEPV(bs0[3]); }
  KEEPV(bs1[0]); KEEPV(bs1[1]);
  if constexpr (NWN == 4) { KEEPV(bs1[2]); KEEPV(bs1[3]); }
  KEEPV(afA[0]); KEEPV(afA[1]); KEEPV(afA[2]); KEEPV(afA[3]);
  KEEPV(afA[4]); KEEPV(afA[5]); KEEPV(afA[6]); KEEPV(afA[7]);
  KEEPV(afB[0]); KEEPV(afB[1]); KEEPV(afB[2]); KEEPV(afB[3]);
  KEEPV(afB[4]); KEEPV(afB[5]); KEEPV(afB[6]); KEEPV(afB[7]);

  const int r0 = mt * (NWM * 128) + wm + fq * 4;
  const int c0 = nt * BN + wn + fr;
#pragma unroll
  for (int i = 0; i < 8; ++i)
#pragma unroll
    for (int j = 0; j < NWN; ++j)
#pragma unroll
      for (int e = 0; e < 4; ++e)
        cstore(C, (size_t)(r0 + i * 16 + e) * N + c0 + j * 16, acc[i][j][e]);
}

// ---------------- beta / g (log-decay): [L,2048]@[2048,32] x2 + activations ----------------
__global__ __launch_bounds__(256)
void k_ba(const float* __restrict__ h, const float* __restrict__ Wb, const float* __restrict__ Wa,
          const float* __restrict__ A_log, const float* __restrict__ dtb,
          float* __restrict__ beta, float* __restrict__ g_out) {
  const int w = threadIdx.x >> 6, lane = threadIdx.x & 63;
  const int t = blockIdx.x * 4 + w;
  const int j = lane & 31;
  const bool isB = lane < 32;
  const float* __restrict__ hr = h + (size_t)t * DHID;
  const float* Wc = isB ? Wb : Wa;
  float acc = 0.f;
  for (int kk = 0; kk < DHID; ++kk) acc = fmaf(hr[kk], Wc[(size_t)kk * HVN + j], acc);
  if (isB) {
    beta[(size_t)t * HVN + j] = 1.f / (1.f + expf(-acc));
  } else {
    float xx = acc + dtb[j];
    float sp = (xx > 20.f) ? xx : log1pf(expf(xx));
    g_out[(size_t)t * HVN + j] = -expf(A_log[j]) * sp;   // g = log(decay) <= 0
  }
}

// ---------------- in-place l2norm of q (scaled) and k heads ----------------
__global__ __launch_bounds__(256)
void k_l2n(u16* __restrict__ qkvz) {
  const int w = threadIdx.x >> 6, lane = threadIdx.x & 63;
  const int r = blockIdx.x * 4 + w;
  const int isK = r >> 16;
  const int rr = r & 65535;
  const int t = rr >> 4, hd = rr & 15;
  u16* p = qkvz + (size_t)t * NTOT + isK * 2048 + hd * DKK + lane * 2;
  float a = b2f(p[0]), b = b2f(p[1]);
  float ss = a * a + b * b;
  ss = red16(ss);
  ss += __shfl_xor(ss, 16);
  ss += __shfl_xor(ss, 32);
  const float sc = rsqrtf(ss + 1e-6f) * (isK ? 1.f : 0.08838834764831845f);
  p[0] = f2bf(a * sc); p[1] = f2bf(b * sc);
}

// ---------------- chunk solve (parallel): per (hv, chunk n) ----------------
__global__ __launch_bounds__(256)
void k_r1(const u16* __restrict__ qkvz, const float* __restrict__ beta_g,
          const float* __restrict__ g_g, u16* __restrict__ UM_g, float* __restrict__ cumL_g) {
  const int pair = blockIdx.x;          // hv*64 + n
  const int hv = pair >> 6, n = pair & 63;
  const int hk = hv >> 1;
  const int t0 = n * 64;
  const int tid = threadIdx.x, lane = tid & 63, wv = tid >> 6;
  const int fr = lane & 15, fq = lane >> 4;

  __shared__ __align__(16) u16 Xb[256 * 64];
  __shared__ __align__(16) u16 Dbuf0[64 * 64 * 2];
  __shared__ __align__(16) u16 Dbuf1[64 * 64 * 2];
  __shared__ float Lc[64];
  __shared__ float Bc[64];
  u16* Kl = Dbuf0;

  const int j = tid & 63, h = tid >> 6;
  const u16* kg = qkvz + (size_t)(t0 + j) * NTOT + 2048 + hk * DKK + h * 32;
  const u16* vg = qkvz + (size_t)(t0 + j) * NTOT + 4096 + hv * DKK + h * 32;
  u16x8 kv[4], vv[4];
#pragma unroll
  for (int i = 0; i < 4; ++i) { kv[i] = *(const u16x8*)(kg + i * 8); vv[i] = *(const u16x8*)(vg + i * 8); }
  if (tid < 64) {
    Lc[tid] = g_g[(size_t)(t0 + tid) * HVN + hv];
    Bc[tid] = beta_g[(size_t)(t0 + tid) * HVN + hv];
  }
#pragma unroll
  for (int i = 0; i < 4; ++i) *(u16x8*)&Kl[sw16(j, h * 32 + i * 8, 128)] = kv[i];
  __syncthreads();
  if (tid == 0) { float a = 0.f; for (int t = 0; t < 64; ++t) { a += Lc[t]; Lc[t] = a; } }
  __syncthreads();
  if (tid < 64) cumL_g[(size_t)pair * 64 + tid] = Lc[tid];

  {
    const float bj = Bc[j];
    const float mj = bj * __expf(Lc[j]);
#pragma unroll
    for (int i = 0; i < 4; ++i)
#pragma unroll
      for (int e = 0; e < 8; ++e) {
        int c = h * 32 + i * 8 + e;
        Xb[sw16(c, j, 64)] = f2bf(bj * b2f(vv[i][e]));
        Xb[sw16(128 + c, j, 64)] = f2bf(mj * b2f(kv[i][e]));
      }
  }
  f32x4 kk[4] = {};
#pragma unroll
  for (int ks = 0; ks < 4; ++ks) {
    short8 afr = *(const short8*)&Kl[sw16(wv * 16 + fr, ks * 32 + fq * 8, 128)];
#pragma unroll
    for (int ct = 0; ct < 4; ++ct) {
      short8 bfr = *(const short8*)&Kl[sw16(ct * 16 + fr, ks * 32 + fq * 8, 128)];
      kk[ct] = MFMA16(afr, bfr, kk[ct]);
    }
  }
  __syncthreads();

  f32x4 acc[16];
#pragma unroll
  for (int ct = 0; ct < 16; ++ct) {
    u16x4 xi = *(const u16x4*)&Xb[sw16(ct * 16 + fr, wv * 16 + fq * 4, 64)];
    acc[ct][0] = b2f(xi[0]); acc[ct][1] = b2f(xi[1]); acc[ct][2] = b2f(xi[2]); acc[ct][3] = b2f(xi[3]);
  }
#pragma unroll
  for (int ct = 0; ct < 4; ++ct) {
    const int s = ct * 16 + fr;
    u16x4 pk;
#pragma unroll
    for (int e = 0; e < 4; ++e) {
      const int t = wv * 16 + fq * 4 + e;
      float v = (s < t) ? -Bc[t] * __expf(Lc[t] - Lc[s]) * kk[ct][e] : 0.f;
      pk[e] = f2bf(v);
      Dbuf0[sw16(t, s, 64)] = pk[e];
    }
    *(u16x4*)&Dbuf0[4096 + sw16(s, wv * 16 + fq * 4, 64)] = pk;
  }
  __syncthreads();

  u16* DA = Dbuf0;
  u16* DB = Dbuf1;
  for (int stg = 0; stg < 6; ++stg) {
    u16* Dr = DA;
    u16* Dc = DA + 4096;
    short8 da0 = *(const short8*)&Dr[sw16(wv * 16 + fr, 0 + fq * 8, 64)];
    short8 da1 = *(const short8*)&Dr[sw16(wv * 16 + fr, 32 + fq * 8, 64)];
#pragma unroll
    for (int ct = 0; ct < 16; ++ct) {
      short8 b0 = *(const short8*)&Xb[sw16(ct * 16 + fr, 0 + fq * 8, 64)];
      short8 b1 = *(const short8*)&Xb[sw16(ct * 16 + fr, 32 + fq * 8, 64)];
      acc[ct] = MFMA16(da0, b0, acc[ct]);
      acc[ct] = MFMA16(da1, b1, acc[ct]);
    }
    f32x4 sq[4] = {};
    if (stg < 5) {
#pragma unroll
      for (int ct = 0; ct < 4; ++ct) {
        short8 sb0 = *(const short8*)&Dc[sw16(ct * 16 + fr, 0 + fq * 8, 64)];
        short8 sb1 = *(const short8*)&Dc[sw16(ct * 16 + fr, 32 + fq * 8, 64)];
        sq[ct] = MFMA16(da0, sb0, sq[ct]);
        sq[ct] = MFMA16(da1, sb1, sq[ct]);
      }
    }
    __syncthreads();
#pragma unroll
    for (int ct = 0; ct < 16; ++ct) {
      u16x4 pk;
      pk[0] = f2bf(acc[ct][0]); pk[1] = f2bf(acc[ct][1]); pk[2] = f2bf(acc[ct][2]); pk[3] = f2bf(acc[ct][3]);
      *(u16x4*)&Xb[sw16(ct * 16 + fr, wv * 16 + fq * 4, 64)] = pk;
    }
    if (stg < 5) {
#pragma unroll
      for (int ct = 0; ct < 4; ++ct) {
        u16x4 pk;
        pk[0] = f2bf(sq[ct][0]); pk[1] = f2bf(sq[ct][1]); pk[2] = f2bf(sq[ct][2]); pk[3] = f2bf(sq[ct][3]);
        *(u16x4*)&(DB + 4096)[sw16(ct * 16 + fr, wv * 16 + fq * 4, 64)] = pk;
#pragma unroll
        for (int e = 0; e < 4; ++e) DB[sw16(wv * 16 + fq * 4 + e, ct * 16 + fr, 64)] = pk[e];
      }
    }
    __syncthreads();
    u16* tmp = DA; DA = DB; DB = tmp;
  }

#pragma unroll
  for (int ct = 0; ct < 16; ++ct) {
    const int c = ct * 16 + fr;
#pragma unroll
    for (int e = 0; e < 4; ++e) {
      const int t = wv * 16 + fq * 4 + e;
      float v = acc[ct][e];
      if (ct >= 8) v = -v;
      UM_g[((size_t)pair * 64 + t) * 256 + c] = f2bf(v);
    }
  }
}

// ---------------- sequential chunk scan: 128 blocks = (hv, dv-quarter cs) ----------------
// R16: Kt transpose moved off LDS scalar writes. K loaded COLUMN-wise from global
// (16 scalar L2 loads/thread, issued 1 chunk ahead), STW writes Kt as 2 vector u16x8.
// Kt holds RAW k^T; the e^{L63-Lt} scale moves to dT2 = delta * e^{L63-Lt} (ph1).
// S-update: sa = eC*sa + Kt_raw @ dT2  ==  eC*sa + Kbar^T @ delta.
__global__ __launch_bounds__(512)
void k_r2(u16* __restrict__ qkvz, const u16* __restrict__ UM_g,
          const float* __restrict__ cumL_g, u16* __restrict__ o1_g) {
  const int hv = blockIdx.x >> 2, cs = blockIdx.x & 3;
  const int hk = hv >> 1;
  const int tid = threadIdx.x, lane = tid & 63, w = tid >> 6;   // 8 waves
  const int fr = lane & 15, fq = lane >> 4;
  const int j = tid & 63, h = tid >> 6;                          // staging coords
  const int tw = w & 3, dwv = w >> 2;                            // ph1 tile coords
  const int kdk = tid >> 2, ktb = (tid & 3) * 16;                // Kt column coords

  __shared__ __align__(16) u16 Ml2[2][8192];   // -M rows [t][dk] swz
  __shared__ __align__(16) u16 Ql2[2][8192];   // q rows
  __shared__ __align__(16) u16 Kt2[2][8192];   // RAW k^T [dk][t] swz
  __shared__ __align__(16) u16 dT[2048];       // delta^T [32 ldv][64 t] swz (raw)
  __shared__ __align__(16) u16 dT2[2048];      // delta^T * e^{L63-Lt} swz
  __shared__ __align__(16) u16 SbT[4096];      // S^T [32 ldv][128 dk] swz
  __shared__ __align__(16) u16 o1b[2048];      // o1 [32 ldv][64 t] swz
  __shared__ float Lc2[2][64];

  f32x4 sacc[2];
#pragma unroll
  for (int d = 0; d < 2; ++d) sacc[d] = (f32x4){0.f, 0.f, 0.f, 0.f};
  for (int i = tid; i < 4096; i += 512) SbT[i] = 0;

  u16x8 pQ0, pQ1, pM0, pM1;
  u16 pKc[16];
  u16 pUn0, pUn1, pUn2, pUn3, pUc0, pUc1, pUc2, pUc3;
  float pL, pL63;

#define PREF(nn) {                                                            \
    const int nc = ((nn) < 64) ? (nn) : 63;                                   \
    const int pr = hv * 64 + nc; const int tt0 = nc * 64;                     \
    const u16* qg = qkvz + (size_t)(tt0 + j) * NTOT + hk * DKK + h * 16;      \
    pQ0 = *(const u16x8*)qg;          pQ1 = *(const u16x8*)(qg + 8);          \
    const u16* kg = qkvz + (size_t)(tt0 + ktb) * NTOT + 2048 + hk * DKK + kdk; \
    _Pragma("unroll")                                                         \
    for (int i = 0; i < 16; ++i) pKc[i] = kg[(size_t)i * NTOT];               \
    const u16* mg = UM_g + ((size_t)pr * 64 + j) * 256;                       \
    pM0 = *(const u16x8*)(mg + 128 + h * 16);                                 \
    pM1 = *(const u16x8*)(mg + 136 + h * 16);                                 \
    const u16* ug = UM_g + ((size_t)pr * 64 + tw * 16 + fq * 4) * 256         \
                    + cs * 32 + dwv * 16 + fr;                                \
    pUn0 = ug[0]; pUn1 = ug[256]; pUn2 = ug[512]; pUn3 = ug[768];             \
    pL = cumL_g[(size_t)pr * 64 + j]; pL63 = cumL_g[(size_t)pr * 64 + 63]; }

#define STW(b) {                                                              \
    *(u16x8*)&Ql2[b][sw16(j, h * 16, 128)] = pQ0;                             \
    *(u16x8*)&Ql2[b][sw16(j, h * 16 + 8, 128)] = pQ1;                         \
    *(u16x8*)&Ml2[b][sw16(j, h * 16, 128)] = pM0;                             \
    *(u16x8*)&Ml2[b][sw16(j, h * 16 + 8, 128)] = pM1;                         \
    u16x8 kt0, kt1;                                                           \
    _Pragma("unroll")                                                         \
    for (int e = 0; e < 8; ++e) { kt0[e] = pKc[e]; kt1[e] = pKc[8 + e]; }     \
    *(u16x8*)&Kt2[b][sw16(kdk, ktb, 64)] = kt0;                               \
    *(u16x8*)&Kt2[b][sw16(kdk, ktb + 8, 64)] = kt1;                           \
    if (h == 0) Lc2[b][j] = pL; }

  PREF(0)
  STW(0)
  __syncthreads();

  for (int n = 0; n < 64; ++n) {
    const int cur = n & 1;
    const int pair = hv * 64 + n, t0 = n * 64;
    pUc0 = pUn0; pUc1 = pUn1; pUc2 = pUn2; pUc3 = pUn3;
    const float curL63 = pL63;
    PREF(n + 1)

    // ---- ph1: delta = U + (-M)@S ; o1 = e^{Lt}(Q@S) ; dT2 = delta*e^{L63-Lt} ----
    short8 amf[4], aqf[4];
#pragma unroll
    for (int ks = 0; ks < 4; ++ks) {
      amf[ks] = *(const short8*)&Ml2[cur][sw16(tw * 16 + fr, ks * 32 + fq * 8, 128)];
      aqf[ks] = *(const short8*)&Ql2[cur][sw16(tw * 16 + fr, ks * 32 + fq * 8, 128)];
    }
    float el[4], el2[4];
#pragma unroll
    for (int e = 0; e < 4; ++e) {
      const float Lt = Lc2[cur][tw * 16 + fq * 4 + e];
      el[e] = __expf(Lt);
      el2[e] = __expf(curL63 - Lt);
    }
    {
      f32x4 dc;
      dc[0] = b2f(pUc0); dc[1] = b2f(pUc1); dc[2] = b2f(pUc2); dc[3] = b2f(pUc3);
      f32x4 oc = {};
#pragma unroll
      for (int ks = 0; ks < 4; ++ks) {
        short8 bs = *(const short8*)&SbT[sw16(dwv * 16 + fr, ks * 32 + fq * 8, 128)];
        dc = MFMA16(amf[ks], bs, dc);
        oc = MFMA16(aqf[ks], bs, oc);
      }
      u16x4 pkd, pkd2, pko;
#pragma unroll
      for (int e = 0; e < 4; ++e) {
        pkd[e]  = f2bf(dc[e]);
        pkd2[e] = f2bf(dc[e] * el2[e]);
        pko[e]  = f2bf(oc[e] * el[e]);
      }
      *(u16x4*)&dT[sw16(dwv * 16 + fr, tw * 16 + fq * 4, 64)] = pkd;
      *(u16x4*)&dT2[sw16(dwv * 16 + fr, tw * 16 + fq * 4, 64)] = pkd2;
      *(u16x4*)&o1b[sw16(dwv * 16 + fr, tw * 16 + fq * 4, 64)] = pko;
    }
    __syncthreads();

    // ---- ph2: flush delta/o1 to global; stage next; S-update ----
    {
      const int i = tid * 4;
      u16x4 vd = *(const u16x4*)&dT[i];
      const int f = cs * 2048 + i;
      *(u16x4*)(qkvz + (size_t)(t0 + (f >> 7)) * NTOT + 4096 + hv * DKK + (f & 127)) = vd;
      u16x4 vo = *(const u16x4*)&o1b[i];
      *(u16x4*)(o1_g + (size_t)pair * 8192 + cs * 2048 + i) = vo;
    }
    STW(cur ^ 1)
    {
      const float eC = __expf(curL63);
      short8 ak0 = *(const short8*)&Kt2[cur][sw16(w * 16 + fr, fq * 8, 64)];
      short8 ak1 = *(const short8*)&Kt2[cur][sw16(w * 16 + fr, 32 + fq * 8, 64)];
#pragma unroll
      for (int d = 0; d < 2; ++d) {
        short8 bd0 = *(const short8*)&dT2[sw16(d * 16 + fr, fq * 8, 64)];
        short8 bd1 = *(const short8*)&dT2[sw16(d * 16 + fr, 32 + fq * 8, 64)];
        f32x4 sa = sacc[d];
#pragma unroll
        for (int e = 0; e < 4; ++e) sa[e] *= eC;
        sa = MFMA16(ak0, bd0, sa);
        sa = MFMA16(ak1, bd1, sa);
        sacc[d] = sa;
        u16x4 pk;
        pk[0] = f2bf(sa[0]); pk[1] = f2bf(sa[1]); pk[2] = f2bf(sa[2]); pk[3] = f2bf(sa[3]);
        *(u16x4*)&SbT[sw16(d * 16 + fr, w * 16 + fq * 4, 128)] = pk;
      }
    }
    __syncthreads();
  }
#undef PREF
#undef STW
}

// ---------------- parallel epilogue: o = o1 + G@delta, fused gated RMSNorm ----------------
__global__ __launch_bounds__(512)
void k_r3(const u16* __restrict__ qkvz, const u16* __restrict__ o1_g,
          const float* __restrict__ cumL_g, const float* __restrict__ nw,
          u16* __restrict__ x) {
  const int pair = blockIdx.x, hv = pair >> 6, n = pair & 63, hk = hv >> 1, t0 = n * 64;
  const int tid = threadIdx.x, lane = tid & 63, w = tid >> 6;
  const int fr = lane & 15, fq = lane >> 4;
  const int j = tid & 63, h = tid >> 6;   // h 0..7

  __shared__ __align__(16) u16 Ql[8192];
  __shared__ __align__(16) u16 Kl[8192];
  __shared__ __align__(16) u16 Gl[4096];
  __shared__ __align__(16) u16 dTl[8192];
  __shared__ __align__(16) u16 o1l[8192];      // o1 [dv][t] swz (raw block from k_r2)
  __shared__ __align__(16) float of[64 * 132];
  __shared__ float Lc[64];
  __shared__ float Lw[128];

  {
    const u16* qg = qkvz + (size_t)(t0 + j) * NTOT + hk * DKK + h * 16;
    u16x8 q0 = *(const u16x8*)qg, q1 = *(const u16x8*)(qg + 8);
    u16x8 k0 = *(const u16x8*)(qg + 2048), k1 = *(const u16x8*)(qg + 2056);
    *(u16x8*)&Ql[sw16(j, h * 16, 128)] = q0;
    *(u16x8*)&Ql[sw16(j, h * 16 + 8, 128)] = q1;
    *(u16x8*)&Kl[sw16(j, h * 16, 128)] = k0;
    *(u16x8*)&Kl[sw16(j, h * 16 + 8, 128)] = k1;
  }
#pragma unroll
  for (int it = 0; it < 2; ++it) {
    const int f = ((w * 2 + it) * 64 + lane) * 8;
    gld16(qkvz + (size_t)(t0 + (f >> 7)) * NTOT + 4096 + hv * DKK + (f & 127),
          (char*)dTl + (w * 2 + it) * 1024);
    gld16(o1_g + (size_t)pair * 8192 + f, (char*)o1l + (w * 2 + it) * 1024);
  }
  if (tid < 64) Lc[tid] = cumL_g[(size_t)pair * 64 + tid];
  if (tid < 128) Lw[tid] = nw[tid];
  __syncthreads();

  // ---- G = tril(e^{Lt-Ls} * QK^T) ----
  const int tw = w & 3, sp = (w >> 2) * 2;
  {
    f32x4 kk0 = {}, kk1 = {};
#pragma unroll
    for (int ks = 0; ks < 4; ++ks) {
      short8 aq = *(const short8*)&Ql[sw16(tw * 16 + fr, ks * 32 + fq * 8, 128)];
      short8 b0 = *(const short8*)&Kl[sw16(sp * 16 + fr, ks * 32 + fq * 8, 128)];
      short8 b1 = *(const short8*)&Kl[sw16((sp + 1) * 16 + fr, ks * 32 + fq * 8, 128)];
      kk0 = MFMA16(aq, b0, kk0);
      kk1 = MFMA16(aq, b1, kk1);
    }
#pragma unroll
    for (int e = 0; e < 4; ++e) {
      const int t = tw * 16 + fq * 4 + e;
      const float Lt = Lc[t];
      const int s0 = sp * 16 + fr, s1 = s0 + 16;
      Gl[sw16(t, s0, 64)] = f2bf((s0 <= t) ? kk0[e] * __expf(Lt - Lc[s0]) : 0.f);
      Gl[sw16(t, s1, 64)] = f2bf((s1 <= t) ? kk1[e] * __expf(Lt - Lc[s1]) : 0.f);
    }
  }
  __syncthreads();

  // ---- o = G@delta ----
  {
    short8 ag0 = *(const short8*)&Gl[sw16(tw * 16 + fr, fq * 8, 64)];
    short8 ag1 = *(const short8*)&Gl[sw16(tw * 16 + fr, 32 + fq * 8, 64)];
#pragma unroll
    for (int dd = 0; dd < 4; ++dd) {
      const int d = (w >> 2) * 4 + dd;
      short8 bd0 = *(const short8*)&dTl[sw16(d * 16 + fr, fq * 8, 64)];
      short8 bd1 = *(const short8*)&dTl[sw16(d * 16 + fr, 32 + fq * 8, 64)];
      f32x4 oc = {};
      oc = MFMA16(ag0, bd0, oc);
      oc = MFMA16(ag1, bd1, oc);
#pragma unroll
      for (int e = 0; e < 4; ++e) of[(tw * 16 + fq * 4 + e) * 132 + d * 16 + fr] = oc[e];
    }
  }
  __syncthreads();

  // ---- fused gated RMSNorm: x = rmsnorm((of + o1) * silu(z)) * w ----
  {
    const int t = tid >> 3, q8 = tid & 7;
    const u16* zp = qkvz + (size_t)(t0 + t) * NTOT + 8192 + hv * DKK + q8 * 16;
    float xv[16];
    float ss = 0.f;
#pragma unroll
    for (int i = 0; i < 2; ++i) {
      u16x8 zv = *(const u16x8*)(zp + i * 8);
#pragma unroll
      for (int e = 0; e < 8; ++e) {
        const int dv = q8 * 16 + i * 8 + e;
        float z = b2f(zv[e]);
        float o = of[t * 132 + dv] + b2f(o1l[sw16(dv, t, 64)]);
        float xx = o * (z / (1.f + __expf(-z)));
        xv[i * 8 + e] = xx;
        ss = fmaf(xx, xx, ss);
      }
    }
    ss += __shfl_xor(ss, 1);
    ss += __shfl_xor(ss, 2);
    ss += __shfl_xor(ss, 4);
    const float scl = rsqrtf(ss * (1.f / 128.f) + 1e-6f);
    u16* xo = x + (size_t)(t0 + t) * 4096 + hv * DKK + q8 * 16;
#pragma unroll
    for (int i = 0; i < 2; ++i) {
      u16x8 pk;
#pragma unroll
      for (int e = 0; e < 8; ++e) pk[e] = f2bf(xv[i * 8 + e] * scl * Lw[q8 * 16 + i * 8 + e]);
      *(u16x8*)(xo + i * 8) = pk;
    }
  }
}

extern "C" void kernel_launch(void* const* d_in, const int* in_sizes, int n_in,
                              void* d_out, int out_size, void* d_ws, size_t ws_size,
                              hipStream_t stream) {
  const float* h    = (const float*)d_in[0];
  const float* Wq   = (const float*)d_in[1];
  const float* Wk   = (const float*)d_in[2];
  const float* Wv   = (const float*)d_in[3];
  const float* Wz   = (const float*)d_in[4];
  const float* Wb   = (const float*)d_in[5];
  const float* Wa   = (const float*)d_in[6];
  const float* Alog = (const float*)d_in[7];
  const float* dtb  = (const float*)d_in[8];
  const float* nw   = (const float*)d_in[9];
  const float* Wo   = (const float*)d_in[10];
  char* ws = (char*)d_ws;
  u16* h_bf  = (u16*)(ws);
  u16* Bfq   = (u16*)(ws + 16777216ull);      // [768 j16][64 kt][512] bf16 = 50.33MB
  u16* UM    = (u16*)(ws);                    // [2048][64][256] bf16 = 64MB (after GEMM)
  u16* Bfo   = (u16*)(ws + 67108864ull);      // [128 j16][128 kt][512] bf16 = 16.8MB
  u16* qkvz  = (u16*)(ws + 83886080ull);
  u16* o1g   = (u16*)(ws + 184549376ull);     // [2048][128dv][64t] bf16 = 32MB
  u16* xbuf  = (u16*)(ws + 16777216ull);      // aliases Bfq (dead after qkvz GEMM)
  float* beta  = (float*)(ws + 218103808ull);
  float* g     = (float*)(ws + 218103808ull + 524288ull);
  float* cumL  = (float*)(ws + 218103808ull + 1048576ull);

  k_cvt<<<8192, 256, 0, stream>>>(h, h_bf, LTOK * DHID);
  k_trf<<<2048, 256, 0, stream>>>(Wq, Bfq, 2048, 64, 0);
  k_trf<<<2048, 256, 0, stream>>>(Wk, Bfq, 2048, 64, 128);
  k_trf<<<4096, 256, 0, stream>>>(Wv, Bfq, 4096, 64, 256);
  k_trf<<<4096, 256, 0, stream>>>(Wz, Bfq, 4096, 64, 512);
  k_trf<<<4096, 256, 0, stream>>>(Wo, Bfo, 2048, 128, 0);
  k_g256<u16, 2, 4><<<768, 512, 0, stream>>>(h_bf, Bfq, qkvz, 4096, 12288, 2048, 48);
  k_ba<<<1024, 256, 0, stream>>>(h, Wb, Wa, Alog, dtb, beta, g);
  k_l2n<<<32768, 256, 0, stream>>>(qkvz);
  k_r1<<<2048, 256, 0, stream>>>(qkvz, beta, g, UM, cumL);
  k_r2<<<128, 512, 0, stream>>>(qkvz, UM, cumL, o1g);
  k_r3<<<2048, 512, 0, stream>>>(qkvz, o1g, cumL, nw, xbuf);
  k_g256<float, 1, 2><<<512, 256, 0, stream>>>(xbuf, Bfo, (float*)d_out, 4096, 2048, 4096, 16);
}

// Round 17
// 792.754 us; speedup vs baseline: 1.0348x; 1.0139x over previous
//
#include <hip/hip_runtime.h>

#define LTOK 4096
#define DHID 2048
#define HKN  16
#define HVN  32
#define DKK  128
#define NTOT 12288

typedef unsigned short u16;
typedef __attribute__((ext_vector_type(8))) short short8;
typedef __attribute__((ext_vector_type(8))) unsigned short u16x8;
typedef __attribute__((ext_vector_type(4))) unsigned short u16x4;
typedef __attribute__((ext_vector_type(4))) float f32x4;

__device__ __forceinline__ float b2f(u16 u) {
  unsigned int x = ((unsigned int)u) << 16;
  return __builtin_bit_cast(float, x);
}
__device__ __forceinline__ u16 f2bf(float f) {
  unsigned int u = __builtin_bit_cast(unsigned int, f);
  u += 0x7FFFu + ((u >> 16) & 1u);
  return (u16)(u >> 16);
}

template<int C> __device__ __forceinline__ float dppmv(float x) {
  int i = __builtin_amdgcn_update_dpp(0, __builtin_bit_cast(int, x), C, 0xF, 0xF, true);
  return __builtin_bit_cast(float, i);
}
__device__ __forceinline__ float red16(float x) {
  x += dppmv<0xB1>(x);
  x += dppmv<0x4E>(x);
  x += dppmv<0x124>(x);
  x += dppmv<0x128>(x);
  return x;
}

__device__ __forceinline__ void gld16(const void* g, void* l) {
  __builtin_amdgcn_global_load_lds((const __attribute__((address_space(1))) void*)g,
                                   (__attribute__((address_space(3))) void*)l, 16, 0, 0);
}

// pinned-order LDS vector read (addr VGPR + compile-time byte offset)
template<int OFF> __device__ __forceinline__ short8 dsr(unsigned a) {
  short8 r;
  asm volatile("ds_read_b128 %0, %1 offset:%2" : "=v"(r) : "v"(a), "n"(OFF));
  return r;
}
// pinned-order global vector load to VGPR (B fragments; counted in vmcnt manually)
__device__ __forceinline__ short8 gldx4(const u16* p) {
  short8 r;
  asm volatile("global_load_dwordx4 %0, %1, off" : "=v"(r) : "v"(p));
  return r;
}
// keep a register value live (rule #17) - blocks allocator reuse until this point
#define KEEPV(x) asm volatile("" :: "v"(x))

// swizzled LDS element offsets (XOR row-bits into 16B-slot bits); byte^=((r&7)<<4)
__device__ __forceinline__ int sw16(int r, int c, int rowc) { return (r * rowc + c) ^ ((r & 7) << 3); }

__device__ __forceinline__ void cstore(u16* C, size_t i, float v) { C[i] = f2bf(v); }
__device__ __forceinline__ void cstore(float* C, size_t i, float v) { C[i] = v; }

// ---------------- fp32 -> bf16 convert ----------------
__global__ __launch_bounds__(256)
void k_cvt(const float* __restrict__ s, u16* __restrict__ d, int n) {
  const int i = (blockIdx.x * 256 + threadIdx.x) * 4;
  const float4 v = *(const float4*)(s + i);
  ushort4 o;
  o.x = f2bf(v.x); o.y = f2bf(v.y); o.z = f2bf(v.z); o.w = f2bf(v.w);
  *(ushort4*)(d + i) = o;
}

// ---------------- fp32 W[K][N] -> bf16 B-fragment-major layout ----------------
__global__ __launch_bounds__(256)
void k_trf(const float* __restrict__ W, u16* __restrict__ Bf, int Ncols, int nkt, int j16base) {
  const int wv = threadIdx.x >> 6, lane = threadIdx.x & 63;
  const int frag = blockIdx.x * 4 + wv;
  const int j16 = frag / nkt, kt = frag % nkt;
  const int r0 = kt * 32 + (lane >> 4) * 8;
  const int c = j16 * 16 + (lane & 15);
  u16x8 o;
#pragma unroll
  for (int e = 0; e < 8; ++e) o[e] = f2bf(W[(size_t)(r0 + e) * Ncols + c]);
  *(u16x8*)(Bf + ((size_t)(j16base + j16) * nkt + kt) * 512 + lane * 8) = o;
}

#define MFMA16(a, b, c) __builtin_amdgcn_mfma_f32_16x16x32_bf16(a, b, c, 0, 0, 0)

// ---------------- (NWM*128)xBN bf16 MFMA GEMM, B-from-global (flatmm) ----------------
template<typename OutT, int NWM, int NWN>
__global__ __launch_bounds__(NWM * 256, 2)
void k_g256(const u16* __restrict__ A, const u16* __restrict__ Bf, OutT* __restrict__ C,
            int M, int N, int K, int NT) {
  constexpr int BN = NWN * 64;
  constexpr int BUFE = NWM * 4096;           // A elems per LDS buffer
  __shared__ u16 Lds[4 * BUFE];
  const int tid = threadIdx.x;
  const int lane = tid & 63, w = tid >> 6;
  const int fr = lane & 15, fq = lane >> 4;
  const int wm = (w >> 2) * 128, wn = (w & 3) * (NWN * 16);
  const int nkt = K >> 5;
  const size_t sK = (size_t)K;

  // supertile + XCD-aware ordering (bijective; gridDim.x % 8 == 0)
  const int MT = gridDim.x / NT;
  const int nts = (NT < 16) ? NT : 16;
  const int per_super = MT * nts;
  const int super = blockIdx.x / per_super;
  const int within = blockIdx.x % per_super;
  const int mtg = MT >> 3;
  const int q = within >> 3;
  const int mt = (within & 7) * mtg + (q % mtg);
  const int nt = super * nts + q / mtg;

  // A staging: thread covers row tid/4 (+NWM*64 for 2nd load); k-slot pre-swizzled (T2)
  const int kslot = ((tid & 3) ^ ((tid >> 3) & 3)) * 8;
  const u16* aS = A + (size_t)(mt * (NWM * 128) + (tid >> 2)) * sK + kslot;

  // B fragment base pointers (compile-time-indexed -> registers, rule #20)
  const int jw = nt * (BN / 16) + (w & 3) * NWN;
  const u16* bp[NWN];
#pragma unroll
  for (int j = 0; j < NWN; ++j) bp[j] = Bf + ((size_t)(jw + j) * nkt) * 512 + lane * 8;

  f32x4 acc[8][NWN] = {};

  auto STAGE = [&](int kt_) {
    const int sk = (kt_ < nkt) ? kt_ : nkt - 1;
    u16* base = &Lds[(kt_ & 3) * BUFE];
    gld16(aS + (size_t)sk * 32, base + tid * 8);
    gld16(aS + (size_t)(NWM * 64) * sK + (size_t)sk * 32, base + NWM * 2048 + tid * 8);
  };

#define LOADB(bset, kt_) {                                                    \
    const int sk2 = ((kt_) < nkt) ? (kt_) : (nkt - 1);                        \
    _Pragma("unroll")                                                         \
    for (int j = 0; j < NWN; ++j) bset[j] = gldx4(bp[j] + (size_t)sk2 * 512); }

  const int akey = (fr >> 1) & 3;            // read-side swizzle key
  const unsigned ldsBase = (unsigned)(size_t)(__attribute__((address_space(3))) void*)&Lds[0];
  const unsigned aA0 = ldsBase + 2u * (unsigned)((wm + fr) * 32 + ((fq ^ akey) << 3));

  short8 afA[8], afB[8], bs0[NWN], bs1[NWN];

#define RD(afX, kt_) {                                                        \
    const unsigned aAr = aA0 + (unsigned)(((kt_) & 3) * (BUFE * 2));          \
    afX[0] = dsr<0>(aAr);    afX[1] = dsr<1024>(aAr);                         \
    afX[2] = dsr<2048>(aAr); afX[3] = dsr<3072>(aAr);                         \
    afX[4] = dsr<4096>(aAr); afX[5] = dsr<5120>(aAr);                         \
    afX[6] = dsr<6144>(aAr); afX[7] = dsr<7168>(aAr); }

  // prologue: A0..A2 staged, B0+B1 loaded, full drain, read A0 fragments
  STAGE(0); STAGE(1); STAGE(2);
  LOADB(bs0, 0)
  LOADB(bs1, 1)
  asm volatile("s_waitcnt vmcnt(0)" ::: "memory");
  __builtin_amdgcn_s_barrier();
  RD(afA, 0)
  asm volatile("s_waitcnt lgkmcnt(0)" ::: "memory");
  __builtin_amdgcn_sched_barrier(0);

#define ITER(kt_, afC, bC, afN) {                                             \
    STAGE((kt_) + 3);                                                         \
    asm volatile("s_waitcnt vmcnt(%0)" :: "n"(NWN + 4) : "memory");           \
    __builtin_amdgcn_s_barrier();                                             \
    __builtin_amdgcn_sched_barrier(0);                                        \
    RD(afN, (kt_) + 1)                                                        \
    __builtin_amdgcn_sched_barrier(0);                                        \
    __builtin_amdgcn_s_setprio(1);                                            \
    _Pragma("unroll")                                                         \
    for (int i = 0; i < 8; ++i)                                               \
      _Pragma("unroll")                                                       \
      for (int j = 0; j < NWN; ++j)                                           \
        acc[i][j] = MFMA16(afC[i], bC[j], acc[i][j]);                         \
    __builtin_amdgcn_s_setprio(0);                                            \
    LOADB(bC, (kt_) + 2)                                                      \
    asm volatile("s_waitcnt lgkmcnt(0)" ::: "memory");                        \
    __builtin_amdgcn_sched_barrier(0); }

  for (int kt = 0; kt < nkt; kt += 2) {
    ITER(kt, afA, bs0, afB)
    ITER(kt + 1, afB, bs1, afA)
  }
#undef ITER
#undef RD
#undef LOADB

  asm volatile("s_waitcnt vmcnt(0) lgkmcnt(0)" ::: "memory");
  __builtin_amdgcn_sched_barrier(0);
  KEEPV(bs0[0]); KEEPV(bs0[1]);
  if constexpr (NWN == 4) { KEEPV(bs0[2]); KEEPV(bs0[3]); }
  KEEPV(bs1[0]); KEEPV(bs1[1]);
  if constexpr (NWN == 4) { KEEPV(bs1[2]); KEEPV(bs1[3]); }
  KEEPV(afA[0]); KEEPV(afA[1]); KEEPV(afA[2]); KEEPV(afA[3]);
  KEEPV(afA[4]); KEEPV(afA[5]); KEEPV(afA[6]); KEEPV(afA[7]);
  KEEPV(afB[0]); KEEPV(afB[1]); KEEPV(afB[2]); KEEPV(afB[3]);
  KEEPV(afB[4]); KEEPV(afB[5]); KEEPV(afB[6]); KEEPV(afB[7]);

  const int r0 = mt * (NWM * 128) + wm + fq * 4;
  const int c0 = nt * BN + wn + fr;
#pragma unroll
  for (int i = 0; i < 8; ++i)
#pragma unroll
    for (int j = 0; j < NWN; ++j)
#pragma unroll
      for (int e = 0; e < 4; ++e)
        cstore(C, (size_t)(r0 + i * 16 + e) * N + c0 + j * 16, acc[i][j][e]);
}

// ---------------- beta / g (log-decay): [L,2048]@[2048,32] x2 + activations ----------------
__global__ __launch_bounds__(256)
void k_ba(const float* __restrict__ h, const float* __restrict__ Wb, const float* __restrict__ Wa,
          const float* __restrict__ A_log, const float* __restrict__ dtb,
          float* __restrict__ beta, float* __restrict__ g_out) {
  const int w = threadIdx.x >> 6, lane = threadIdx.x & 63;
  const int t = blockIdx.x * 4 + w;
  const int j = lane & 31;
  const bool isB = lane < 32;
  const float* __restrict__ hr = h + (size_t)t * DHID;
  const float* Wc = isB ? Wb : Wa;
  float acc = 0.f;
  for (int kk = 0; kk < DHID; ++kk) acc = fmaf(hr[kk], Wc[(size_t)kk * HVN + j], acc);
  if (isB) {
    beta[(size_t)t * HVN + j] = 1.f / (1.f + expf(-acc));
  } else {
    float xx = acc + dtb[j];
    float sp = (xx > 20.f) ? xx : log1pf(expf(xx));
    g_out[(size_t)t * HVN + j] = -expf(A_log[j]) * sp;   // g = log(decay) <= 0
  }
}

// ---------------- in-place l2norm of q (scaled) and k heads ----------------
__global__ __launch_bounds__(256)
void k_l2n(u16* __restrict__ qkvz) {
  const int w = threadIdx.x >> 6, lane = threadIdx.x & 63;
  const int r = blockIdx.x * 4 + w;
  const int isK = r >> 16;
  const int rr = r & 65535;
  const int t = rr >> 4, hd = rr & 15;
  u16* p = qkvz + (size_t)t * NTOT + isK * 2048 + hd * DKK + lane * 2;
  float a = b2f(p[0]), b = b2f(p[1]);
  float ss = a * a + b * b;
  ss = red16(ss);
  ss += __shfl_xor(ss, 16);
  ss += __shfl_xor(ss, 32);
  const float sc = rsqrtf(ss + 1e-6f) * (isK ? 1.f : 0.08838834764831845f);
  p[0] = f2bf(a * sc); p[1] = f2bf(b * sc);
}

// ---------------- chunk solve (parallel): per (hv, chunk n) ----------------
__global__ __launch_bounds__(256)
void k_r1(const u16* __restrict__ qkvz, const float* __restrict__ beta_g,
          const float* __restrict__ g_g, u16* __restrict__ UM_g, float* __restrict__ cumL_g) {
  const int pair = blockIdx.x;          // hv*64 + n
  const int hv = pair >> 6, n = pair & 63;
  const int hk = hv >> 1;
  const int t0 = n * 64;
  const int tid = threadIdx.x, lane = tid & 63, wv = tid >> 6;
  const int fr = lane & 15, fq = lane >> 4;

  __shared__ __align__(16) u16 Xb[256 * 64];
  __shared__ __align__(16) u16 Dbuf0[64 * 64 * 2];
  __shared__ __align__(16) u16 Dbuf1[64 * 64 * 2];
  __shared__ float Lc[64];
  __shared__ float Bc[64];
  u16* Kl = Dbuf0;

  const int j = tid & 63, h = tid >> 6;
  const u16* kg = qkvz + (size_t)(t0 + j) * NTOT + 2048 + hk * DKK + h * 32;
  const u16* vg = qkvz + (size_t)(t0 + j) * NTOT + 4096 + hv * DKK + h * 32;
  u16x8 kv[4], vv[4];
#pragma unroll
  for (int i = 0; i < 4; ++i) { kv[i] = *(const u16x8*)(kg + i * 8); vv[i] = *(const u16x8*)(vg + i * 8); }
  if (tid < 64) {
    Lc[tid] = g_g[(size_t)(t0 + tid) * HVN + hv];
    Bc[tid] = beta_g[(size_t)(t0 + tid) * HVN + hv];
  }
#pragma unroll
  for (int i = 0; i < 4; ++i) *(u16x8*)&Kl[sw16(j, h * 32 + i * 8, 128)] = kv[i];
  __syncthreads();
  if (tid == 0) { float a = 0.f; for (int t = 0; t < 64; ++t) { a += Lc[t]; Lc[t] = a; } }
  __syncthreads();
  if (tid < 64) cumL_g[(size_t)pair * 64 + tid] = Lc[tid];

  {
    const float bj = Bc[j];
    const float mj = bj * __expf(Lc[j]);
#pragma unroll
    for (int i = 0; i < 4; ++i)
#pragma unroll
      for (int e = 0; e < 8; ++e) {
        int c = h * 32 + i * 8 + e;
        Xb[sw16(c, j, 64)] = f2bf(bj * b2f(vv[i][e]));
        Xb[sw16(128 + c, j, 64)] = f2bf(mj * b2f(kv[i][e]));
      }
  }
  f32x4 kk[4] = {};
#pragma unroll
  for (int ks = 0; ks < 4; ++ks) {
    short8 afr = *(const short8*)&Kl[sw16(wv * 16 + fr, ks * 32 + fq * 8, 128)];
#pragma unroll
    for (int ct = 0; ct < 4; ++ct) {
      short8 bfr = *(const short8*)&Kl[sw16(ct * 16 + fr, ks * 32 + fq * 8, 128)];
      kk[ct] = MFMA16(afr, bfr, kk[ct]);
    }
  }
  __syncthreads();

  f32x4 acc[16];
#pragma unroll
  for (int ct = 0; ct < 16; ++ct) {
    u16x4 xi = *(const u16x4*)&Xb[sw16(ct * 16 + fr, wv * 16 + fq * 4, 64)];
    acc[ct][0] = b2f(xi[0]); acc[ct][1] = b2f(xi[1]); acc[ct][2] = b2f(xi[2]); acc[ct][3] = b2f(xi[3]);
  }
#pragma unroll
  for (int ct = 0; ct < 4; ++ct) {
    const int s = ct * 16 + fr;
    u16x4 pk;
#pragma unroll
    for (int e = 0; e < 4; ++e) {
      const int t = wv * 16 + fq * 4 + e;
      float v = (s < t) ? -Bc[t] * __expf(Lc[t] - Lc[s]) * kk[ct][e] : 0.f;
      pk[e] = f2bf(v);
      Dbuf0[sw16(t, s, 64)] = pk[e];
    }
    *(u16x4*)&Dbuf0[4096 + sw16(s, wv * 16 + fq * 4, 64)] = pk;
  }
  __syncthreads();

  u16* DA = Dbuf0;
  u16* DB = Dbuf1;
  for (int stg = 0; stg < 6; ++stg) {
    u16* Dr = DA;
    u16* Dc = DA + 4096;
    short8 da0 = *(const short8*)&Dr[sw16(wv * 16 + fr, 0 + fq * 8, 64)];
    short8 da1 = *(const short8*)&Dr[sw16(wv * 16 + fr, 32 + fq * 8, 64)];
#pragma unroll
    for (int ct = 0; ct < 16; ++ct) {
      short8 b0 = *(const short8*)&Xb[sw16(ct * 16 + fr, 0 + fq * 8, 64)];
      short8 b1 = *(const short8*)&Xb[sw16(ct * 16 + fr, 32 + fq * 8, 64)];
      acc[ct] = MFMA16(da0, b0, acc[ct]);
      acc[ct] = MFMA16(da1, b1, acc[ct]);
    }
    f32x4 sq[4] = {};
    if (stg < 5) {
#pragma unroll
      for (int ct = 0; ct < 4; ++ct) {
        short8 sb0 = *(const short8*)&Dc[sw16(ct * 16 + fr, 0 + fq * 8, 64)];
        short8 sb1 = *(const short8*)&Dc[sw16(ct * 16 + fr, 32 + fq * 8, 64)];
        sq[ct] = MFMA16(da0, sb0, sq[ct]);
        sq[ct] = MFMA16(da1, sb1, sq[ct]);
      }
    }
    __syncthreads();
#pragma unroll
    for (int ct = 0; ct < 16; ++ct) {
      u16x4 pk;
      pk[0] = f2bf(acc[ct][0]); pk[1] = f2bf(acc[ct][1]); pk[2] = f2bf(acc[ct][2]); pk[3] = f2bf(acc[ct][3]);
      *(u16x4*)&Xb[sw16(ct * 16 + fr, wv * 16 + fq * 4, 64)] = pk;
    }
    if (stg < 5) {
#pragma unroll
      for (int ct = 0; ct < 4; ++ct) {
        u16x4 pk;
        pk[0] = f2bf(sq[ct][0]); pk[1] = f2bf(sq[ct][1]); pk[2] = f2bf(sq[ct][2]); pk[3] = f2bf(sq[ct][3]);
        *(u16x4*)&(DB + 4096)[sw16(ct * 16 + fr, wv * 16 + fq * 4, 64)] = pk;
#pragma unroll
        for (int e = 0; e < 4; ++e) DB[sw16(wv * 16 + fq * 4 + e, ct * 16 + fr, 64)] = pk[e];
      }
    }
    __syncthreads();
    u16* tmp = DA; DA = DB; DB = tmp;
  }

#pragma unroll
  for (int ct = 0; ct < 16; ++ct) {
    const int c = ct * 16 + fr;
#pragma unroll
    for (int e = 0; e < 4; ++e) {
      const int t = wv * 16 + fq * 4 + e;
      float v = acc[ct][e];
      if (ct >= 8) v = -v;
      UM_g[((size_t)pair * 64 + t) * 256 + c] = f2bf(v);
    }
  }
}

// ---------------- sequential chunk scan: 128 blocks = (hv, dv-quarter cs) ----------------
// R17: Q/M/K MFMA operands live ONLY in registers - each thread loads its wave's private
// fragments directly from global in PREF (one chunk ahead; coalesced 64B lines for Q/M,
// d16 column loads for K). Ql2/Ml2/Kt2 LDS buffers deleted (119KB -> 20KB); only the
// cross-wave tiles (dT, dT2, o1b, SbT) remain in LDS. Register A/B sets, x2-unrolled
// chunk loop (rule #20). Arithmetic identical to R16.
__global__ __launch_bounds__(512)
void k_r2(u16* __restrict__ qkvz, const u16* __restrict__ UM_g,
          const float* __restrict__ cumL_g, u16* __restrict__ o1_g) {
  const int hv = blockIdx.x >> 2, cs = blockIdx.x & 3;
  const int hk = hv >> 1;
  const int tid = threadIdx.x, lane = tid & 63, w = tid >> 6;   // 8 waves
  const int fr = lane & 15, fq = lane >> 4;
  const int tw = w & 3, dwv = w >> 2;                            // ph1 tile coords

  __shared__ __align__(16) u16 dT[2048];       // delta^T [32 ldv][64 t] swz (raw)
  __shared__ __align__(16) u16 dT2[2048];      // delta^T * e^{L63-Lt} swz
  __shared__ __align__(16) u16 o1b[2048];      // o1 [32 ldv][64 t] swz
  __shared__ __align__(16) u16 SbT[4096];      // S^T [32 ldv][128 dk] swz

  f32x4 sacc[2];
#pragma unroll
  for (int d = 0; d < 2; ++d) sacc[d] = (f32x4){0.f, 0.f, 0.f, 0.f};
  for (int i = tid; i < 4096; i += 512) SbT[i] = 0;

  u16x8 QA[4], MA[4], QB[4], MB[4], KA0, KA1, KB0, KB1;
  u16 UA[4], UB[4];
  float LA4[4], LB4[4], LA63, LB63;

  // per-thread private fragment loads, issued one chunk ahead:
  //  Q/M: A-operand rows tw*16+fr, cols ks*32+fq*8 (4x u16x8, 64B-line coalesced)
  //  K:   S-update A-operand dk=w*16+fr, t=fq*8+e / 32+fq*8+e (16 d16 column loads)
  //  U:   4 scalars; L: cumL[tw*16+fq*4+e] + L63
#define PREF(nn, Q, Mv, K0, K1, U, L4, L63v) {                                \
    const int nc = ((nn) < 64) ? (nn) : 63;                                   \
    const int pr = hv * 64 + nc; const int tt0 = nc * 64;                     \
    const u16* qg = qkvz + (size_t)(tt0 + tw * 16 + fr) * NTOT + hk * DKK + fq * 8; \
    Q[0] = *(const u16x8*)qg;        Q[1] = *(const u16x8*)(qg + 32);         \
    Q[2] = *(const u16x8*)(qg + 64); Q[3] = *(const u16x8*)(qg + 96);         \
    const u16* mg = UM_g + ((size_t)pr * 64 + tw * 16 + fr) * 256 + 128 + fq * 8; \
    Mv[0] = *(const u16x8*)mg;        Mv[1] = *(const u16x8*)(mg + 32);       \
    Mv[2] = *(const u16x8*)(mg + 64); Mv[3] = *(const u16x8*)(mg + 96);       \
    const u16* ug = UM_g + ((size_t)pr * 64 + tw * 16 + fq * 4) * 256         \
                    + cs * 32 + dwv * 16 + fr;                                \
    U[0] = ug[0]; U[1] = ug[256]; U[2] = ug[512]; U[3] = ug[768];             \
    const u16* kg = qkvz + (size_t)(tt0 + fq * 8) * NTOT + 2048 + hk * DKK + w * 16 + fr; \
    _Pragma("unroll")                                                         \
    for (int e = 0; e < 8; ++e) {                                             \
      K0[e] = kg[(size_t)e * NTOT];                                           \
      K1[e] = kg[(size_t)(32 + e) * NTOT];                                    \
    }                                                                         \
    _Pragma("unroll")                                                         \
    for (int e = 0; e < 4; ++e) L4[e] = cumL_g[(size_t)pr * 64 + tw * 16 + fq * 4 + e]; \
    L63v = cumL_g[(size_t)pr * 64 + 63]; }

#define PH1(Q, Mv, U, L4, L63v) {                                             \
    float el[4], el2[4];                                                      \
    _Pragma("unroll")                                                         \
    for (int e = 0; e < 4; ++e) {                                             \
      el[e] = __expf(L4[e]);                                                  \
      el2[e] = __expf(L63v - L4[e]);                                          \
    }                                                                         \
    f32x4 dc;                                                                 \
    dc[0] = b2f(U[0]); dc[1] = b2f(U[1]); dc[2] = b2f(U[2]); dc[3] = b2f(U[3]); \
    f32x4 oc = {};                                                            \
    _Pragma("unroll")                                                         \
    for (int ks = 0; ks < 4; ++ks) {                                          \
      short8 bs = *(const short8*)&SbT[sw16(dwv * 16 + fr, ks * 32 + fq * 8, 128)]; \
      dc = MFMA16(__builtin_bit_cast(short8, Mv[ks]), bs, dc);                \
      oc = MFMA16(__builtin_bit_cast(short8, Q[ks]), bs, oc);                 \
    }                                                                         \
    u16x4 pkd, pkd2, pko;                                                     \
    _Pragma("unroll")                                                         \
    for (int e = 0; e < 4; ++e) {                                             \
      pkd[e]  = f2bf(dc[e]);                                                  \
      pkd2[e] = f2bf(dc[e] * el2[e]);                                         \
      pko[e]  = f2bf(oc[e] * el[e]);                                          \
    }                                                                         \
    *(u16x4*)&dT[sw16(dwv * 16 + fr, tw * 16 + fq * 4, 64)] = pkd;            \
    *(u16x4*)&dT2[sw16(dwv * 16 + fr, tw * 16 + fq * 4, 64)] = pkd2;          \
    *(u16x4*)&o1b[sw16(dwv * 16 + fr, tw * 16 + fq * 4, 64)] = pko; }

#define PH2(K0, K1, L63v, t0_, pair_) {                                       \
    {                                                                         \
      const int i = tid * 4;                                                  \
      u16x4 vd = *(const u16x4*)&dT[i];                                       \
      const int f = cs * 2048 + i;                                            \
      *(u16x4*)(qkvz + (size_t)((t0_) + (f >> 7)) * NTOT + 4096 + hv * DKK + (f & 127)) = vd; \
      u16x4 vo = *(const u16x4*)&o1b[i];                                      \
      *(u16x4*)(o1_g + (size_t)(pair_) * 8192 + cs * 2048 + i) = vo;          \
    }                                                                         \
    const float eC = __expf(L63v);                                            \
    short8 ak0 = __builtin_bit_cast(short8, K0);                              \
    short8 ak1 = __builtin_bit_cast(short8, K1);                              \
    _Pragma("unroll")                                                         \
    for (int d = 0; d < 2; ++d) {                                             \
      short8 bd0 = *(const short8*)&dT2[sw16(d * 16 + fr, fq * 8, 64)];       \
      short8 bd1 = *(const short8*)&dT2[sw16(d * 16 + fr, 32 + fq * 8, 64)];  \
      f32x4 sa = sacc[d];                                                     \
      _Pragma("unroll")                                                       \
      for (int e = 0; e < 4; ++e) sa[e] *= eC;                                \
      sa = MFMA16(ak0, bd0, sa);                                              \
      sa = MFMA16(ak1, bd1, sa);                                              \
      sacc[d] = sa;                                                           \
      u16x4 pk;                                                               \
      pk[0] = f2bf(sa[0]); pk[1] = f2bf(sa[1]); pk[2] = f2bf(sa[2]); pk[3] = f2bf(sa[3]); \
      *(u16x4*)&SbT[sw16(d * 16 + fr, w * 16 + fq * 4, 128)] = pk;            \
    }                                                                         \
  }

  PREF(0, QA, MA, KA0, KA1, UA, LA4, LA63)
  __syncthreads();   // SbT zero-init visible

  for (int n = 0; n < 64; n += 2) {
    {
      PREF(n + 1, QB, MB, KB0, KB1, UB, LB4, LB63)
      PH1(QA, MA, UA, LA4, LA63)
      __syncthreads();
      const int t0 = n * 64, pair = hv * 64 + n;
      PH2(KA0, KA1, LA63, t0, pair)
      __syncthreads();
    }
    {
      PREF(n + 2, QA, MA, KA0, KA1, UA, LA4, LA63)
      PH1(QB, MB, UB, LB4, LB63)
      __syncthreads();
      const int t0 = (n + 1) * 64, pair = hv * 64 + n + 1;
      PH2(KB0, KB1, LB63, t0, pair)
      __syncthreads();
    }
  }
#undef PREF
#undef PH1
#undef PH2
}

// ---------------- parallel epilogue: o = o1 + G@delta, fused gated RMSNorm ----------------
__global__ __launch_bounds__(512)
void k_r3(const u16* __restrict__ qkvz, const u16* __restrict__ o1_g,
          const float* __restrict__ cumL_g, const float* __restrict__ nw,
          u16* __restrict__ x) {
  const int pair = blockIdx.x, hv = pair >> 6, n = pair & 63, hk = hv >> 1, t0 = n * 64;
  const int tid = threadIdx.x, lane = tid & 63, w = tid >> 6;
  const int fr = lane & 15, fq = lane >> 4;
  const int j = tid & 63, h = tid >> 6;   // h 0..7

  __shared__ __align__(16) u16 Ql[8192];
  __shared__ __align__(16) u16 Kl[8192];
  __shared__ __align__(16) u16 Gl[4096];
  __shared__ __align__(16) u16 dTl[8192];
  __shared__ __align__(16) u16 o1l[8192];      // o1 [dv][t] swz (raw block from k_r2)
  __shared__ __align__(16) float of[64 * 132];
  __shared__ float Lc[64];
  __shared__ float Lw[128];

  {
    const u16* qg = qkvz + (size_t)(t0 + j) * NTOT + hk * DKK + h * 16;
    u16x8 q0 = *(const u16x8*)qg, q1 = *(const u16x8*)(qg + 8);
    u16x8 k0 = *(const u16x8*)(qg + 2048), k1 = *(const u16x8*)(qg + 2056);
    *(u16x8*)&Ql[sw16(j, h * 16, 128)] = q0;
    *(u16x8*)&Ql[sw16(j, h * 16 + 8, 128)] = q1;
    *(u16x8*)&Kl[sw16(j, h * 16, 128)] = k0;
    *(u16x8*)&Kl[sw16(j, h * 16 + 8, 128)] = k1;
  }
#pragma unroll
  for (int it = 0; it < 2; ++it) {
    const int f = ((w * 2 + it) * 64 + lane) * 8;
    gld16(qkvz + (size_t)(t0 + (f >> 7)) * NTOT + 4096 + hv * DKK + (f & 127),
          (char*)dTl + (w * 2 + it) * 1024);
    gld16(o1_g + (size_t)pair * 8192 + f, (char*)o1l + (w * 2 + it) * 1024);
  }
  if (tid < 64) Lc[tid] = cumL_g[(size_t)pair * 64 + tid];
  if (tid < 128) Lw[tid] = nw[tid];
  __syncthreads();

  // ---- G = tril(e^{Lt-Ls} * QK^T) ----
  const int tw = w & 3, sp = (w >> 2) * 2;
  {
    f32x4 kk0 = {}, kk1 = {};
#pragma unroll
    for (int ks = 0; ks < 4; ++ks) {
      short8 aq = *(const short8*)&Ql[sw16(tw * 16 + fr, ks * 32 + fq * 8, 128)];
      short8 b0 = *(const short8*)&Kl[sw16(sp * 16 + fr, ks * 32 + fq * 8, 128)];
      short8 b1 = *(const short8*)&Kl[sw16((sp + 1) * 16 + fr, ks * 32 + fq * 8, 128)];
      kk0 = MFMA16(aq, b0, kk0);
      kk1 = MFMA16(aq, b1, kk1);
    }
#pragma unroll
    for (int e = 0; e < 4; ++e) {
      const int t = tw * 16 + fq * 4 + e;
      const float Lt = Lc[t];
      const int s0 = sp * 16 + fr, s1 = s0 + 16;
      Gl[sw16(t, s0, 64)] = f2bf((s0 <= t) ? kk0[e] * __expf(Lt - Lc[s0]) : 0.f);
      Gl[sw16(t, s1, 64)] = f2bf((s1 <= t) ? kk1[e] * __expf(Lt - Lc[s1]) : 0.f);
    }
  }
  __syncthreads();

  // ---- o = G@delta ----
  {
    short8 ag0 = *(const short8*)&Gl[sw16(tw * 16 + fr, fq * 8, 64)];
    short8 ag1 = *(const short8*)&Gl[sw16(tw * 16 + fr, 32 + fq * 8, 64)];
#pragma unroll
    for (int dd = 0; dd < 4; ++dd) {
      const int d = (w >> 2) * 4 + dd;
      short8 bd0 = *(const short8*)&dTl[sw16(d * 16 + fr, fq * 8, 64)];
      short8 bd1 = *(const short8*)&dTl[sw16(d * 16 + fr, 32 + fq * 8, 64)];
      f32x4 oc = {};
      oc = MFMA16(ag0, bd0, oc);
      oc = MFMA16(ag1, bd1, oc);
#pragma unroll
      for (int e = 0; e < 4; ++e) of[(tw * 16 + fq * 4 + e) * 132 + d * 16 + fr] = oc[e];
    }
  }
  __syncthreads();

  // ---- fused gated RMSNorm: x = rmsnorm((of + o1) * silu(z)) * w ----
  {
    const int t = tid >> 3, q8 = tid & 7;
    const u16* zp = qkvz + (size_t)(t0 + t) * NTOT + 8192 + hv * DKK + q8 * 16;
    float xv[16];
    float ss = 0.f;
#pragma unroll
    for (int i = 0; i < 2; ++i) {
      u16x8 zv = *(const u16x8*)(zp + i * 8);
#pragma unroll
      for (int e = 0; e < 8; ++e) {
        const int dv = q8 * 16 + i * 8 + e;
        float z = b2f(zv[e]);
        float o = of[t * 132 + dv] + b2f(o1l[sw16(dv, t, 64)]);
        float xx = o * (z / (1.f + __expf(-z)));
        xv[i * 8 + e] = xx;
        ss = fmaf(xx, xx, ss);
      }
    }
    ss += __shfl_xor(ss, 1);
    ss += __shfl_xor(ss, 2);
    ss += __shfl_xor(ss, 4);
    const float scl = rsqrtf(ss * (1.f / 128.f) + 1e-6f);
    u16* xo = x + (size_t)(t0 + t) * 4096 + hv * DKK + q8 * 16;
#pragma unroll
    for (int i = 0; i < 2; ++i) {
      u16x8 pk;
#pragma unroll
      for (int e = 0; e < 8; ++e) pk[e] = f2bf(xv[i * 8 + e] * scl * Lw[q8 * 16 + i * 8 + e]);
      *(u16x8*)(xo + i * 8) = pk;
    }
  }
}

extern "C" void kernel_launch(void* const* d_in, const int* in_sizes, int n_in,
                              void* d_out, int out_size, void* d_ws, size_t ws_size,
                              hipStream_t stream) {
  const float* h    = (const float*)d_in[0];
  const float* Wq   = (const float*)d_in[1];
  const float* Wk   = (const float*)d_in[2];
  const float* Wv   = (const float*)d_in[3];
  const float* Wz   = (const float*)d_in[4];
  const float* Wb   = (const float*)d_in[5];
  const float* Wa   = (const float*)d_in[6];
  const float* Alog = (const float*)d_in[7];
  const float* dtb  = (const float*)d_in[8];
  const float* nw   = (const float*)d_in[9];
  const float* Wo   = (const float*)d_in[10];
  char* ws = (char*)d_ws;
  u16* h_bf  = (u16*)(ws);
  u16* Bfq   = (u16*)(ws + 16777216ull);      // [768 j16][64 kt][512] bf16 = 50.33MB
  u16* UM    = (u16*)(ws);                    // [2048][64][256] bf16 = 64MB (after GEMM)
  u16* Bfo   = (u16*)(ws + 67108864ull);      // [128 j16][128 kt][512] bf16 = 16.8MB
  u16* qkvz  = (u16*)(ws + 83886080ull);
  u16* o1g   = (u16*)(ws + 184549376ull);     // [2048][128dv][64t] bf16 = 32MB
  u16* xbuf  = (u16*)(ws + 16777216ull);      // aliases Bfq (dead after qkvz GEMM)
  float* beta  = (float*)(ws + 218103808ull);
  float* g     = (float*)(ws + 218103808ull + 524288ull);
  float* cumL  = (float*)(ws + 218103808ull + 1048576ull);

  k_cvt<<<8192, 256, 0, stream>>>(h, h_bf, LTOK * DHID);
  k_trf<<<2048, 256, 0, stream>>>(Wq, Bfq, 2048, 64, 0);
  k_trf<<<2048, 256, 0, stream>>>(Wk, Bfq, 2048, 64, 128);
  k_trf<<<4096, 256, 0, stream>>>(Wv, Bfq, 4096, 64, 256);
  k_trf<<<4096, 256, 0, stream>>>(Wz, Bfq, 4096, 64, 512);
  k_trf<<<4096, 256, 0, stream>>>(Wo, Bfo, 2048, 128, 0);
  k_g256<u16, 2, 4><<<768, 512, 0, stream>>>(h_bf, Bfq, qkvz, 4096, 12288, 2048, 48);
  k_ba<<<1024, 256, 0, stream>>>(h, Wb, Wa, Alog, dtb, beta, g);
  k_l2n<<<32768, 256, 0, stream>>>(qkvz);
  k_r1<<<2048, 256, 0, stream>>>(qkvz, beta, g, UM, cumL);
  k_r2<<<128, 512, 0, stream>>>(qkvz, UM, cumL, o1g);
  k_r3<<<2048, 512, 0, stream>>>(qkvz, o1g, cumL, nw, xbuf);
  k_g256<float, 1, 2><<<512, 256, 0, stream>>>(xbuf, Bfo, (float*)d_out, 4096, 2048, 4096, 16);
}

// Round 18
// 758.961 us; speedup vs baseline: 1.0809x; 1.0445x over previous
//
#include <hip/hip_runtime.h>

#define LTOK 4096
#define DHID 2048
#define HKN  16
#define HVN  32
#define DKK  128
#define NTOT 12288

typedef unsigned short u16;
typedef __attribute__((ext_vector_type(8))) short short8;
typedef __attribute__((ext_vector_type(8))) unsigned short u16x8;
typedef __attribute__((ext_vector_type(4))) unsigned short u16x4;
typedef __attribute__((ext_vector_type(4))) float f32x4;

__device__ __forceinline__ float b2f(u16 u) {
  unsigned int x = ((unsigned int)u) << 16;
  return __builtin_bit_cast(float, x);
}
__device__ __forceinline__ u16 f2bf(float f) {
  unsigned int u = __builtin_bit_cast(unsigned int, f);
  u += 0x7FFFu + ((u >> 16) & 1u);
  return (u16)(u >> 16);
}

template<int C> __device__ __forceinline__ float dppmv(float x) {
  int i = __builtin_amdgcn_update_dpp(0, __builtin_bit_cast(int, x), C, 0xF, 0xF, true);
  return __builtin_bit_cast(float, i);
}
__device__ __forceinline__ float red16(float x) {
  x += dppmv<0xB1>(x);
  x += dppmv<0x4E>(x);
  x += dppmv<0x124>(x);
  x += dppmv<0x128>(x);
  return x;
}

__device__ __forceinline__ void gld16(const void* g, void* l) {
  __builtin_amdgcn_global_load_lds((const __attribute__((address_space(1))) void*)g,
                                   (__attribute__((address_space(3))) void*)l, 16, 0, 0);
}

// pinned-order LDS vector read (addr VGPR + compile-time byte offset)
template<int OFF> __device__ __forceinline__ short8 dsr(unsigned a) {
  short8 r;
  asm volatile("ds_read_b128 %0, %1 offset:%2" : "=v"(r) : "v"(a), "n"(OFF));
  return r;
}
// pinned-order global vector load to VGPR (B fragments; counted in vmcnt manually)
__device__ __forceinline__ short8 gldx4(const u16* p) {
  short8 r;
  asm volatile("global_load_dwordx4 %0, %1, off" : "=v"(r) : "v"(p));
  return r;
}
// keep a register value live (rule #17) - blocks allocator reuse until this point
#define KEEPV(x) asm volatile("" :: "v"(x))

// swizzled LDS element offsets (XOR row-bits into 16B-slot bits); byte^=((r&7)<<4)
__device__ __forceinline__ int sw16(int r, int c, int rowc) { return (r * rowc + c) ^ ((r & 7) << 3); }

__device__ __forceinline__ void cstore(u16* C, size_t i, float v) { C[i] = f2bf(v); }
__device__ __forceinline__ void cstore(float* C, size_t i, float v) { C[i] = v; }

// ---------------- fp32 -> bf16 convert ----------------
__global__ __launch_bounds__(256)
void k_cvt(const float* __restrict__ s, u16* __restrict__ d, int n) {
  const int i = (blockIdx.x * 256 + threadIdx.x) * 4;
  const float4 v = *(const float4*)(s + i);
  ushort4 o;
  o.x = f2bf(v.x); o.y = f2bf(v.y); o.z = f2bf(v.z); o.w = f2bf(v.w);
  *(ushort4*)(d + i) = o;
}

// ---------------- fp32 W[K][N] -> bf16 B-fragment-major layout ----------------
__global__ __launch_bounds__(256)
void k_trf(const float* __restrict__ W, u16* __restrict__ Bf, int Ncols, int nkt, int j16base) {
  const int wv = threadIdx.x >> 6, lane = threadIdx.x & 63;
  const int frag = blockIdx.x * 4 + wv;
  const int j16 = frag / nkt, kt = frag % nkt;
  const int r0 = kt * 32 + (lane >> 4) * 8;
  const int c = j16 * 16 + (lane & 15);
  u16x8 o;
#pragma unroll
  for (int e = 0; e < 8; ++e) o[e] = f2bf(W[(size_t)(r0 + e) * Ncols + c]);
  *(u16x8*)(Bf + ((size_t)(j16base + j16) * nkt + kt) * 512 + lane * 8) = o;
}

#define MFMA16(a, b, c) __builtin_amdgcn_mfma_f32_16x16x32_bf16(a, b, c, 0, 0, 0)

// ---------------- (NWM*128)xBN bf16 MFMA GEMM, B-from-global (flatmm) ----------------
template<typename OutT, int NWM, int NWN>
__global__ __launch_bounds__(NWM * 256, 2)
void k_g256(const u16* __restrict__ A, const u16* __restrict__ Bf, OutT* __restrict__ C,
            int M, int N, int K, int NT) {
  constexpr int BN = NWN * 64;
  constexpr int BUFE = NWM * 4096;           // A elems per LDS buffer
  __shared__ u16 Lds[4 * BUFE];
  const int tid = threadIdx.x;
  const int lane = tid & 63, w = tid >> 6;
  const int fr = lane & 15, fq = lane >> 4;
  const int wm = (w >> 2) * 128, wn = (w & 3) * (NWN * 16);
  const int nkt = K >> 5;
  const size_t sK = (size_t)K;

  // supertile + XCD-aware ordering (bijective; gridDim.x % 8 == 0)
  const int MT = gridDim.x / NT;
  const int nts = (NT < 16) ? NT : 16;
  const int per_super = MT * nts;
  const int super = blockIdx.x / per_super;
  const int within = blockIdx.x % per_super;
  const int mtg = MT >> 3;
  const int q = within >> 3;
  const int mt = (within & 7) * mtg + (q % mtg);
  const int nt = super * nts + q / mtg;

  // A staging: thread covers row tid/4 (+NWM*64 for 2nd load); k-slot pre-swizzled (T2)
  const int kslot = ((tid & 3) ^ ((tid >> 3) & 3)) * 8;
  const u16* aS = A + (size_t)(mt * (NWM * 128) + (tid >> 2)) * sK + kslot;

  // B fragment base pointers (compile-time-indexed -> registers, rule #20)
  const int jw = nt * (BN / 16) + (w & 3) * NWN;
  const u16* bp[NWN];
#pragma unroll
  for (int j = 0; j < NWN; ++j) bp[j] = Bf + ((size_t)(jw + j) * nkt) * 512 + lane * 8;

  f32x4 acc[8][NWN] = {};

  auto STAGE = [&](int kt_) {
    const int sk = (kt_ < nkt) ? kt_ : nkt - 1;
    u16* base = &Lds[(kt_ & 3) * BUFE];
    gld16(aS + (size_t)sk * 32, base + tid * 8);
    gld16(aS + (size_t)(NWM * 64) * sK + (size_t)sk * 32, base + NWM * 2048 + tid * 8);
  };

#define LOADB(bset, kt_) {                                                    \
    const int sk2 = ((kt_) < nkt) ? (kt_) : (nkt - 1);                        \
    _Pragma("unroll")                                                         \
    for (int j = 0; j < NWN; ++j) bset[j] = gldx4(bp[j] + (size_t)sk2 * 512); }

  const int akey = (fr >> 1) & 3;            // read-side swizzle key
  const unsigned ldsBase = (unsigned)(size_t)(__attribute__((address_space(3))) void*)&Lds[0];
  const unsigned aA0 = ldsBase + 2u * (unsigned)((wm + fr) * 32 + ((fq ^ akey) << 3));

  short8 afA[8], afB[8], bs0[NWN], bs1[NWN];

#define RD(afX, kt_) {                                                        \
    const unsigned aAr = aA0 + (unsigned)(((kt_) & 3) * (BUFE * 2));          \
    afX[0] = dsr<0>(aAr);    afX[1] = dsr<1024>(aAr);                         \
    afX[2] = dsr<2048>(aAr); afX[3] = dsr<3072>(aAr);                         \
    afX[4] = dsr<4096>(aAr); afX[5] = dsr<5120>(aAr);                         \
    afX[6] = dsr<6144>(aAr); afX[7] = dsr<7168>(aAr); }

  // prologue: A0..A2 staged, B0+B1 loaded, full drain, read A0 fragments
  STAGE(0); STAGE(1); STAGE(2);
  LOADB(bs0, 0)
  LOADB(bs1, 1)
  asm volatile("s_waitcnt vmcnt(0)" ::: "memory");
  __builtin_amdgcn_s_barrier();
  RD(afA, 0)
  asm volatile("s_waitcnt lgkmcnt(0)" ::: "memory");
  __builtin_amdgcn_sched_barrier(0);

#define ITER(kt_, afC, bC, afN) {                                             \
    STAGE((kt_) + 3);                                                         \
    asm volatile("s_waitcnt vmcnt(%0)" :: "n"(NWN + 4) : "memory");           \
    __builtin_amdgcn_s_barrier();                                             \
    __builtin_amdgcn_sched_barrier(0);                                        \
    RD(afN, (kt_) + 1)                                                        \
    __builtin_amdgcn_sched_barrier(0);                                        \
    __builtin_amdgcn_s_setprio(1);                                            \
    _Pragma("unroll")                                                         \
    for (int i = 0; i < 8; ++i)                                               \
      _Pragma("unroll")                                                       \
      for (int j = 0; j < NWN; ++j)                                           \
        acc[i][j] = MFMA16(afC[i], bC[j], acc[i][j]);                         \
    __builtin_amdgcn_s_setprio(0);                                            \
    LOADB(bC, (kt_) + 2)                                                      \
    asm volatile("s_waitcnt lgkmcnt(0)" ::: "memory");                        \
    __builtin_amdgcn_sched_barrier(0); }

  for (int kt = 0; kt < nkt; kt += 2) {
    ITER(kt, afA, bs0, afB)
    ITER(kt + 1, afB, bs1, afA)
  }
#undef ITER
#undef RD
#undef LOADB

  asm volatile("s_waitcnt vmcnt(0) lgkmcnt(0)" ::: "memory");
  __builtin_amdgcn_sched_barrier(0);
  KEEPV(bs0[0]); KEEPV(bs0[1]);
  if constexpr (NWN == 4) { KEEPV(bs0[2]); KEEPV(bs0[3]); }
  KEEPV(bs1[0]); KEEPV(bs1[1]);
  if constexpr (NWN == 4) { KEEPV(bs1[2]); KEEPV(bs1[3]); }
  KEEPV(afA[0]); KEEPV(afA[1]); KEEPV(afA[2]); KEEPV(afA[3]);
  KEEPV(afA[4]); KEEPV(afA[5]); KEEPV(afA[6]); KEEPV(afA[7]);
  KEEPV(afB[0]); KEEPV(afB[1]); KEEPV(afB[2]); KEEPV(afB[3]);
  KEEPV(afB[4]); KEEPV(afB[5]); KEEPV(afB[6]); KEEPV(afB[7]);

  const int r0 = mt * (NWM * 128) + wm + fq * 4;
  const int c0 = nt * BN + wn + fr;
#pragma unroll
  for (int i = 0; i < 8; ++i)
#pragma unroll
    for (int j = 0; j < NWN; ++j)
#pragma unroll
      for (int e = 0; e < 4; ++e)
        cstore(C, (size_t)(r0 + i * 16 + e) * N + c0 + j * 16, acc[i][j][e]);
}

// ---------------- beta / g (log-decay): [L,2048]@[2048,32] x2 + activations ----------------
__global__ __launch_bounds__(256)
void k_ba(const float* __restrict__ h, const float* __restrict__ Wb, const float* __restrict__ Wa,
          const float* __restrict__ A_log, const float* __restrict__ dtb,
          float* __restrict__ beta, float* __restrict__ g_out) {
  const int w = threadIdx.x >> 6, lane = threadIdx.x & 63;
  const int t = blockIdx.x * 4 + w;
  const int j = lane & 31;
  const bool isB = lane < 32;
  const float* __restrict__ hr = h + (size_t)t * DHID;
  const float* Wc = isB ? Wb : Wa;
  float acc = 0.f;
  for (int kk = 0; kk < DHID; ++kk) acc = fmaf(hr[kk], Wc[(size_t)kk * HVN + j], acc);
  if (isB) {
    beta[(size_t)t * HVN + j] = 1.f / (1.f + expf(-acc));
  } else {
    float xx = acc + dtb[j];
    float sp = (xx > 20.f) ? xx : log1pf(expf(xx));
    g_out[(size_t)t * HVN + j] = -expf(A_log[j]) * sp;   // g = log(decay) <= 0
  }
}

// ---------------- in-place l2norm of q (scaled) and k heads ----------------
__global__ __launch_bounds__(256)
void k_l2n(u16* __restrict__ qkvz) {
  const int w = threadIdx.x >> 6, lane = threadIdx.x & 63;
  const int r = blockIdx.x * 4 + w;
  const int isK = r >> 16;
  const int rr = r & 65535;
  const int t = rr >> 4, hd = rr & 15;
  u16* p = qkvz + (size_t)t * NTOT + isK * 2048 + hd * DKK + lane * 2;
  float a = b2f(p[0]), b = b2f(p[1]);
  float ss = a * a + b * b;
  ss = red16(ss);
  ss += __shfl_xor(ss, 16);
  ss += __shfl_xor(ss, 32);
  const float sc = rsqrtf(ss + 1e-6f) * (isK ? 1.f : 0.08838834764831845f);
  p[0] = f2bf(a * sc); p[1] = f2bf(b * sc);
}

// ---------------- chunk solve (parallel): per (hv, chunk n) ----------------
__global__ __launch_bounds__(256)
void k_r1(const u16* __restrict__ qkvz, const float* __restrict__ beta_g,
          const float* __restrict__ g_g, u16* __restrict__ UM_g, float* __restrict__ cumL_g) {
  const int pair = blockIdx.x;          // hv*64 + n
  const int hv = pair >> 6, n = pair & 63;
  const int hk = hv >> 1;
  const int t0 = n * 64;
  const int tid = threadIdx.x, lane = tid & 63, wv = tid >> 6;
  const int fr = lane & 15, fq = lane >> 4;

  __shared__ __align__(16) u16 Xb[256 * 64];
  __shared__ __align__(16) u16 Dbuf0[64 * 64 * 2];
  __shared__ __align__(16) u16 Dbuf1[64 * 64 * 2];
  __shared__ float Lc[64];
  __shared__ float Bc[64];
  u16* Kl = Dbuf0;

  const int j = tid & 63, h = tid >> 6;
  const u16* kg = qkvz + (size_t)(t0 + j) * NTOT + 2048 + hk * DKK + h * 32;
  const u16* vg = qkvz + (size_t)(t0 + j) * NTOT + 4096 + hv * DKK + h * 32;
  u16x8 kv[4], vv[4];
#pragma unroll
  for (int i = 0; i < 4; ++i) { kv[i] = *(const u16x8*)(kg + i * 8); vv[i] = *(const u16x8*)(vg + i * 8); }
  if (tid < 64) {
    Lc[tid] = g_g[(size_t)(t0 + tid) * HVN + hv];
    Bc[tid] = beta_g[(size_t)(t0 + tid) * HVN + hv];
  }
#pragma unroll
  for (int i = 0; i < 4; ++i) *(u16x8*)&Kl[sw16(j, h * 32 + i * 8, 128)] = kv[i];
  __syncthreads();
  if (tid == 0) { float a = 0.f; for (int t = 0; t < 64; ++t) { a += Lc[t]; Lc[t] = a; } }
  __syncthreads();
  if (tid < 64) cumL_g[(size_t)pair * 64 + tid] = Lc[tid];

  {
    const float bj = Bc[j];
    const float mj = bj * __expf(Lc[j]);
#pragma unroll
    for (int i = 0; i < 4; ++i)
#pragma unroll
      for (int e = 0; e < 8; ++e) {
        int c = h * 32 + i * 8 + e;
        Xb[sw16(c, j, 64)] = f2bf(bj * b2f(vv[i][e]));
        Xb[sw16(128 + c, j, 64)] = f2bf(mj * b2f(kv[i][e]));
      }
  }
  f32x4 kk[4] = {};
#pragma unroll
  for (int ks = 0; ks < 4; ++ks) {
    short8 afr = *(const short8*)&Kl[sw16(wv * 16 + fr, ks * 32 + fq * 8, 128)];
#pragma unroll
    for (int ct = 0; ct < 4; ++ct) {
      short8 bfr = *(const short8*)&Kl[sw16(ct * 16 + fr, ks * 32 + fq * 8, 128)];
      kk[ct] = MFMA16(afr, bfr, kk[ct]);
    }
  }
  __syncthreads();

  f32x4 acc[16];
#pragma unroll
  for (int ct = 0; ct < 16; ++ct) {
    u16x4 xi = *(const u16x4*)&Xb[sw16(ct * 16 + fr, wv * 16 + fq * 4, 64)];
    acc[ct][0] = b2f(xi[0]); acc[ct][1] = b2f(xi[1]); acc[ct][2] = b2f(xi[2]); acc[ct][3] = b2f(xi[3]);
  }
#pragma unroll
  for (int ct = 0; ct < 4; ++ct) {
    const int s = ct * 16 + fr;
    u16x4 pk;
#pragma unroll
    for (int e = 0; e < 4; ++e) {
      const int t = wv * 16 + fq * 4 + e;
      float v = (s < t) ? -Bc[t] * __expf(Lc[t] - Lc[s]) * kk[ct][e] : 0.f;
      pk[e] = f2bf(v);
      Dbuf0[sw16(t, s, 64)] = pk[e];
    }
    *(u16x4*)&Dbuf0[4096 + sw16(s, wv * 16 + fq * 4, 64)] = pk;
  }
  __syncthreads();

  u16* DA = Dbuf0;
  u16* DB = Dbuf1;
  for (int stg = 0; stg < 6; ++stg) {
    u16* Dr = DA;
    u16* Dc = DA + 4096;
    short8 da0 = *(const short8*)&Dr[sw16(wv * 16 + fr, 0 + fq * 8, 64)];
    short8 da1 = *(const short8*)&Dr[sw16(wv * 16 + fr, 32 + fq * 8, 64)];
#pragma unroll
    for (int ct = 0; ct < 16; ++ct) {
      short8 b0 = *(const short8*)&Xb[sw16(ct * 16 + fr, 0 + fq * 8, 64)];
      short8 b1 = *(const short8*)&Xb[sw16(ct * 16 + fr, 32 + fq * 8, 64)];
      acc[ct] = MFMA16(da0, b0, acc[ct]);
      acc[ct] = MFMA16(da1, b1, acc[ct]);
    }
    f32x4 sq[4] = {};
    if (stg < 5) {
#pragma unroll
      for (int ct = 0; ct < 4; ++ct) {
        short8 sb0 = *(const short8*)&Dc[sw16(ct * 16 + fr, 0 + fq * 8, 64)];
        short8 sb1 = *(const short8*)&Dc[sw16(ct * 16 + fr, 32 + fq * 8, 64)];
        sq[ct] = MFMA16(da0, sb0, sq[ct]);
        sq[ct] = MFMA16(da1, sb1, sq[ct]);
      }
    }
    __syncthreads();
#pragma unroll
    for (int ct = 0; ct < 16; ++ct) {
      u16x4 pk;
      pk[0] = f2bf(acc[ct][0]); pk[1] = f2bf(acc[ct][1]); pk[2] = f2bf(acc[ct][2]); pk[3] = f2bf(acc[ct][3]);
      *(u16x4*)&Xb[sw16(ct * 16 + fr, wv * 16 + fq * 4, 64)] = pk;
    }
    if (stg < 5) {
#pragma unroll
      for (int ct = 0; ct < 4; ++ct) {
        u16x4 pk;
        pk[0] = f2bf(sq[ct][0]); pk[1] = f2bf(sq[ct][1]); pk[2] = f2bf(sq[ct][2]); pk[3] = f2bf(sq[ct][3]);
        *(u16x4*)&(DB + 4096)[sw16(ct * 16 + fr, wv * 16 + fq * 4, 64)] = pk;
#pragma unroll
        for (int e = 0; e < 4; ++e) DB[sw16(wv * 16 + fq * 4 + e, ct * 16 + fr, 64)] = pk[e];
      }
    }
    __syncthreads();
    u16* tmp = DA; DA = DB; DB = tmp;
  }

#pragma unroll
  for (int ct = 0; ct < 16; ++ct) {
    const int c = ct * 16 + fr;
#pragma unroll
    for (int e = 0; e < 4; ++e) {
      const int t = wv * 16 + fq * 4 + e;
      float v = acc[ct][e];
      if (ct >= 8) v = -v;
      UM_g[((size_t)pair * 64 + t) * 256 + c] = f2bf(v);
    }
  }
}

// ---------------- sequential chunk scan: 256 blocks = (hv, dv-eighth cs), 4 waves ----------------
// R18: 8-way dv split (ldv=16) -> all 256 CUs active, per-wave serial work halved.
// Q/M/K register-only operands (R17); LDS only for cross-wave tiles (10KB).
// Wave w = t-tile tw=w for ph1; ph2: dk-tiles {w*32, w*32+16}.
__global__ __launch_bounds__(256)
void k_r2(u16* __restrict__ qkvz, const u16* __restrict__ UM_g,
          const float* __restrict__ cumL_g, u16* __restrict__ o1_g) {
  const int hv = blockIdx.x >> 3, cs = blockIdx.x & 7;
  const int hk = hv >> 1;
  const int tid = threadIdx.x, lane = tid & 63, w = tid >> 6;   // 4 waves
  const int fr = lane & 15, fq = lane >> 4;
  const int tw = w;                                              // ph1 t-tile 0..3

  __shared__ __align__(16) u16 dT[1024];       // delta^T [16 ldv][64 t] swz (raw)
  __shared__ __align__(16) u16 dT2[1024];      // delta^T * e^{L63-Lt} swz
  __shared__ __align__(16) u16 o1b[1024];      // o1 [16 ldv][64 t] swz
  __shared__ __align__(16) u16 SbT[2048];      // S^T [16 ldv][128 dk] swz

  f32x4 sacc[2];
#pragma unroll
  for (int d = 0; d < 2; ++d) sacc[d] = (f32x4){0.f, 0.f, 0.f, 0.f};
  for (int i = tid; i < 2048; i += 256) SbT[i] = 0;

  u16x8 QA[4], MA[4], QB[4], MB[4];
  u16x8 KA00, KA01, KA10, KA11, KB00, KB01, KB10, KB11;
  u16 UA[4], UB[4];
  float LA4[4], LB4[4], LA63, LB63;

  // per-thread private fragment loads, one chunk ahead:
  //  Q/M: rows tw*16+fr, cols ks*32+fq*8 (coalesced 64B lines)
  //  K:   dk in {w*32+fr, w*32+16+fr}, t = fq*8+e and 32+fq*8+e (32 d16 column loads)
  //  U:   4 scalars at col cs*16+fr; L: cumL[tw*16+fq*4+e] + L63
#define PREF(nn, Q, Mv, K00, K01, K10, K11, U, L4, L63v) {                    \
    const int nc = ((nn) < 64) ? (nn) : 63;                                   \
    const int pr = hv * 64 + nc; const int tt0 = nc * 64;                     \
    const u16* qg = qkvz + (size_t)(tt0 + tw * 16 + fr) * NTOT + hk * DKK + fq * 8; \
    Q[0] = *(const u16x8*)qg;        Q[1] = *(const u16x8*)(qg + 32);         \
    Q[2] = *(const u16x8*)(qg + 64); Q[3] = *(const u16x8*)(qg + 96);         \
    const u16* mg = UM_g + ((size_t)pr * 64 + tw * 16 + fr) * 256 + 128 + fq * 8; \
    Mv[0] = *(const u16x8*)mg;        Mv[1] = *(const u16x8*)(mg + 32);       \
    Mv[2] = *(const u16x8*)(mg + 64); Mv[3] = *(const u16x8*)(mg + 96);       \
    const u16* ug = UM_g + ((size_t)pr * 64 + tw * 16 + fq * 4) * 256         \
                    + cs * 16 + fr;                                           \
    U[0] = ug[0]; U[1] = ug[256]; U[2] = ug[512]; U[3] = ug[768];             \
    const u16* kg = qkvz + (size_t)(tt0 + fq * 8) * NTOT + 2048 + hk * DKK + w * 32 + fr; \
    _Pragma("unroll")                                                         \
    for (int e = 0; e < 8; ++e) {                                             \
      K00[e] = kg[(size_t)e * NTOT];                                          \
      K01[e] = kg[(size_t)(32 + e) * NTOT];                                   \
      K10[e] = kg[(size_t)e * NTOT + 16];                                     \
      K11[e] = kg[(size_t)(32 + e) * NTOT + 16];                              \
    }                                                                         \
    _Pragma("unroll")                                                         \
    for (int e = 0; e < 4; ++e) L4[e] = cumL_g[(size_t)pr * 64 + tw * 16 + fq * 4 + e]; \
    L63v = cumL_g[(size_t)pr * 64 + 63]; }

#define PH1(Q, Mv, U, L4, L63v) {                                             \
    float el[4], el2[4];                                                      \
    _Pragma("unroll")                                                         \
    for (int e = 0; e < 4; ++e) {                                             \
      el[e] = __expf(L4[e]);                                                  \
      el2[e] = __expf(L63v - L4[e]);                                          \
    }                                                                         \
    f32x4 dc;                                                                 \
    dc[0] = b2f(U[0]); dc[1] = b2f(U[1]); dc[2] = b2f(U[2]); dc[3] = b2f(U[3]); \
    f32x4 oc = {};                                                            \
    _Pragma("unroll")                                                         \
    for (int ks = 0; ks < 4; ++ks) {                                          \
      short8 bs = *(const short8*)&SbT[sw16(fr, ks * 32 + fq * 8, 128)];      \
      dc = MFMA16(__builtin_bit_cast(short8, Mv[ks]), bs, dc);                \
      oc = MFMA16(__builtin_bit_cast(short8, Q[ks]), bs, oc);                 \
    }                                                                         \
    u16x4 pkd, pkd2, pko;                                                     \
    _Pragma("unroll")                                                         \
    for (int e = 0; e < 4; ++e) {                                             \
      pkd[e]  = f2bf(dc[e]);                                                  \
      pkd2[e] = f2bf(dc[e] * el2[e]);                                         \
      pko[e]  = f2bf(oc[e] * el[e]);                                          \
    }                                                                         \
    *(u16x4*)&dT[sw16(fr, tw * 16 + fq * 4, 64)] = pkd;                       \
    *(u16x4*)&dT2[sw16(fr, tw * 16 + fq * 4, 64)] = pkd2;                     \
    *(u16x4*)&o1b[sw16(fr, tw * 16 + fq * 4, 64)] = pko; }

#define PH2(K00, K01, K10, K11, L63v, t0_, pair_) {                           \
    {                                                                         \
      const int i = tid * 4;                                                  \
      u16x4 vd = *(const u16x4*)&dT[i];                                       \
      const int f = cs * 1024 + i;                                            \
      *(u16x4*)(qkvz + (size_t)((t0_) + (f >> 7)) * NTOT + 4096 + hv * DKK + (f & 127)) = vd; \
      u16x4 vo = *(const u16x4*)&o1b[i];                                      \
      *(u16x4*)(o1_g + (size_t)(pair_) * 8192 + f) = vo;                      \
    }                                                                         \
    const float eC = __expf(L63v);                                            \
    short8 bd0 = *(const short8*)&dT2[sw16(fr, fq * 8, 64)];                  \
    short8 bd1 = *(const short8*)&dT2[sw16(fr, 32 + fq * 8, 64)];             \
    {                                                                         \
      f32x4 sa = sacc[0];                                                     \
      _Pragma("unroll")                                                       \
      for (int e = 0; e < 4; ++e) sa[e] *= eC;                                \
      sa = MFMA16(__builtin_bit_cast(short8, K00), bd0, sa);                  \
      sa = MFMA16(__builtin_bit_cast(short8, K01), bd1, sa);                  \
      sacc[0] = sa;                                                           \
      u16x4 pk;                                                               \
      pk[0] = f2bf(sa[0]); pk[1] = f2bf(sa[1]); pk[2] = f2bf(sa[2]); pk[3] = f2bf(sa[3]); \
      *(u16x4*)&SbT[sw16(fr, w * 32 + fq * 4, 128)] = pk;                     \
    }                                                                         \
    {                                                                         \
      f32x4 sa = sacc[1];                                                     \
      _Pragma("unroll")                                                       \
      for (int e = 0; e < 4; ++e) sa[e] *= eC;                                \
      sa = MFMA16(__builtin_bit_cast(short8, K10), bd0, sa);                  \
      sa = MFMA16(__builtin_bit_cast(short8, K11), bd1, sa);                  \
      sacc[1] = sa;                                                           \
      u16x4 pk;                                                               \
      pk[0] = f2bf(sa[0]); pk[1] = f2bf(sa[1]); pk[2] = f2bf(sa[2]); pk[3] = f2bf(sa[3]); \
      *(u16x4*)&SbT[sw16(fr, w * 32 + 16 + fq * 4, 128)] = pk;                \
    }                                                                         \
  }

  PREF(0, QA, MA, KA00, KA01, KA10, KA11, UA, LA4, LA63)
  __syncthreads();   // SbT zero-init visible

  for (int n = 0; n < 64; n += 2) {
    {
      PREF(n + 1, QB, MB, KB00, KB01, KB10, KB11, UB, LB4, LB63)
      PH1(QA, MA, UA, LA4, LA63)
      __syncthreads();
      const int t0 = n * 64, pair = hv * 64 + n;
      PH2(KA00, KA01, KA10, KA11, LA63, t0, pair)
      __syncthreads();
    }
    {
      PREF(n + 2, QA, MA, KA00, KA01, KA10, KA11, UA, LA4, LA63)
      PH1(QB, MB, UB, LB4, LB63)
      __syncthreads();
      const int t0 = (n + 1) * 64, pair = hv * 64 + n + 1;
      PH2(KB00, KB01, KB10, KB11, LB63, t0, pair)
      __syncthreads();
    }
  }
#undef PREF
#undef PH1
#undef PH2
}

// ---------------- parallel epilogue: o = o1 + G@delta, fused gated RMSNorm ----------------
__global__ __launch_bounds__(512)
void k_r3(const u16* __restrict__ qkvz, const u16* __restrict__ o1_g,
          const float* __restrict__ cumL_g, const float* __restrict__ nw,
          u16* __restrict__ x) {
  const int pair = blockIdx.x, hv = pair >> 6, n = pair & 63, hk = hv >> 1, t0 = n * 64;
  const int tid = threadIdx.x, lane = tid & 63, w = tid >> 6;
  const int fr = lane & 15, fq = lane >> 4;
  const int j = tid & 63, h = tid >> 6;   // h 0..7

  __shared__ __align__(16) u16 Ql[8192];
  __shared__ __align__(16) u16 Kl[8192];
  __shared__ __align__(16) u16 Gl[4096];
  __shared__ __align__(16) u16 dTl[8192];
  __shared__ __align__(16) u16 o1l[8192];      // o1 [dv][t] swz (raw block from k_r2)
  __shared__ __align__(16) float of[64 * 132];
  __shared__ float Lc[64];
  __shared__ float Lw[128];

  {
    const u16* qg = qkvz + (size_t)(t0 + j) * NTOT + hk * DKK + h * 16;
    u16x8 q0 = *(const u16x8*)qg, q1 = *(const u16x8*)(qg + 8);
    u16x8 k0 = *(const u16x8*)(qg + 2048), k1 = *(const u16x8*)(qg + 2056);
    *(u16x8*)&Ql[sw16(j, h * 16, 128)] = q0;
    *(u16x8*)&Ql[sw16(j, h * 16 + 8, 128)] = q1;
    *(u16x8*)&Kl[sw16(j, h * 16, 128)] = k0;
    *(u16x8*)&Kl[sw16(j, h * 16 + 8, 128)] = k1;
  }
#pragma unroll
  for (int it = 0; it < 2; ++it) {
    const int f = ((w * 2 + it) * 64 + lane) * 8;
    gld16(qkvz + (size_t)(t0 + (f >> 7)) * NTOT + 4096 + hv * DKK + (f & 127),
          (char*)dTl + (w * 2 + it) * 1024);
    gld16(o1_g + (size_t)pair * 8192 + f, (char*)o1l + (w * 2 + it) * 1024);
  }
  if (tid < 64) Lc[tid] = cumL_g[(size_t)pair * 64 + tid];
  if (tid < 128) Lw[tid] = nw[tid];
  __syncthreads();

  // ---- G = tril(e^{Lt-Ls} * QK^T) ----
  const int tw = w & 3, sp = (w >> 2) * 2;
  {
    f32x4 kk0 = {}, kk1 = {};
#pragma unroll
    for (int ks = 0; ks < 4; ++ks) {
      short8 aq = *(const short8*)&Ql[sw16(tw * 16 + fr, ks * 32 + fq * 8, 128)];
      short8 b0 = *(const short8*)&Kl[sw16(sp * 16 + fr, ks * 32 + fq * 8, 128)];
      short8 b1 = *(const short8*)&Kl[sw16((sp + 1) * 16 + fr, ks * 32 + fq * 8, 128)];
      kk0 = MFMA16(aq, b0, kk0);
      kk1 = MFMA16(aq, b1, kk1);
    }
#pragma unroll
    for (int e = 0; e < 4; ++e) {
      const int t = tw * 16 + fq * 4 + e;
      const float Lt = Lc[t];
      const int s0 = sp * 16 + fr, s1 = s0 + 16;
      Gl[sw16(t, s0, 64)] = f2bf((s0 <= t) ? kk0[e] * __expf(Lt - Lc[s0]) : 0.f);
      Gl[sw16(t, s1, 64)] = f2bf((s1 <= t) ? kk1[e] * __expf(Lt - Lc[s1]) : 0.f);
    }
  }
  __syncthreads();

  // ---- o = G@delta ----
  {
    short8 ag0 = *(const short8*)&Gl[sw16(tw * 16 + fr, fq * 8, 64)];
    short8 ag1 = *(const short8*)&Gl[sw16(tw * 16 + fr, 32 + fq * 8, 64)];
#pragma unroll
    for (int dd = 0; dd < 4; ++dd) {
      const int d = (w >> 2) * 4 + dd;
      short8 bd0 = *(const short8*)&dTl[sw16(d * 16 + fr, fq * 8, 64)];
      short8 bd1 = *(const short8*)&dTl[sw16(d * 16 + fr, 32 + fq * 8, 64)];
      f32x4 oc = {};
      oc = MFMA16(ag0, bd0, oc);
      oc = MFMA16(ag1, bd1, oc);
#pragma unroll
      for (int e = 0; e < 4; ++e) of[(tw * 16 + fq * 4 + e) * 132 + d * 16 + fr] = oc[e];
    }
  }
  __syncthreads();

  // ---- fused gated RMSNorm: x = rmsnorm((of + o1) * silu(z)) * w ----
  {
    const int t = tid >> 3, q8 = tid & 7;
    const u16* zp = qkvz + (size_t)(t0 + t) * NTOT + 8192 + hv * DKK + q8 * 16;
    float xv[16];
    float ss = 0.f;
#pragma unroll
    for (int i = 0; i < 2; ++i) {
      u16x8 zv = *(const u16x8*)(zp + i * 8);
#pragma unroll
      for (int e = 0; e < 8; ++e) {
        const int dv = q8 * 16 + i * 8 + e;
        float z = b2f(zv[e]);
        float o = of[t * 132 + dv] + b2f(o1l[sw16(dv, t, 64)]);
        float xx = o * (z / (1.f + __expf(-z)));
        xv[i * 8 + e] = xx;
        ss = fmaf(xx, xx, ss);
      }
    }
    ss += __shfl_xor(ss, 1);
    ss += __shfl_xor(ss, 2);
    ss += __shfl_xor(ss, 4);
    const float scl = rsqrtf(ss * (1.f / 128.f) + 1e-6f);
    u16* xo = x + (size_t)(t0 + t) * 4096 + hv * DKK + q8 * 16;
#pragma unroll
    for (int i = 0; i < 2; ++i) {
      u16x8 pk;
#pragma unroll
      for (int e = 0; e < 8; ++e) pk[e] = f2bf(xv[i * 8 + e] * scl * Lw[q8 * 16 + i * 8 + e]);
      *(u16x8*)(xo + i * 8) = pk;
    }
  }
}

extern "C" void kernel_launch(void* const* d_in, const int* in_sizes, int n_in,
                              void* d_out, int out_size, void* d_ws, size_t ws_size,
                              hipStream_t stream) {
  const float* h    = (const float*)d_in[0];
  const float* Wq   = (const float*)d_in[1];
  const float* Wk   = (const float*)d_in[2];
  const float* Wv   = (const float*)d_in[3];
  const float* Wz   = (const float*)d_in[4];
  const float* Wb   = (const float*)d_in[5];
  const float* Wa   = (const float*)d_in[6];
  const float* Alog = (const float*)d_in[7];
  const float* dtb  = (const float*)d_in[8];
  const float* nw   = (const float*)d_in[9];
  const float* Wo   = (const float*)d_in[10];
  char* ws = (char*)d_ws;
  u16* h_bf  = (u16*)(ws);
  u16* Bfq   = (u16*)(ws + 16777216ull);      // [768 j16][64 kt][512] bf16 = 50.33MB
  u16* UM    = (u16*)(ws);                    // [2048][64][256] bf16 = 64MB (after GEMM)
  u16* Bfo   = (u16*)(ws + 67108864ull);      // [128 j16][128 kt][512] bf16 = 16.8MB
  u16* qkvz  = (u16*)(ws + 83886080ull);
  u16* o1g   = (u16*)(ws + 184549376ull);     // [2048][128dv][64t] bf16 = 32MB
  u16* xbuf  = (u16*)(ws + 16777216ull);      // aliases Bfq (dead after qkvz GEMM)
  float* beta  = (float*)(ws + 218103808ull);
  float* g     = (float*)(ws + 218103808ull + 524288ull);
  float* cumL  = (float*)(ws + 218103808ull + 1048576ull);

  k_cvt<<<8192, 256, 0, stream>>>(h, h_bf, LTOK * DHID);
  k_trf<<<2048, 256, 0, stream>>>(Wq, Bfq, 2048, 64, 0);
  k_trf<<<2048, 256, 0, stream>>>(Wk, Bfq, 2048, 64, 128);
  k_trf<<<4096, 256, 0, stream>>>(Wv, Bfq, 4096, 64, 256);
  k_trf<<<4096, 256, 0, stream>>>(Wz, Bfq, 4096, 64, 512);
  k_trf<<<4096, 256, 0, stream>>>(Wo, Bfo, 2048, 128, 0);
  k_g256<u16, 2, 4><<<768, 512, 0, stream>>>(h_bf, Bfq, qkvz, 4096, 12288, 2048, 48);
  k_ba<<<1024, 256, 0, stream>>>(h, Wb, Wa, Alog, dtb, beta, g);
  k_l2n<<<32768, 256, 0, stream>>>(qkvz);
  k_r1<<<2048, 256, 0, stream>>>(qkvz, beta, g, UM, cumL);
  k_r2<<<256, 256, 0, stream>>>(qkvz, UM, cumL, o1g);
  k_r3<<<2048, 512, 0, stream>>>(qkvz, o1g, cumL, nw, xbuf);
  k_g256<float, 1, 2><<<512, 256, 0, stream>>>(xbuf, Bfo, (float*)d_out, 4096, 2048, 4096, 16);
}

// Round 19
// 751.010 us; speedup vs baseline: 1.0923x; 1.0106x over previous
//
#include <hip/hip_runtime.h>

#define LTOK 4096
#define DHID 2048
#define HKN  16
#define HVN  32
#define DKK  128
#define NTOT 12288

typedef unsigned short u16;
typedef __attribute__((ext_vector_type(8))) short short8;
typedef __attribute__((ext_vector_type(8))) unsigned short u16x8;
typedef __attribute__((ext_vector_type(4))) unsigned short u16x4;
typedef __attribute__((ext_vector_type(4))) float f32x4;

__device__ __forceinline__ float b2f(u16 u) {
  unsigned int x = ((unsigned int)u) << 16;
  return __builtin_bit_cast(float, x);
}
__device__ __forceinline__ u16 f2bf(float f) {
  unsigned int u = __builtin_bit_cast(unsigned int, f);
  u += 0x7FFFu + ((u >> 16) & 1u);
  return (u16)(u >> 16);
}

template<int C> __device__ __forceinline__ float dppmv(float x) {
  int i = __builtin_amdgcn_update_dpp(0, __builtin_bit_cast(int, x), C, 0xF, 0xF, true);
  return __builtin_bit_cast(float, i);
}
__device__ __forceinline__ float red16(float x) {
  x += dppmv<0xB1>(x);
  x += dppmv<0x4E>(x);
  x += dppmv<0x124>(x);
  x += dppmv<0x128>(x);
  return x;
}

__device__ __forceinline__ void gld16(const void* g, void* l) {
  __builtin_amdgcn_global_load_lds((const __attribute__((address_space(1))) void*)g,
                                   (__attribute__((address_space(3))) void*)l, 16, 0, 0);
}

// pinned-order LDS vector read (addr VGPR + compile-time byte offset)
template<int OFF> __device__ __forceinline__ short8 dsr(unsigned a) {
  short8 r;
  asm volatile("ds_read_b128 %0, %1 offset:%2" : "=v"(r) : "v"(a), "n"(OFF));
  return r;
}
// pinned-order global vector load to VGPR (B fragments; counted in vmcnt manually)
__device__ __forceinline__ short8 gldx4(const u16* p) {
  short8 r;
  asm volatile("global_load_dwordx4 %0, %1, off" : "=v"(r) : "v"(p));
  return r;
}
// keep a register value live (rule #17) - blocks allocator reuse until this point
#define KEEPV(x) asm volatile("" :: "v"(x))

// swizzled LDS element offsets (XOR row-bits into 16B-slot bits); byte^=((r&7)<<4)
__device__ __forceinline__ int sw16(int r, int c, int rowc) { return (r * rowc + c) ^ ((r & 7) << 3); }

__device__ __forceinline__ void cstore(u16* C, size_t i, float v) { C[i] = f2bf(v); }
__device__ __forceinline__ void cstore(float* C, size_t i, float v) { C[i] = v; }

// ---------------- fp32 -> bf16 convert ----------------
__global__ __launch_bounds__(256)
void k_cvt(const float* __restrict__ s, u16* __restrict__ d, int n) {
  const int i = (blockIdx.x * 256 + threadIdx.x) * 4;
  const float4 v = *(const float4*)(s + i);
  ushort4 o;
  o.x = f2bf(v.x); o.y = f2bf(v.y); o.z = f2bf(v.z); o.w = f2bf(v.w);
  *(ushort4*)(d + i) = o;
}

// ---------------- fp32 W[K][N] -> bf16 B-fragment-major layout ----------------
__global__ __launch_bounds__(256)
void k_trf(const float* __restrict__ W, u16* __restrict__ Bf, int Ncols, int nkt, int j16base) {
  const int wv = threadIdx.x >> 6, lane = threadIdx.x & 63;
  const int frag = blockIdx.x * 4 + wv;
  const int j16 = frag / nkt, kt = frag % nkt;
  const int r0 = kt * 32 + (lane >> 4) * 8;
  const int c = j16 * 16 + (lane & 15);
  u16x8 o;
#pragma unroll
  for (int e = 0; e < 8; ++e) o[e] = f2bf(W[(size_t)(r0 + e) * Ncols + c]);
  *(u16x8*)(Bf + ((size_t)(j16base + j16) * nkt + kt) * 512 + lane * 8) = o;
}

#define MFMA16(a, b, c) __builtin_amdgcn_mfma_f32_16x16x32_bf16(a, b, c, 0, 0, 0)

// ---------------- (NWM*128)xBN bf16 MFMA GEMM, B-from-global (flatmm) ----------------
// R19: 3 LDS buffers (was 4) -> 48KB/block -> 3 blocks/CU co-resident; the extra
// block's waves absorb the per-K-tile barrier rendezvous skew (R18 plateau at 54%
// MfmaUtil with ~1-2 blocks/CU). Depth-2 A-stage prefetch; rotating mod-3 buffer
// index. vmcnt: steady queue {B(kt),S(kt+1),B(kt+1),S(kt+2)} = 2N+4; wait retires
// B(kt)+S(kt+1) -> vmcnt(N+2). B stays 2-tiles-ahead (reload consumed set post-MFMA).
template<typename OutT, int NWM, int NWN>
__global__ __launch_bounds__(NWM * 256, 2)
void k_g256(const u16* __restrict__ A, const u16* __restrict__ Bf, OutT* __restrict__ C,
            int M, int N, int K, int NT) {
  constexpr int BN = NWN * 64;
  constexpr int BUFE = NWM * 4096;           // A elems per LDS buffer
  __shared__ u16 Lds[3 * BUFE];
  const int tid = threadIdx.x;
  const int lane = tid & 63, w = tid >> 6;
  const int fr = lane & 15, fq = lane >> 4;
  const int wm = (w >> 2) * 128, wn = (w & 3) * (NWN * 16);
  const int nkt = K >> 5;
  const size_t sK = (size_t)K;

  // supertile + XCD-aware ordering (bijective; gridDim.x % 8 == 0)
  const int MT = gridDim.x / NT;
  const int nts = (NT < 16) ? NT : 16;
  const int per_super = MT * nts;
  const int super = blockIdx.x / per_super;
  const int within = blockIdx.x % per_super;
  const int mtg = MT >> 3;
  const int q = within >> 3;
  const int mt = (within & 7) * mtg + (q % mtg);
  const int nt = super * nts + q / mtg;

  // A staging: thread covers row tid/4 (+NWM*64 for 2nd load); k-slot pre-swizzled (T2)
  const int kslot = ((tid & 3) ^ ((tid >> 3) & 3)) * 8;
  const u16* aS = A + (size_t)(mt * (NWM * 128) + (tid >> 2)) * sK + kslot;

  // B fragment base pointers (compile-time-indexed -> registers, rule #20)
  const int jw = nt * (BN / 16) + (w & 3) * NWN;
  const u16* bp[NWN];
#pragma unroll
  for (int j = 0; j < NWN; ++j) bp[j] = Bf + ((size_t)(jw + j) * nkt) * 512 + lane * 8;

  f32x4 acc[8][NWN] = {};

  auto STAGE = [&](int kt_, int buf_) {
    const int sk = (kt_ < nkt) ? kt_ : nkt - 1;
    u16* base = &Lds[buf_ * BUFE];
    gld16(aS + (size_t)sk * 32, base + tid * 8);
    gld16(aS + (size_t)(NWM * 64) * sK + (size_t)sk * 32, base + NWM * 2048 + tid * 8);
  };

#define LOADB(bset, kt_) {                                                    \
    const int sk2 = ((kt_) < nkt) ? (kt_) : (nkt - 1);                        \
    _Pragma("unroll")                                                         \
    for (int j = 0; j < NWN; ++j) bset[j] = gldx4(bp[j] + (size_t)sk2 * 512); }

  const int akey = (fr >> 1) & 3;            // read-side swizzle key
  const unsigned ldsBase = (unsigned)(size_t)(__attribute__((address_space(3))) void*)&Lds[0];
  const unsigned aA0 = ldsBase + 2u * (unsigned)((wm + fr) * 32 + ((fq ^ akey) << 3));

  short8 afA[8], afB[8], bs0[NWN], bs1[NWN];

#define RD(afX, rb_) {                                                        \
    const unsigned aAr = aA0 + (unsigned)((rb_) * (BUFE * 2));                \
    afX[0] = dsr<0>(aAr);    afX[1] = dsr<1024>(aAr);                         \
    afX[2] = dsr<2048>(aAr); afX[3] = dsr<3072>(aAr);                         \
    afX[4] = dsr<4096>(aAr); afX[5] = dsr<5120>(aAr);                         \
    afX[6] = dsr<6144>(aAr); afX[7] = dsr<7168>(aAr); }

  // prologue: A0,A1 staged (bufs 0,1), B0+B1 loaded, full drain, read A0 fragments
  STAGE(0, 0); STAGE(1, 1);
  LOADB(bs0, 0)
  LOADB(bs1, 1)
  asm volatile("s_waitcnt vmcnt(0)" ::: "memory");
  __builtin_amdgcn_s_barrier();
  RD(afA, 0)
  asm volatile("s_waitcnt lgkmcnt(0)" ::: "memory");
  __builtin_amdgcn_sched_barrier(0);

  int sb = 2;    // buffer receiving tile kt+2 (= (kt+2)%3 at loop head)
  int rbn = 1;   // buffer holding tile kt+1 (= (kt+1)%3 at loop head)

  // per iter kt: STAGE(kt+2 -> sb); vmcnt(N+2) -> {B(kt),A(kt+1)} landed; barrier;
  // RD A(kt+1) from rbn into next set (no wait); MFMA(kt); reload consumed B set
  // with B(kt+2); lgkm(0)+sched_barrier (rule #18); advance mod-3 counters.
#define ITER(kt_, afC, bC, afN) {                                             \
    STAGE((kt_) + 2, sb);                                                     \
    asm volatile("s_waitcnt vmcnt(%0)" :: "n"(NWN + 2) : "memory");           \
    __builtin_amdgcn_s_barrier();                                             \
    __builtin_amdgcn_sched_barrier(0);                                        \
    RD(afN, rbn)                                                              \
    __builtin_amdgcn_sched_barrier(0);                                        \
    __builtin_amdgcn_s_setprio(1);                                            \
    _Pragma("unroll")                                                         \
    for (int i = 0; i < 8; ++i)                                               \
      _Pragma("unroll")                                                       \
      for (int j = 0; j < NWN; ++j)                                           \
        acc[i][j] = MFMA16(afC[i], bC[j], acc[i][j]);                         \
    __builtin_amdgcn_s_setprio(0);                                            \
    LOADB(bC, (kt_) + 2)                                                      \
    asm volatile("s_waitcnt lgkmcnt(0)" ::: "memory");                        \
    __builtin_amdgcn_sched_barrier(0);                                        \
    sb = (sb == 2) ? 0 : sb + 1;                                              \
    rbn = (rbn == 2) ? 0 : rbn + 1; }

  for (int kt = 0; kt < nkt; kt += 2) {
    ITER(kt, afA, bs0, afB)
    ITER(kt + 1, afB, bs1, afA)
  }
#undef ITER
#undef RD
#undef LOADB

  asm volatile("s_waitcnt vmcnt(0) lgkmcnt(0)" ::: "memory");
  __builtin_amdgcn_sched_barrier(0);
  KEEPV(bs0[0]); KEEPV(bs0[1]);
  if constexpr (NWN == 4) { KEEPV(bs0[2]); KEEPV(bs0[3]); }
  KEEPV(bs1[0]); KEEPV(bs1[1]);
  if constexpr (NWN == 4) { KEEPV(bs1[2]); KEEPV(bs1[3]); }
  KEEPV(afA[0]); KEEPV(afA[1]); KEEPV(afA[2]); KEEPV(afA[3]);
  KEEPV(afA[4]); KEEPV(afA[5]); KEEPV(afA[6]); KEEPV(afA[7]);
  KEEPV(afB[0]); KEEPV(afB[1]); KEEPV(afB[2]); KEEPV(afB[3]);
  KEEPV(afB[4]); KEEPV(afB[5]); KEEPV(afB[6]); KEEPV(afB[7]);

  const int r0 = mt * (NWM * 128) + wm + fq * 4;
  const int c0 = nt * BN + wn + fr;
#pragma unroll
  for (int i = 0; i < 8; ++i)
#pragma unroll
    for (int j = 0; j < NWN; ++j)
#pragma unroll
      for (int e = 0; e < 4; ++e)
        cstore(C, (size_t)(r0 + i * 16 + e) * N + c0 + j * 16, acc[i][j][e]);
}

// ---------------- beta / g (log-decay): [L,2048]@[2048,32] x2 + activations ----------------
__global__ __launch_bounds__(256)
void k_ba(const float* __restrict__ h, const float* __restrict__ Wb, const float* __restrict__ Wa,
          const float* __restrict__ A_log, const float* __restrict__ dtb,
          float* __restrict__ beta, float* __restrict__ g_out) {
  const int w = threadIdx.x >> 6, lane = threadIdx.x & 63;
  const int t = blockIdx.x * 4 + w;
  const int j = lane & 31;
  const bool isB = lane < 32;
  const float* __restrict__ hr = h + (size_t)t * DHID;
  const float* Wc = isB ? Wb : Wa;
  float acc = 0.f;
  for (int kk = 0; kk < DHID; ++kk) acc = fmaf(hr[kk], Wc[(size_t)kk * HVN + j], acc);
  if (isB) {
    beta[(size_t)t * HVN + j] = 1.f / (1.f + expf(-acc));
  } else {
    float xx = acc + dtb[j];
    float sp = (xx > 20.f) ? xx : log1pf(expf(xx));
    g_out[(size_t)t * HVN + j] = -expf(A_log[j]) * sp;   // g = log(decay) <= 0
  }
}

// ---------------- in-place l2norm of q (scaled) and k heads ----------------
__global__ __launch_bounds__(256)
void k_l2n(u16* __restrict__ qkvz) {
  const int w = threadIdx.x >> 6, lane = threadIdx.x & 63;
  const int r = blockIdx.x * 4 + w;
  const int isK = r >> 16;
  const int rr = r & 65535;
  const int t = rr >> 4, hd = rr & 15;
  u16* p = qkvz + (size_t)t * NTOT + isK * 2048 + hd * DKK + lane * 2;
  float a = b2f(p[0]), b = b2f(p[1]);
  float ss = a * a + b * b;
  ss = red16(ss);
  ss += __shfl_xor(ss, 16);
  ss += __shfl_xor(ss, 32);
  const float sc = rsqrtf(ss + 1e-6f) * (isK ? 1.f : 0.08838834764831845f);
  p[0] = f2bf(a * sc); p[1] = f2bf(b * sc);
}

// ---------------- chunk solve (parallel): per (hv, chunk n) ----------------
__global__ __launch_bounds__(256)
void k_r1(const u16* __restrict__ qkvz, const float* __restrict__ beta_g,
          const float* __restrict__ g_g, u16* __restrict__ UM_g, float* __restrict__ cumL_g) {
  const int pair = blockIdx.x;          // hv*64 + n
  const int hv = pair >> 6, n = pair & 63;
  const int hk = hv >> 1;
  const int t0 = n * 64;
  const int tid = threadIdx.x, lane = tid & 63, wv = tid >> 6;
  const int fr = lane & 15, fq = lane >> 4;

  __shared__ __align__(16) u16 Xb[256 * 64];
  __shared__ __align__(16) u16 Dbuf0[64 * 64 * 2];
  __shared__ __align__(16) u16 Dbuf1[64 * 64 * 2];
  __shared__ float Lc[64];
  __shared__ float Bc[64];
  u16* Kl = Dbuf0;

  const int j = tid & 63, h = tid >> 6;
  const u16* kg = qkvz + (size_t)(t0 + j) * NTOT + 2048 + hk * DKK + h * 32;
  const u16* vg = qkvz + (size_t)(t0 + j) * NTOT + 4096 + hv * DKK + h * 32;
  u16x8 kv[4], vv[4];
#pragma unroll
  for (int i = 0; i < 4; ++i) { kv[i] = *(const u16x8*)(kg + i * 8); vv[i] = *(const u16x8*)(vg + i * 8); }
  if (tid < 64) {
    Lc[tid] = g_g[(size_t)(t0 + tid) * HVN + hv];
    Bc[tid] = beta_g[(size_t)(t0 + tid) * HVN + hv];
  }
#pragma unroll
  for (int i = 0; i < 4; ++i) *(u16x8*)&Kl[sw16(j, h * 32 + i * 8, 128)] = kv[i];
  __syncthreads();
  if (tid == 0) { float a = 0.f; for (int t = 0; t < 64; ++t) { a += Lc[t]; Lc[t] = a; } }
  __syncthreads();
  if (tid < 64) cumL_g[(size_t)pair * 64 + tid] = Lc[tid];

  {
    const float bj = Bc[j];
    const float mj = bj * __expf(Lc[j]);
#pragma unroll
    for (int i = 0; i < 4; ++i)
#pragma unroll
      for (int e = 0; e < 8; ++e) {
        int c = h * 32 + i * 8 + e;
        Xb[sw16(c, j, 64)] = f2bf(bj * b2f(vv[i][e]));
        Xb[sw16(128 + c, j, 64)] = f2bf(mj * b2f(kv[i][e]));
      }
  }
  f32x4 kk[4] = {};
#pragma unroll
  for (int ks = 0; ks < 4; ++ks) {
    short8 afr = *(const short8*)&Kl[sw16(wv * 16 + fr, ks * 32 + fq * 8, 128)];
#pragma unroll
    for (int ct = 0; ct < 4; ++ct) {
      short8 bfr = *(const short8*)&Kl[sw16(ct * 16 + fr, ks * 32 + fq * 8, 128)];
      kk[ct] = MFMA16(afr, bfr, kk[ct]);
    }
  }
  __syncthreads();

  f32x4 acc[16];
#pragma unroll
  for (int ct = 0; ct < 16; ++ct) {
    u16x4 xi = *(const u16x4*)&Xb[sw16(ct * 16 + fr, wv * 16 + fq * 4, 64)];
    acc[ct][0] = b2f(xi[0]); acc[ct][1] = b2f(xi[1]); acc[ct][2] = b2f(xi[2]); acc[ct][3] = b2f(xi[3]);
  }
#pragma unroll
  for (int ct = 0; ct < 4; ++ct) {
    const int s = ct * 16 + fr;
    u16x4 pk;
#pragma unroll
    for (int e = 0; e < 4; ++e) {
      const int t = wv * 16 + fq * 4 + e;
      float v = (s < t) ? -Bc[t] * __expf(Lc[t] - Lc[s]) * kk[ct][e] : 0.f;
      pk[e] = f2bf(v);
      Dbuf0[sw16(t, s, 64)] = pk[e];
    }
    *(u16x4*)&Dbuf0[4096 + sw16(s, wv * 16 + fq * 4, 64)] = pk;
  }
  __syncthreads();

  u16* DA = Dbuf0;
  u16* DB = Dbuf1;
  for (int stg = 0; stg < 6; ++stg) {
    u16* Dr = DA;
    u16* Dc = DA + 4096;
    short8 da0 = *(const short8*)&Dr[sw16(wv * 16 + fr, 0 + fq * 8, 64)];
    short8 da1 = *(const short8*)&Dr[sw16(wv * 16 + fr, 32 + fq * 8, 64)];
#pragma unroll
    for (int ct = 0; ct < 16; ++ct) {
      short8 b0 = *(const short8*)&Xb[sw16(ct * 16 + fr, 0 + fq * 8, 64)];
      short8 b1 = *(const short8*)&Xb[sw16(ct * 16 + fr, 32 + fq * 8, 64)];
      acc[ct] = MFMA16(da0, b0, acc[ct]);
      acc[ct] = MFMA16(da1, b1, acc[ct]);
    }
    f32x4 sq[4] = {};
    if (stg < 5) {
#pragma unroll
      for (int ct = 0; ct < 4; ++ct) {
        short8 sb0 = *(const short8*)&Dc[sw16(ct * 16 + fr, 0 + fq * 8, 64)];
        short8 sb1 = *(const short8*)&Dc[sw16(ct * 16 + fr, 32 + fq * 8, 64)];
        sq[ct] = MFMA16(da0, sb0, sq[ct]);
        sq[ct] = MFMA16(da1, sb1, sq[ct]);
      }
    }
    __syncthreads();
#pragma unroll
    for (int ct = 0; ct < 16; ++ct) {
      u16x4 pk;
      pk[0] = f2bf(acc[ct][0]); pk[1] = f2bf(acc[ct][1]); pk[2] = f2bf(acc[ct][2]); pk[3] = f2bf(acc[ct][3]);
      *(u16x4*)&Xb[sw16(ct * 16 + fr, wv * 16 + fq * 4, 64)] = pk;
    }
    if (stg < 5) {
#pragma unroll
      for (int ct = 0; ct < 4; ++ct) {
        u16x4 pk;
        pk[0] = f2bf(sq[ct][0]); pk[1] = f2bf(sq[ct][1]); pk[2] = f2bf(sq[ct][2]); pk[3] = f2bf(sq[ct][3]);
        *(u16x4*)&(DB + 4096)[sw16(ct * 16 + fr, wv * 16 + fq * 4, 64)] = pk;
#pragma unroll
        for (int e = 0; e < 4; ++e) DB[sw16(wv * 16 + fq * 4 + e, ct * 16 + fr, 64)] = pk[e];
      }
    }
    __syncthreads();
    u16* tmp = DA; DA = DB; DB = tmp;
  }

#pragma unroll
  for (int ct = 0; ct < 16; ++ct) {
    const int c = ct * 16 + fr;
#pragma unroll
    for (int e = 0; e < 4; ++e) {
      const int t = wv * 16 + fq * 4 + e;
      float v = acc[ct][e];
      if (ct >= 8) v = -v;
      UM_g[((size_t)pair * 64 + t) * 256 + c] = f2bf(v);
    }
  }
}

// ---------------- sequential chunk scan: 256 blocks = (hv, dv-eighth cs), 4 waves ----------------
__global__ __launch_bounds__(256)
void k_r2(u16* __restrict__ qkvz, const u16* __restrict__ UM_g,
          const float* __restrict__ cumL_g, u16* __restrict__ o1_g) {
  const int hv = blockIdx.x >> 3, cs = blockIdx.x & 7;
  const int hk = hv >> 1;
  const int tid = threadIdx.x, lane = tid & 63, w = tid >> 6;   // 4 waves
  const int fr = lane & 15, fq = lane >> 4;
  const int tw = w;                                              // ph1 t-tile 0..3

  __shared__ __align__(16) u16 dT[1024];       // delta^T [16 ldv][64 t] swz (raw)
  __shared__ __align__(16) u16 dT2[1024];      // delta^T * e^{L63-Lt} swz
  __shared__ __align__(16) u16 o1b[1024];      // o1 [16 ldv][64 t] swz
  __shared__ __align__(16) u16 SbT[2048];      // S^T [16 ldv][128 dk] swz

  f32x4 sacc[2];
#pragma unroll
  for (int d = 0; d < 2; ++d) sacc[d] = (f32x4){0.f, 0.f, 0.f, 0.f};
  for (int i = tid; i < 2048; i += 256) SbT[i] = 0;

  u16x8 QA[4], MA[4], QB[4], MB[4];
  u16x8 KA00, KA01, KA10, KA11, KB00, KB01, KB10, KB11;
  u16 UA[4], UB[4];
  float LA4[4], LB4[4], LA63, LB63;

#define PREF(nn, Q, Mv, K00, K01, K10, K11, U, L4, L63v) {                    \
    const int nc = ((nn) < 64) ? (nn) : 63;                                   \
    const int pr = hv * 64 + nc; const int tt0 = nc * 64;                     \
    const u16* qg = qkvz + (size_t)(tt0 + tw * 16 + fr) * NTOT + hk * DKK + fq * 8; \
    Q[0] = *(const u16x8*)qg;        Q[1] = *(const u16x8*)(qg + 32);         \
    Q[2] = *(const u16x8*)(qg + 64); Q[3] = *(const u16x8*)(qg + 96);         \
    const u16* mg = UM_g + ((size_t)pr * 64 + tw * 16 + fr) * 256 + 128 + fq * 8; \
    Mv[0] = *(const u16x8*)mg;        Mv[1] = *(const u16x8*)(mg + 32);       \
    Mv[2] = *(const u16x8*)(mg + 64); Mv[3] = *(const u16x8*)(mg + 96);       \
    const u16* ug = UM_g + ((size_t)pr * 64 + tw * 16 + fq * 4) * 256         \
                    + cs * 16 + fr;                                           \
    U[0] = ug[0]; U[1] = ug[256]; U[2] = ug[512]; U[3] = ug[768];             \
    const u16* kg = qkvz + (size_t)(tt0 + fq * 8) * NTOT + 2048 + hk * DKK + w * 32 + fr; \
    _Pragma("unroll")                                                         \
    for (int e = 0; e < 8; ++e) {                                             \
      K00[e] = kg[(size_t)e * NTOT];                                          \
      K01[e] = kg[(size_t)(32 + e) * NTOT];                                   \
      K10[e] = kg[(size_t)e * NTOT + 16];                                     \
      K11[e] = kg[(size_t)(32 + e) * NTOT + 16];                              \
    }                                                                         \
    _Pragma("unroll")                                                         \
    for (int e = 0; e < 4; ++e) L4[e] = cumL_g[(size_t)pr * 64 + tw * 16 + fq * 4 + e]; \
    L63v = cumL_g[(size_t)pr * 64 + 63]; }

#define PH1(Q, Mv, U, L4, L63v) {                                             \
    float el[4], el2[4];                                                      \
    _Pragma("unroll")                                                         \
    for (int e = 0; e < 4; ++e) {                                             \
      el[e] = __expf(L4[e]);                                                  \
      el2[e] = __expf(L63v - L4[e]);                                          \
    }                                                                         \
    f32x4 dc;                                                                 \
    dc[0] = b2f(U[0]); dc[1] = b2f(U[1]); dc[2] = b2f(U[2]); dc[3] = b2f(U[3]); \
    f32x4 oc = {};                                                            \
    _Pragma("unroll")                                                         \
    for (int ks = 0; ks < 4; ++ks) {                                          \
      short8 bs = *(const short8*)&SbT[sw16(fr, ks * 32 + fq * 8, 128)];      \
      dc = MFMA16(__builtin_bit_cast(short8, Mv[ks]), bs, dc);                \
      oc = MFMA16(__builtin_bit_cast(short8, Q[ks]), bs, oc);                 \
    }                                                                         \
    u16x4 pkd, pkd2, pko;                                                     \
    _Pragma("unroll")                                                         \
    for (int e = 0; e < 4; ++e) {                                             \
      pkd[e]  = f2bf(dc[e]);                                                  \
      pkd2[e] = f2bf(dc[e] * el2[e]);                                         \
      pko[e]  = f2bf(oc[e] * el[e]);                                          \
    }                                                                         \
    *(u16x4*)&dT[sw16(fr, tw * 16 + fq * 4, 64)] = pkd;                       \
    *(u16x4*)&dT2[sw16(fr, tw * 16 + fq * 4, 64)] = pkd2;                     \
    *(u16x4*)&o1b[sw16(fr, tw * 16 + fq * 4, 64)] = pko; }

#define PH2(K00, K01, K10, K11, L63v, t0_, pair_) {                           \
    {                                                                         \
      const int i = tid * 4;                                                  \
      u16x4 vd = *(const u16x4*)&dT[i];                                       \
      const int f = cs * 1024 + i;                                            \
      *(u16x4*)(qkvz + (size_t)((t0_) + (f >> 7)) * NTOT + 4096 + hv * DKK + (f & 127)) = vd; \
      u16x4 vo = *(const u16x4*)&o1b[i];                                      \
      *(u16x4*)(o1_g + (size_t)(pair_) * 8192 + f) = vo;                      \
    }                                                                         \
    const float eC = __expf(L63v);                                            \
    short8 bd0 = *(const short8*)&dT2[sw16(fr, fq * 8, 64)];                  \
    short8 bd1 = *(const short8*)&dT2[sw16(fr, 32 + fq * 8, 64)];             \
    {                                                                         \
      f32x4 sa = sacc[0];                                                     \
      _Pragma("unroll")                                                       \
      for (int e = 0; e < 4; ++e) sa[e] *= eC;                                \
      sa = MFMA16(__builtin_bit_cast(short8, K00), bd0, sa);                  \
      sa = MFMA16(__builtin_bit_cast(short8, K01), bd1, sa);                  \
      sacc[0] = sa;                                                           \
      u16x4 pk;                                                               \
      pk[0] = f2bf(sa[0]); pk[1] = f2bf(sa[1]); pk[2] = f2bf(sa[2]); pk[3] = f2bf(sa[3]); \
      *(u16x4*)&SbT[sw16(fr, w * 32 + fq * 4, 128)] = pk;                     \
    }                                                                         \
    {                                                                         \
      f32x4 sa = sacc[1];                                                     \
      _Pragma("unroll")                                                       \
      for (int e = 0; e < 4; ++e) sa[e] *= eC;                                \
      sa = MFMA16(__builtin_bit_cast(short8, K10), bd0, sa);                  \
      sa = MFMA16(__builtin_bit_cast(short8, K11), bd1, sa);                  \
      sacc[1] = sa;                                                           \
      u16x4 pk;                                                               \
      pk[0] = f2bf(sa[0]); pk[1] = f2bf(sa[1]); pk[2] = f2bf(sa[2]); pk[3] = f2bf(sa[3]); \
      *(u16x4*)&SbT[sw16(fr, w * 32 + 16 + fq * 4, 128)] = pk;                \
    }                                                                         \
  }

  PREF(0, QA, MA, KA00, KA01, KA10, KA11, UA, LA4, LA63)
  __syncthreads();   // SbT zero-init visible

  for (int n = 0; n < 64; n += 2) {
    {
      PREF(n + 1, QB, MB, KB00, KB01, KB10, KB11, UB, LB4, LB63)
      PH1(QA, MA, UA, LA4, LA63)
      __syncthreads();
      const int t0 = n * 64, pair = hv * 64 + n;
      PH2(KA00, KA01, KA10, KA11, LA63, t0, pair)
      __syncthreads();
    }
    {
      PREF(n + 2, QA, MA, KA00, KA01, KA10, KA11, UA, LA4, LA63)
      PH1(QB, MB, UB, LB4, LB63)
      __syncthreads();
      const int t0 = (n + 1) * 64, pair = hv * 64 + n + 1;
      PH2(KB00, KB01, KB10, KB11, LB63, t0, pair)
      __syncthreads();
    }
  }
#undef PREF
#undef PH1
#undef PH2
}

// ---------------- parallel epilogue: o = o1 + G@delta, fused gated RMSNorm ----------------
__global__ __launch_bounds__(512)
void k_r3(const u16* __restrict__ qkvz, const u16* __restrict__ o1_g,
          const float* __restrict__ cumL_g, const float* __restrict__ nw,
          u16* __restrict__ x) {
  const int pair = blockIdx.x, hv = pair >> 6, n = pair & 63, hk = hv >> 1, t0 = n * 64;
  const int tid = threadIdx.x, lane = tid & 63, w = tid >> 6;
  const int fr = lane & 15, fq = lane >> 4;
  const int j = tid & 63, h = tid >> 6;   // h 0..7

  __shared__ __align__(16) u16 Ql[8192];
  __shared__ __align__(16) u16 Kl[8192];
  __shared__ __align__(16) u16 Gl[4096];
  __shared__ __align__(16) u16 dTl[8192];
  __shared__ __align__(16) u16 o1l[8192];      // o1 [dv][t] swz (raw block from k_r2)
  __shared__ __align__(16) float of[64 * 132];
  __shared__ float Lc[64];
  __shared__ float Lw[128];

  {
    const u16* qg = qkvz + (size_t)(t0 + j) * NTOT + hk * DKK + h * 16;
    u16x8 q0 = *(const u16x8*)qg, q1 = *(const u16x8*)(qg + 8);
    u16x8 k0 = *(const u16x8*)(qg + 2048), k1 = *(const u16x8*)(qg + 2056);
    *(u16x8*)&Ql[sw16(j, h * 16, 128)] = q0;
    *(u16x8*)&Ql[sw16(j, h * 16 + 8, 128)] = q1;
    *(u16x8*)&Kl[sw16(j, h * 16, 128)] = k0;
    *(u16x8*)&Kl[sw16(j, h * 16 + 8, 128)] = k1;
  }
#pragma unroll
  for (int it = 0; it < 2; ++it) {
    const int f = ((w * 2 + it) * 64 + lane) * 8;
    gld16(qkvz + (size_t)(t0 + (f >> 7)) * NTOT + 4096 + hv * DKK + (f & 127),
          (char*)dTl + (w * 2 + it) * 1024);
    gld16(o1_g + (size_t)pair * 8192 + f, (char*)o1l + (w * 2 + it) * 1024);
  }
  if (tid < 64) Lc[tid] = cumL_g[(size_t)pair * 64 + tid];
  if (tid < 128) Lw[tid] = nw[tid];
  __syncthreads();

  // ---- G = tril(e^{Lt-Ls} * QK^T) ----
  const int tw = w & 3, sp = (w >> 2) * 2;
  {
    f32x4 kk0 = {}, kk1 = {};
#pragma unroll
    for (int ks = 0; ks < 4; ++ks) {
      short8 aq = *(const short8*)&Ql[sw16(tw * 16 + fr, ks * 32 + fq * 8, 128)];
      short8 b0 = *(const short8*)&Kl[sw16(sp * 16 + fr, ks * 32 + fq * 8, 128)];
      short8 b1 = *(const short8*)&Kl[sw16((sp + 1) * 16 + fr, ks * 32 + fq * 8, 128)];
      kk0 = MFMA16(aq, b0, kk0);
      kk1 = MFMA16(aq, b1, kk1);
    }
#pragma unroll
    for (int e = 0; e < 4; ++e) {
      const int t = tw * 16 + fq * 4 + e;
      const float Lt = Lc[t];
      const int s0 = sp * 16 + fr, s1 = s0 + 16;
      Gl[sw16(t, s0, 64)] = f2bf((s0 <= t) ? kk0[e] * __expf(Lt - Lc[s0]) : 0.f);
      Gl[sw16(t, s1, 64)] = f2bf((s1 <= t) ? kk1[e] * __expf(Lt - Lc[s1]) : 0.f);
    }
  }
  __syncthreads();

  // ---- o = G@delta ----
  {
    short8 ag0 = *(const short8*)&Gl[sw16(tw * 16 + fr, fq * 8, 64)];
    short8 ag1 = *(const short8*)&Gl[sw16(tw * 16 + fr, 32 + fq * 8, 64)];
#pragma unroll
    for (int dd = 0; dd < 4; ++dd) {
      const int d = (w >> 2) * 4 + dd;
      short8 bd0 = *(const short8*)&dTl[sw16(d * 16 + fr, fq * 8, 64)];
      short8 bd1 = *(const short8*)&dTl[sw16(d * 16 + fr, 32 + fq * 8, 64)];
      f32x4 oc = {};
      oc = MFMA16(ag0, bd0, oc);
      oc = MFMA16(ag1, bd1, oc);
#pragma unroll
      for (int e = 0; e < 4; ++e) of[(tw * 16 + fq * 4 + e) * 132 + d * 16 + fr] = oc[e];
    }
  }
  __syncthreads();

  // ---- fused gated RMSNorm: x = rmsnorm((of + o1) * silu(z)) * w ----
  {
    const int t = tid >> 3, q8 = tid & 7;
    const u16* zp = qkvz + (size_t)(t0 + t) * NTOT + 8192 + hv * DKK + q8 * 16;
    float xv[16];
    float ss = 0.f;
#pragma unroll
    for (int i = 0; i < 2; ++i) {
      u16x8 zv = *(const u16x8*)(zp + i * 8);
#pragma unroll
      for (int e = 0; e < 8; ++e) {
        const int dv = q8 * 16 + i * 8 + e;
        float z = b2f(zv[e]);
        float o = of[t * 132 + dv] + b2f(o1l[sw16(dv, t, 64)]);
        float xx = o * (z / (1.f + __expf(-z)));
        xv[i * 8 + e] = xx;
        ss = fmaf(xx, xx, ss);
      }
    }
    ss += __shfl_xor(ss, 1);
    ss += __shfl_xor(ss, 2);
    ss += __shfl_xor(ss, 4);
    const float scl = rsqrtf(ss * (1.f / 128.f) + 1e-6f);
    u16* xo = x + (size_t)(t0 + t) * 4096 + hv * DKK + q8 * 16;
#pragma unroll
    for (int i = 0; i < 2; ++i) {
      u16x8 pk;
#pragma unroll
      for (int e = 0; e < 8; ++e) pk[e] = f2bf(xv[i * 8 + e] * scl * Lw[q8 * 16 + i * 8 + e]);
      *(u16x8*)(xo + i * 8) = pk;
    }
  }
}

extern "C" void kernel_launch(void* const* d_in, const int* in_sizes, int n_in,
                              void* d_out, int out_size, void* d_ws, size_t ws_size,
                              hipStream_t stream) {
  const float* h    = (const float*)d_in[0];
  const float* Wq   = (const float*)d_in[1];
  const float* Wk   = (const float*)d_in[2];
  const float* Wv   = (const float*)d_in[3];
  const float* Wz   = (const float*)d_in[4];
  const float* Wb   = (const float*)d_in[5];
  const float* Wa   = (const float*)d_in[6];
  const float* Alog = (const float*)d_in[7];
  const float* dtb  = (const float*)d_in[8];
  const float* nw   = (const float*)d_in[9];
  const float* Wo   = (const float*)d_in[10];
  char* ws = (char*)d_ws;
  u16* h_bf  = (u16*)(ws);
  u16* Bfq   = (u16*)(ws + 16777216ull);      // [768 j16][64 kt][512] bf16 = 50.33MB
  u16* UM    = (u16*)(ws);                    // [2048][64][256] bf16 = 64MB (after GEMM)
  u16* Bfo   = (u16*)(ws + 67108864ull);      // [128 j16][128 kt][512] bf16 = 16.8MB
  u16* qkvz  = (u16*)(ws + 83886080ull);
  u16* o1g   = (u16*)(ws + 184549376ull);     // [2048][128dv][64t] bf16 = 32MB
  u16* xbuf  = (u16*)(ws + 16777216ull);      // aliases Bfq (dead after qkvz GEMM)
  float* beta  = (float*)(ws + 218103808ull);
  float* g     = (float*)(ws + 218103808ull + 524288ull);
  float* cumL  = (float*)(ws + 218103808ull + 1048576ull);

  k_cvt<<<8192, 256, 0, stream>>>(h, h_bf, LTOK * DHID);
  k_trf<<<2048, 256, 0, stream>>>(Wq, Bfq, 2048, 64, 0);
  k_trf<<<2048, 256, 0, stream>>>(Wk, Bfq, 2048, 64, 128);
  k_trf<<<4096, 256, 0, stream>>>(Wv, Bfq, 4096, 64, 256);
  k_trf<<<4096, 256, 0, stream>>>(Wz, Bfq, 4096, 64, 512);
  k_trf<<<4096, 256, 0, stream>>>(Wo, Bfo, 2048, 128, 0);
  k_g256<u16, 2, 4><<<768, 512, 0, stream>>>(h_bf, Bfq, qkvz, 4096, 12288, 2048, 48);
  k_ba<<<1024, 256, 0, stream>>>(h, Wb, Wa, Alog, dtb, beta, g);
  k_l2n<<<32768, 256, 0, stream>>>(qkvz);
  k_r1<<<2048, 256, 0, stream>>>(qkvz, beta, g, UM, cumL);
  k_r2<<<256, 256, 0, stream>>>(qkvz, UM, cumL, o1g);
  k_r3<<<2048, 512, 0, stream>>>(qkvz, o1g, cumL, nw, xbuf);
  k_g256<float, 1, 2><<<512, 256, 0, stream>>>(xbuf, Bfo, (float*)d_out, 4096, 2048, 4096, 16);
}